// Round 9
// baseline (750.228 us; speedup 1.0000x reference)
//
#include <hip/hip_runtime.h>
#include <stdint.h>

#define N_NODES 100000
#define N_EDGES 1000000
#define NBLK 391   // ceil(N_NODES/256)

typedef unsigned short u16;
typedef unsigned int u32;
typedef __attribute__((ext_vector_type(8))) short bshort8;
typedef __attribute__((ext_vector_type(4))) float f32x4;

__device__ __forceinline__ float bf2f(u16 u){ union{float f; u32 i;} x; x.i=((u32)u)<<16; return x.f; }
__device__ __forceinline__ u16 f2bf(float f){ union{float f; u32 i;} x; x.f=f; u32 r = x.i + 0x7FFFu + ((x.i>>16)&1u); return (u16)(r>>16); }

__device__ __forceinline__ float fexp2(float x){
#if __has_builtin(__builtin_amdgcn_exp2f)
    return __builtin_amdgcn_exp2f(x);
#else
    return exp2f(x);
#endif
}
__device__ __forceinline__ float frcp(float x){
#if __has_builtin(__builtin_amdgcn_rcpf)
    return __builtin_amdgcn_rcpf(x);
#else
    return 1.0f/x;
#endif
}
#define LOG2E 1.442695041f

// ---------------- dtype detector (f32 vs bf16 device buffers) ----------------
__global__ void k_detect(const u16* __restrict__ x, int* flagp){
    __shared__ int cnt;
    if(threadIdx.x == 0) cnt = 0;
    __syncthreads();
    int c = 0;
    for(int i = threadIdx.x; i < 2048; i += 256){
        int e = (x[i] >> 7) & 0xFF;
        if(e >= 0x90) c++;
    }
    atomicAdd(&cnt, c);
    __syncthreads();
    if(threadIdx.x == 0) flagp[0] = (cnt > 64) ? 1 : 0;   // 1 = f32, 0 = bf16
}

// canonical f32 table offsets
#define CX    0
#define CW1   800000
#define CB1   800512
#define CW2   800576
#define CB2   804672
#define CEMB  804736
#define CWIH  808832
#define CWHH  821120
#define CBIH  833408
#define CBHH  833600
#define CL1W  833792
#define CL1B  841984
#define CLTW  842048
#define CLTB  850240
#define CLFW  850304
#define CLFB  850560
#define CTOT  850562

__device__ __forceinline__ float ldany(const void* p, int i, int fl){
    return fl ? ((const float*)p)[i] : bf2f(((const u16*)p)[i]);
}

__global__ void k_convert(const int* __restrict__ flagp,
                          const void* x, const void* w1, const void* b1, const void* w2,
                          const void* b2, const void* emb, const void* wih, const void* whh,
                          const void* bih, const void* bhh, const void* l1w, const void* l1b,
                          const void* ltw, const void* ltb, const void* lfw, const void* lfb,
                          float* __restrict__ canon){
    int i = blockIdx.x*256 + threadIdx.x;
    if(i >= CTOT) return;
    int fl = *flagp;
    const void* p; int off;
    if     (i < CW1 ){ p = x;   off = i;        }
    else if(i < CB1 ){ p = w1;  off = i - CW1;  }
    else if(i < CW2 ){ p = b1;  off = i - CB1;  }
    else if(i < CB2 ){ p = w2;  off = i - CW2;  }
    else if(i < CEMB){ p = b2;  off = i - CB2;  }
    else if(i < CWIH){ p = emb; off = i - CEMB; }
    else if(i < CWHH){ p = wih; off = i - CWIH; }
    else if(i < CBIH){ p = whh; off = i - CWHH; }
    else if(i < CBHH){ p = bih; off = i - CBIH; }
    else if(i < CL1W){ p = bhh; off = i - CBHH; }
    else if(i < CL1B){ p = l1w; off = i - CL1W; }
    else if(i < CLTW){ p = l1b; off = i - CL1B; }
    else if(i < CLTB){ p = ltw; off = i - CLTW; }
    else if(i < CLFW){ p = ltb; off = i - CLTB; }
    else if(i < CLFB){ p = lfw; off = i - CLFW; }
    else             { p = lfb; off = i - CLFB; }
    float v = ldany(p, off, fl);
    canon[i] = (v == v && fabsf(v) < 1e30f) ? v : 0.f;
}

// ---------------- CSR build: histogram -> scan -> fill (el, dl, eid) ----------------
__global__ void k_hist(const int* __restrict__ ei, int* __restrict__ deg){
    int e = blockIdx.x*256 + threadIdx.x;
    if(e < N_EDGES) atomicAdd(&deg[ei[N_EDGES + e]], 1);
}
__global__ void k_scan1(const int* __restrict__ deg, int* __restrict__ rowptr,
                        int* __restrict__ bsum){
    __shared__ int sh[256];
    int tid = threadIdx.x;
    int i = blockIdx.x*256 + tid;
    int v = (i < N_NODES) ? deg[i] : 0;
    sh[tid] = v;
    __syncthreads();
    for(int off = 1; off < 256; off <<= 1){
        int t = (tid >= off) ? sh[tid - off] : 0;
        __syncthreads();
        sh[tid] += t;
        __syncthreads();
    }
    if(i < N_NODES) rowptr[i] = sh[tid] - v;
    if(tid == 255) bsum[blockIdx.x] = sh[255];
}
__global__ void k_scan2(int* __restrict__ bsum){
    __shared__ int sh[512];
    int tid = threadIdx.x;
    int v = (tid < NBLK) ? bsum[tid] : 0;
    sh[tid] = v;
    __syncthreads();
    for(int off = 1; off < 512; off <<= 1){
        int t = (tid >= off) ? sh[tid - off] : 0;
        __syncthreads();
        sh[tid] += t;
        __syncthreads();
    }
    if(tid < NBLK) bsum[tid] = sh[tid] - v;
}
__global__ void k_scan3(const int* __restrict__ deg, const int* __restrict__ bsum,
                        int* __restrict__ rowptr, int* __restrict__ cursor,
                        float* __restrict__ dinv){
    int i = blockIdx.x*256 + threadIdx.x;
    if(i < N_NODES){
        int r = rowptr[i] + bsum[i >> 8];
        rowptr[i] = r;
        cursor[i] = r;
        dinv[i] = rsqrtf((float)deg[i] + 1.0f);   // +1 self loop
    }
    if(i == 0) rowptr[N_NODES] = N_EDGES;
}
__global__ void k_fill(const int* __restrict__ ei, int* __restrict__ cursor,
                       int* __restrict__ el, int* __restrict__ dl, int* __restrict__ eid){
    int e = blockIdx.x*256 + threadIdx.x;
    if(e < N_EDGES){
        int s = ei[e], d = ei[N_EDGES + e];
        int pos = atomicAdd(&cursor[d], 1);
        el[pos] = s;
        dl[pos] = d;
        eid[pos] = e;
    }
}

// ---------------- conv1: src = bf16((x @ W1) * dinv) ----------------
__global__ void k_t1s(const float* __restrict__ cx, const float* __restrict__ cw1,
                      const float* __restrict__ dinv, u16* __restrict__ src){
    __shared__ float w[512];
    int t = threadIdx.x;
    w[t]       = cw1[t];
    w[t + 256] = cw1[t + 256];
    __syncthreads();
    int i = blockIdx.x*256 + t;      // grid exactly N*64/256
    int n = i >> 6, f = i & 63;
    const float* xr = cx + n*8;
    float acc = 0.f;
    #pragma unroll
    for(int k = 0; k < 8; k++) acc += xr[k] * w[k*64 + f];
    src[i] = f2bf(acc * dinv[n]);
}

// ---------------- fused gather + epilogue (bf16 src rows, strided bf16 out) ----------------
__global__ __launch_bounds__(256)
void k_gather_ep(const int* __restrict__ rowptr, const int* __restrict__ el,
                 const u16* __restrict__ src, const float* __restrict__ dinv,
                 const float* __restrict__ b, u16* __restrict__ h, int ostride){
    int gid = blockIdx.x*256 + threadIdx.x;   // grid exactly N*64/256
    int node = gid >> 6, lane = gid & 63;
    int beg = rowptr[node], end = rowptr[node + 1];
    float acc = bf2f(src[node*64 + lane]);    // self loop (pre-scaled by dinv[src])
    int i = beg;
    for(; i + 4 <= end; i += 4){
        int s0 = el[i], s1 = el[i+1], s2 = el[i+2], s3 = el[i+3];
        float a0 = bf2f(src[s0*64 + lane]);
        float a1 = bf2f(src[s1*64 + lane]);
        float a2 = bf2f(src[s2*64 + lane]);
        float a3 = bf2f(src[s3*64 + lane]);
        acc += a0; acc += a1; acc += a2; acc += a3;
    }
    for(; i < end; i++) acc += bf2f(src[el[i]*64 + lane]);
    h[node*ostride + lane] = f2bf(fmaxf(dinv[node]*acc + b[lane], 0.f));
}

// ---------------- pack B matrix (f32 canon -> bf16 MFMA fragment order) ----------------
__global__ void k_packb(const float* __restrict__ src, u16* __restrict__ dst,
                        int K, int N, int ldk, int ldn){
    int i = blockIdx.x*256 + threadIdx.x;
    if(i >= K*N) return;
    int k = i / N, n = i % N;
    int kt = k >> 5, kk = k & 31, q = kk >> 3, j = kk & 7;
    int nt = n >> 4, nn = n & 15;
    int KT = K >> 5;
    dst[(((nt*KT + kt)*64) + (q*16 + nn))*8 + j] = f2bf(src[k*ldk + n*ldn]);
}

// ---------------- gi table (b_hh folded for r,z) ----------------
__global__ void k_gitab(const float* __restrict__ emb, const float* __restrict__ wih,
                        const float* __restrict__ bih, const float* __restrict__ bhh,
                        float* __restrict__ giT){
    int i = blockIdx.x*256 + threadIdx.x;
    if(i >= 64*192) return;
    int v = i / 192, g = i % 192;
    float acc = bih[g] + ((g < 128) ? bhh[g] : 0.0f);
    const float* wr = wih + g*64;
    const float* er = emb + v*64;
    for(int f = 0; f < 64; f++) acc += wr[f] * er[f];
    giT[i] = acc;
}

// ---------------- conv2 GEMM: src = bf16((h1 @ W2) * dinv) ----------------
__global__ __launch_bounds__(256, 4)
void k_conv2(const u16* __restrict__ h, const u16* __restrict__ w2p,
             const float* __restrict__ dinv, u16* __restrict__ src){
    int wv = threadIdx.x >> 6, lane = threadIdx.x & 63;
    int g = blockIdx.x*4 + wv;
    if(g >= N_NODES/16) return;
    int q = lane >> 4, m = lane & 15, col = m;
    bshort8 a0 = *(const bshort8*)(h + (g*16 + m)*64 + q*8);
    bshort8 a1 = *(const bshort8*)(h + (g*16 + m)*64 + 32 + q*8);
    f32x4 acc[4];
    #pragma unroll
    for(int nt = 0; nt < 4; nt++){
        f32x4 c = {0.f,0.f,0.f,0.f};
        c = __builtin_amdgcn_mfma_f32_16x16x32_bf16(a0, *(const bshort8*)(w2p + ((nt*2+0)*64 + lane)*8), c, 0,0,0);
        c = __builtin_amdgcn_mfma_f32_16x16x32_bf16(a1, *(const bshort8*)(w2p + ((nt*2+1)*64 + lane)*8), c, 0,0,0);
        acc[nt] = c;
    }
    #pragma unroll
    for(int nt = 0; nt < 4; nt++)
        #pragma unroll
        for(int r = 0; r < 4; r++){
            int node = g*16 + q*4 + r;
            src[node*64 + nt*16 + col] = f2bf(acc[nt][r] * dinv[node]);
        }
}

// ---------------- GRU: wave per 16 nodes; Whh in LDS; strided output into nodef ----------------
__global__ __launch_bounds__(256, 3)
void k_gru(const int* __restrict__ xt, const u16* __restrict__ whhp,
           const float* __restrict__ giT, const float* __restrict__ bhh,
           u16* __restrict__ txt){   // txt = nodef + 64, stride 128
    __shared__ __align__(16) u16 wsh[12288];
    __shared__ __align__(16) float hsh[4][16][68];
    int tid = threadIdx.x;
    {
        const uint4* s = (const uint4*)whhp;
        uint4* d = (uint4*)wsh;
        #pragma unroll
        for(int i = 0; i < 6; i++) d[tid + 256*i] = s[tid + 256*i];
    }
    __syncthreads();

    int wv = tid >> 6, lane = tid & 63;
    int q = lane >> 4, m = lane & 15, col = m;
    int g = blockIdx.x*4 + wv;
    bool active = g < (N_NODES/16);
    int nb = active ? g*16 : 0;

    float bhhn[4];
    #pragma unroll
    for(int t = 0; t < 4; t++) bhhn[t] = bhh[128 + t*16 + col];

    const bshort8* wl = (const bshort8*)wsh;
    float* hp = &hsh[wv][m][0];

    float hc[4][4];
    #pragma unroll
    for(int t = 0; t < 4; t++)
        #pragma unroll
        for(int r = 0; r < 4; r++) hc[t][r] = 0.f;

    for(int s = 0; s < 10; s++){
        #pragma unroll
        for(int t = 0; t < 4; t++)
            #pragma unroll
            for(int r = 0; r < 4; r++)
                hsh[wv][q*4 + r][t*16 + col] = hc[t][r];

        asm volatile("" ::: "memory");
        float4 x0 = *(float4*)(hp + q*8);
        float4 x1 = *(float4*)(hp + q*8 + 4);
        float4 x2 = *(float4*)(hp + 32 + q*8);
        float4 x3 = *(float4*)(hp + 32 + q*8 + 4);
        u32 aw[8];
        aw[0] = (u32)f2bf(x0.x) | ((u32)f2bf(x0.y) << 16);
        aw[1] = (u32)f2bf(x0.z) | ((u32)f2bf(x0.w) << 16);
        aw[2] = (u32)f2bf(x1.x) | ((u32)f2bf(x1.y) << 16);
        aw[3] = (u32)f2bf(x1.z) | ((u32)f2bf(x1.w) << 16);
        aw[4] = (u32)f2bf(x2.x) | ((u32)f2bf(x2.y) << 16);
        aw[5] = (u32)f2bf(x2.z) | ((u32)f2bf(x2.w) << 16);
        aw[6] = (u32)f2bf(x3.x) | ((u32)f2bf(x3.y) << 16);
        aw[7] = (u32)f2bf(x3.z) | ((u32)f2bf(x3.w) << 16);
        bshort8 a0 = *(bshort8*)&aw[0];
        bshort8 a1 = *(bshort8*)&aw[4];

        int tok[4];
        #pragma unroll
        for(int r = 0; r < 4; r++) tok[r] = xt[(nb + q*4 + r)*10 + s] & 63;

        f32x4 acc[12];
        #pragma unroll
        for(int nt = 0; nt < 12; nt++){
            f32x4 c = {0.f,0.f,0.f,0.f};
            c = __builtin_amdgcn_mfma_f32_16x16x32_bf16(a0, wl[(nt*2+0)*64 + lane], c, 0,0,0);
            c = __builtin_amdgcn_mfma_f32_16x16x32_bf16(a1, wl[(nt*2+1)*64 + lane], c, 0,0,0);
            acc[nt] = c;
        }

        #pragma unroll
        for(int r = 0; r < 4; r++){
            const float* gp = giT + tok[r]*192 + col;
            #pragma unroll
            for(int t = 0; t < 4; t++){
                float gir = gp[t*16], giz = gp[64 + t*16], gin = gp[128 + t*16];
                float rr = frcp(1.0f + fexp2(-LOG2E*(gir + acc[t][r])));
                float zz = frcp(1.0f + fexp2(-LOG2E*(giz + acc[4+t][r])));
                float narg = gin + rr*(acc[8+t][r] + bhhn[t]);
                float e2 = fexp2(2.0f*LOG2E*narg);
                float nn = 1.0f - 2.0f*frcp(e2 + 1.0f);
                hc[t][r] = nn + zz*(hc[t][r] - nn);
            }
        }
        asm volatile("" ::: "memory");
    }
    if(active){
        #pragma unroll
        for(int t = 0; t < 4; t++)
            #pragma unroll
            for(int r = 0; r < 4; r++)
                txt[(size_t)(nb + q*4 + r)*128 + t*16 + col] = f2bf(hc[t][r]);
    }
}

// ---------------- edge MLP: LDS row staging; 4 blocks/CU (R8: latency-bound @21% occ) ----------------
__global__ __launch_bounds__(256, 4)
void k_edge(const int* __restrict__ el, const int* __restrict__ dl, const int* __restrict__ eid,
            const u16* __restrict__ nodef,   // [N][128]: h2 at +0, txt at +64
            const u16* __restrict__ l1p, const u16* __restrict__ ltp,
            const float* __restrict__ b1, const float* __restrict__ bt,
            const float* __restrict__ wfin, const float* __restrict__ bfin,
            const int* __restrict__ flagp, void* __restrict__ out){
    // rows 0..15: s-rows; rows 16..31: d-rows. Row stride 136 u16 = 272 B.
    __shared__ __align__(16) u16 esh[4][32][136];
    union U4B8 { uint4 u; bshort8 b; };
    int tid = threadIdx.x;
    int wv = tid >> 6, lane = tid & 63;
    int q = lane >> 4, m = lane & 15, col = m;
    int t16 = lane & 15;     // 16-B chunk index within a row (staging)
    int rq  = lane >> 4;     // row-within-group (staging)
    int wgid = (blockIdx.x*256 + tid) >> 6;
    int nw = (gridDim.x*256) >> 6;
    int fl = *flagp;

    bshort8 wa[16], wb[16];
    #pragma unroll
    for(int i = 0; i < 16; i++){
        wa[i] = *(const bshort8*)(l1p + (i*64 + lane)*8);
        wb[i] = *(const bshort8*)(ltp + (i*64 + lane)*8);
    }
    float b1c[4], btc[4], wfp[2][4], wft[2][4];
    #pragma unroll
    for(int t = 0; t < 4; t++){
        b1c[t] = b1[t*16 + col];
        btc[t] = bt[t*16 + col];
        wfp[0][t] = wfin[t*16 + col];        wfp[1][t] = wfin[128 + t*16 + col];
        wft[0][t] = wfin[64 + t*16 + col];   wft[1][t] = wfin[128 + 64 + t*16 + col];
    }
    float bf0 = bfin[0], bf1 = bfin[1];

    for(int g = wgid; g < N_EDGES/16; g += nw){
        int pos = g*16 + m;
        int s = el[pos], d = dl[pos];

        // ---- cooperative staging: 8 steps x 4 rows x 256 B ----
        #pragma unroll
        for(int step = 0; step < 8; step++){
            int r = step*4 + rq;                 // 0..31
            int edge = r & 15;
            int nodeS = __shfl(s, edge, 16);
            int nodeD = __shfl(d, edge, 16);
            int node = (r < 16) ? nodeS : nodeD;
            const uint4* gp = (const uint4*)(nodef + (size_t)node*128 + t16*8);
            *(uint4*)&esh[wv][r][t16*8] = *gp;
        }
        asm volatile("" ::: "memory");   // ds_writes complete (program order) before reads

        const u16* sr = &esh[wv][m][0];
        const u16* dr = &esh[wv][16 + m][0];
        U4B8 a0u, a1u, a2u, a3u, c0u, c1u, c2u, c3u;
        a0u.u = *(const uint4*)(sr + q*8);
        a1u.u = *(const uint4*)(sr + 32 + q*8);
        a2u.u = *(const uint4*)(dr + q*8);
        a3u.u = *(const uint4*)(dr + 32 + q*8);
        c0u.u = *(const uint4*)(sr + 64 + q*8);
        c1u.u = *(const uint4*)(sr + 96 + q*8);
        c2u.u = *(const uint4*)(dr + 64 + q*8);
        c3u.u = *(const uint4*)(dr + 96 + q*8);

        f32x4 p[4];
        #pragma unroll
        for(int nt = 0; nt < 4; nt++){
            f32x4 c = {0.f,0.f,0.f,0.f};
            c = __builtin_amdgcn_mfma_f32_16x16x32_bf16(a0u.b, wa[nt*4+0], c, 0,0,0);
            c = __builtin_amdgcn_mfma_f32_16x16x32_bf16(a1u.b, wa[nt*4+1], c, 0,0,0);
            c = __builtin_amdgcn_mfma_f32_16x16x32_bf16(a2u.b, wa[nt*4+2], c, 0,0,0);
            c = __builtin_amdgcn_mfma_f32_16x16x32_bf16(a3u.b, wa[nt*4+3], c, 0,0,0);
            p[nt] = c;
        }
        f32x4 pt[4];
        #pragma unroll
        for(int nt = 0; nt < 4; nt++){
            f32x4 c = {0.f,0.f,0.f,0.f};
            c = __builtin_amdgcn_mfma_f32_16x16x32_bf16(c0u.b, wb[nt*4+0], c, 0,0,0);
            c = __builtin_amdgcn_mfma_f32_16x16x32_bf16(c1u.b, wb[nt*4+1], c, 0,0,0);
            c = __builtin_amdgcn_mfma_f32_16x16x32_bf16(c2u.b, wb[nt*4+2], c, 0,0,0);
            c = __builtin_amdgcn_mfma_f32_16x16x32_bf16(c3u.b, wb[nt*4+3], c, 0,0,0);
            pt[nt] = c;
        }
        float l0[4], l1[4];
        #pragma unroll
        for(int r = 0; r < 4; r++){
            float s0 = 0.f, s1 = 0.f;
            #pragma unroll
            for(int t = 0; t < 4; t++){
                float xp = fmaxf(p[t][r]  + b1c[t], 0.f);
                float xq = fmaxf(pt[t][r] + btc[t], 0.f);
                s0 += xp*wfp[0][t] + xq*wft[0][t];
                s1 += xp*wfp[1][t] + xq*wft[1][t];
            }
            l0[r] = s0; l1[r] = s1;
        }
        #pragma unroll
        for(int r = 0; r < 4; r++)
            #pragma unroll
            for(int msk = 1; msk < 16; msk <<= 1){
                l0[r] += __shfl_xor(l0[r], msk, 64);
                l1[r] += __shfl_xor(l1[r], msk, 64);
            }
        if(m == 0){
            #pragma unroll
            for(int r = 0; r < 4; r++){
                float a = l0[r] + bf0, b = l1[r] + bf1;
                float mx = fmaxf(a, b);
                float lse = mx + __logf(__expf(a - mx) + __expf(b - mx));
                int oi = eid[g*16 + q*4 + r];
                if(fl){
                    float2 v; v.x = a - lse; v.y = b - lse;
                    ((float2*)out)[oi] = v;
                }else{
                    u32 pack = (u32)f2bf(a - lse) | ((u32)f2bf(b - lse) << 16);
                    ((u32*)out)[oi] = pack;
                }
            }
        }
        asm volatile("" ::: "memory");   // reads done before next iteration's staging
    }
}

// ---------------- workspace layout (~55.5 MB) ----------------
static const size_t O_FLAG   = 0;
static const size_t O_CANON  = 4096;       // 3,402,248
static const size_t O_GIT    = 3407872;    // 49,152
static const size_t O_W2P    = 3457024;    // 8,192
static const size_t O_WHHP   = 3465216;    // 24,576
static const size_t O_L1P    = 3489792;    // 16,384
static const size_t O_LTP    = 3506176;    // 16,384
static const size_t O_DINV   = 3522560;    // 400,000
static const size_t O_DEG    = 3922560;    // 400,000
static const size_t O_ROWPTR = 4322560;    // 400,128
static const size_t O_CURSOR = 4722688;    // 400,000
static const size_t O_BSUM   = 5122688;    // 2,048
static const size_t O_EL     = 5124736;    // 4,000,000
static const size_t O_DL     = 9125888;    // 4,000,000
static const size_t O_EID    = 13125888;   // 4,000,000
static const size_t O_SRC    = 17125888;   // N*64 bf16 = 12,800,000
static const size_t O_H1     = 29925888;   // N*64 bf16 = 12,800,000
static const size_t O_NODEF  = 29925888;   // N*128 bf16 = 25,600,000 (overlays h1: h1 dead after conv2)
// end = 55,525,888

extern "C" void kernel_launch(void* const* d_in, const int* in_sizes, int n_in,
                              void* d_out, int out_size, void* d_ws, size_t ws_size,
                              hipStream_t stream){
    const void* x    = d_in[0];
    const int*  ei   = (const int*)d_in[1];
    const int*  xt   = (const int*)d_in[2];

    char* ws = (char*)d_ws;
    int*   flagp  = (int*)(ws + O_FLAG);
    float* canon  = (float*)(ws + O_CANON);
    float* giT    = (float*)(ws + O_GIT);
    u16*   w2p    = (u16*)(ws + O_W2P);
    u16*   whhp   = (u16*)(ws + O_WHHP);
    u16*   l1p    = (u16*)(ws + O_L1P);
    u16*   ltp    = (u16*)(ws + O_LTP);
    float* dinv   = (float*)(ws + O_DINV);
    int*   deg    = (int*)(ws + O_DEG);
    int*   rowptr = (int*)(ws + O_ROWPTR);
    int*   cursor = (int*)(ws + O_CURSOR);
    int*   bsum   = (int*)(ws + O_BSUM);
    int*   el     = (int*)(ws + O_EL);
    int*   dl     = (int*)(ws + O_DL);
    int*   eid    = (int*)(ws + O_EID);
    u16*   src    = (u16*)(ws + O_SRC);
    u16*   hbuf1  = (u16*)(ws + O_H1);
    u16*   nodef  = (u16*)(ws + O_NODEF);

    // dtype detect + canonicalize
    k_detect<<<1, 256, 0, stream>>>((const u16*)x, flagp);
    k_convert<<<(CTOT+255)/256, 256, 0, stream>>>(flagp,
        x, d_in[3], d_in[4], d_in[5], d_in[6], d_in[7], d_in[8], d_in[9],
        d_in[10], d_in[11], d_in[12], d_in[13], d_in[14], d_in[15], d_in[16], d_in[17],
        canon);

    const float* cx   = canon + CX;
    const float* cw1  = canon + CW1;
    const float* cb1  = canon + CB1;
    const float* cw2  = canon + CW2;
    const float* cb2  = canon + CB2;
    const float* cemb = canon + CEMB;
    const float* cwih = canon + CWIH;
    const float* cwhh = canon + CWHH;
    const float* cbih = canon + CBIH;
    const float* cbhh = canon + CBHH;
    const float* cl1w = canon + CL1W;
    const float* cl1b = canon + CL1B;
    const float* cltw = canon + CLTW;
    const float* cltb = canon + CLTB;
    const float* clfw = canon + CLFW;
    const float* clfb = canon + CLFB;

    // CSR build (once; reused by both GCN layers and the edge kernel)
    hipMemsetAsync(deg, 0, (size_t)N_NODES*4, stream);
    k_hist <<<(N_EDGES+255)/256, 256, 0, stream>>>(ei, deg);
    k_scan1<<<NBLK, 256, 0, stream>>>(deg, rowptr, bsum);
    k_scan2<<<1, 512, 0, stream>>>(bsum);
    k_scan3<<<NBLK, 256, 0, stream>>>(deg, bsum, rowptr, cursor, dinv);
    k_fill <<<(N_EDGES+255)/256, 256, 0, stream>>>(ei, cursor, el, dl, eid);

    // weight packing + gi table (tiny)
    k_packb<<<(64*64+255)/256, 256, 0, stream>>>(cw2, w2p, 64, 64, 64, 1);
    k_packb<<<(64*192+255)/256, 256, 0, stream>>>(cwhh, whhp, 64, 192, 1, 64);
    k_packb<<<(128*64+255)/256, 256, 0, stream>>>(cl1w, l1p, 128, 64, 1, 128);
    k_packb<<<(128*64+255)/256, 256, 0, stream>>>(cltw, ltp, 128, 64, 1, 128);
    k_gitab<<<(64*192+255)/256, 256, 0, stream>>>(cemb, cwih, cbih, cbhh, giT);

    // GCN layer 1 (src -> h1, stride 64)
    k_t1s<<<N_NODES*64/256, 256, 0, stream>>>(cx, cw1, dinv, src);
    k_gather_ep<<<N_NODES*64/256, 256, 0, stream>>>(rowptr, el, src, dinv, cb1, hbuf1, 64);

    // GCN layer 2 (h1 -> src -> nodef[+0], stride 128)
    k_conv2<<<(N_NODES/16 + 3)/4, 256, 0, stream>>>(hbuf1, w2p, dinv, src);
    k_gather_ep<<<N_NODES*64/256, 256, 0, stream>>>(rowptr, el, src, dinv, cb2, nodef, 128);

    // GRU over text -> nodef[+64], stride 128
    k_gru<<<(N_NODES/16 + 3)/4, 256, 0, stream>>>(xt, whhp, giT, cbhh, nodef + 64);

    // edge-pair MLPs + final + log_softmax (CSR order, scatter by eid)
    k_edge<<<4096, 256, 0, stream>>>(el, dl, eid, nodef, l1p, ltp, cl1b, cltb, clfw, clfb,
                                     flagp, d_out);
}

// Round 10
// 497.425 us; speedup vs baseline: 1.5082x; 1.5082x over previous
//
#include <hip/hip_runtime.h>
#include <stdint.h>

#define N_NODES 100000
#define N_EDGES 1000000
#define NBLK 391   // ceil(N_NODES/256)

typedef unsigned short u16;
typedef unsigned int u32;
typedef __attribute__((ext_vector_type(8))) short bshort8;
typedef __attribute__((ext_vector_type(4))) float f32x4;

__device__ __forceinline__ float bf2f(u16 u){ union{float f; u32 i;} x; x.i=((u32)u)<<16; return x.f; }
__device__ __forceinline__ u16 f2bf(float f){ union{float f; u32 i;} x; x.f=f; u32 r = x.i + 0x7FFFu + ((x.i>>16)&1u); return (u16)(r>>16); }

__device__ __forceinline__ float fexp2(float x){
#if __has_builtin(__builtin_amdgcn_exp2f)
    return __builtin_amdgcn_exp2f(x);
#else
    return exp2f(x);
#endif
}
__device__ __forceinline__ float frcp(float x){
#if __has_builtin(__builtin_amdgcn_rcpf)
    return __builtin_amdgcn_rcpf(x);
#else
    return 1.0f/x;
#endif
}
#define LOG2E 1.442695041f

// ---------------- dtype detector (f32 vs bf16 device buffers) ----------------
__global__ void k_detect(const u16* __restrict__ x, int* flagp){
    __shared__ int cnt;
    if(threadIdx.x == 0) cnt = 0;
    __syncthreads();
    int c = 0;
    for(int i = threadIdx.x; i < 2048; i += 256){
        int e = (x[i] >> 7) & 0xFF;
        if(e >= 0x90) c++;
    }
    atomicAdd(&cnt, c);
    __syncthreads();
    if(threadIdx.x == 0) flagp[0] = (cnt > 64) ? 1 : 0;   // 1 = f32, 0 = bf16
}

// canonical f32 table offsets
#define CX    0
#define CW1   800000
#define CB1   800512
#define CW2   800576
#define CB2   804672
#define CEMB  804736
#define CWIH  808832
#define CWHH  821120
#define CBIH  833408
#define CBHH  833600
#define CL1W  833792
#define CL1B  841984
#define CLTW  842048
#define CLTB  850240
#define CLFW  850304
#define CLFB  850560
#define CTOT  850562

__device__ __forceinline__ float ldany(const void* p, int i, int fl){
    return fl ? ((const float*)p)[i] : bf2f(((const u16*)p)[i]);
}

__global__ void k_convert(const int* __restrict__ flagp,
                          const void* x, const void* w1, const void* b1, const void* w2,
                          const void* b2, const void* emb, const void* wih, const void* whh,
                          const void* bih, const void* bhh, const void* l1w, const void* l1b,
                          const void* ltw, const void* ltb, const void* lfw, const void* lfb,
                          float* __restrict__ canon){
    int i = blockIdx.x*256 + threadIdx.x;
    if(i >= CTOT) return;
    int fl = *flagp;
    const void* p; int off;
    if     (i < CW1 ){ p = x;   off = i;        }
    else if(i < CB1 ){ p = w1;  off = i - CW1;  }
    else if(i < CW2 ){ p = b1;  off = i - CB1;  }
    else if(i < CB2 ){ p = w2;  off = i - CW2;  }
    else if(i < CEMB){ p = b2;  off = i - CB2;  }
    else if(i < CWIH){ p = emb; off = i - CEMB; }
    else if(i < CWHH){ p = wih; off = i - CWIH; }
    else if(i < CBIH){ p = whh; off = i - CWHH; }
    else if(i < CBHH){ p = bih; off = i - CBIH; }
    else if(i < CL1W){ p = bhh; off = i - CBHH; }
    else if(i < CL1B){ p = l1w; off = i - CL1W; }
    else if(i < CLTW){ p = l1b; off = i - CL1B; }
    else if(i < CLTB){ p = ltw; off = i - CLTW; }
    else if(i < CLFW){ p = ltb; off = i - CLTB; }
    else if(i < CLFB){ p = lfw; off = i - CLFW; }
    else             { p = lfb; off = i - CLFB; }
    float v = ldany(p, off, fl);
    canon[i] = (v == v && fabsf(v) < 1e30f) ? v : 0.f;
}

// ---------------- CSR build: histogram -> scan -> fill (el, dl, eid) ----------------
__global__ void k_hist(const int* __restrict__ ei, int* __restrict__ deg){
    int e = blockIdx.x*256 + threadIdx.x;
    if(e < N_EDGES) atomicAdd(&deg[ei[N_EDGES + e]], 1);
}
__global__ void k_scan1(const int* __restrict__ deg, int* __restrict__ rowptr,
                        int* __restrict__ bsum){
    __shared__ int sh[256];
    int tid = threadIdx.x;
    int i = blockIdx.x*256 + tid;
    int v = (i < N_NODES) ? deg[i] : 0;
    sh[tid] = v;
    __syncthreads();
    for(int off = 1; off < 256; off <<= 1){
        int t = (tid >= off) ? sh[tid - off] : 0;
        __syncthreads();
        sh[tid] += t;
        __syncthreads();
    }
    if(i < N_NODES) rowptr[i] = sh[tid] - v;
    if(tid == 255) bsum[blockIdx.x] = sh[255];
}
__global__ void k_scan2(int* __restrict__ bsum){
    __shared__ int sh[512];
    int tid = threadIdx.x;
    int v = (tid < NBLK) ? bsum[tid] : 0;
    sh[tid] = v;
    __syncthreads();
    for(int off = 1; off < 512; off <<= 1){
        int t = (tid >= off) ? sh[tid - off] : 0;
        __syncthreads();
        sh[tid] += t;
        __syncthreads();
    }
    if(tid < NBLK) bsum[tid] = sh[tid] - v;
}
__global__ void k_scan3(const int* __restrict__ deg, const int* __restrict__ bsum,
                        int* __restrict__ rowptr, int* __restrict__ cursor,
                        float* __restrict__ dinv){
    int i = blockIdx.x*256 + threadIdx.x;
    if(i < N_NODES){
        int r = rowptr[i] + bsum[i >> 8];
        rowptr[i] = r;
        cursor[i] = r;
        dinv[i] = rsqrtf((float)deg[i] + 1.0f);   // +1 self loop
    }
    if(i == 0) rowptr[N_NODES] = N_EDGES;
}
__global__ void k_fill(const int* __restrict__ ei, int* __restrict__ cursor,
                       int* __restrict__ el, int* __restrict__ dl, int* __restrict__ eid){
    int e = blockIdx.x*256 + threadIdx.x;
    if(e < N_EDGES){
        int s = ei[e], d = ei[N_EDGES + e];
        int pos = atomicAdd(&cursor[d], 1);
        el[pos] = s;
        dl[pos] = d;
        eid[pos] = e;
    }
}

// ---------------- conv1: src = bf16((x @ W1) * dinv) ----------------
__global__ void k_t1s(const float* __restrict__ cx, const float* __restrict__ cw1,
                      const float* __restrict__ dinv, u16* __restrict__ src){
    __shared__ float w[512];
    int t = threadIdx.x;
    w[t]       = cw1[t];
    w[t + 256] = cw1[t + 256];
    __syncthreads();
    int i = blockIdx.x*256 + t;      // grid exactly N*64/256
    int n = i >> 6, f = i & 63;
    const float* xr = cx + n*8;
    float acc = 0.f;
    #pragma unroll
    for(int k = 0; k < 8; k++) acc += xr[k] * w[k*64 + f];
    src[i] = f2bf(acc * dinv[n]);
}

// ---------------- fused gather + epilogue (bf16 src rows, strided bf16 out) ----------------
__global__ __launch_bounds__(256)
void k_gather_ep(const int* __restrict__ rowptr, const int* __restrict__ el,
                 const u16* __restrict__ src, const float* __restrict__ dinv,
                 const float* __restrict__ b, u16* __restrict__ h, int ostride){
    int gid = blockIdx.x*256 + threadIdx.x;   // grid exactly N*64/256
    int node = gid >> 6, lane = gid & 63;
    int beg = rowptr[node], end = rowptr[node + 1];
    float acc = bf2f(src[node*64 + lane]);    // self loop (pre-scaled by dinv[src])
    int i = beg;
    for(; i + 4 <= end; i += 4){
        int s0 = el[i], s1 = el[i+1], s2 = el[i+2], s3 = el[i+3];
        float a0 = bf2f(src[s0*64 + lane]);
        float a1 = bf2f(src[s1*64 + lane]);
        float a2 = bf2f(src[s2*64 + lane]);
        float a3 = bf2f(src[s3*64 + lane]);
        acc += a0; acc += a1; acc += a2; acc += a3;
    }
    for(; i < end; i++) acc += bf2f(src[el[i]*64 + lane]);
    h[node*ostride + lane] = f2bf(fmaxf(dinv[node]*acc + b[lane], 0.f));
}

// ---------------- pack B matrix (f32 canon -> bf16 MFMA fragment order) ----------------
__global__ void k_packb(const float* __restrict__ src, u16* __restrict__ dst,
                        int K, int N, int ldk, int ldn){
    int i = blockIdx.x*256 + threadIdx.x;
    if(i >= K*N) return;
    int k = i / N, n = i % N;
    int kt = k >> 5, kk = k & 31, q = kk >> 3, j = kk & 7;
    int nt = n >> 4, nn = n & 15;
    int KT = K >> 5;
    dst[(((nt*KT + kt)*64) + (q*16 + nn))*8 + j] = f2bf(src[k*ldk + n*ldn]);
}

// ---------------- gi table (b_hh folded for r,z) ----------------
__global__ void k_gitab(const float* __restrict__ emb, const float* __restrict__ wih,
                        const float* __restrict__ bih, const float* __restrict__ bhh,
                        float* __restrict__ giT){
    int i = blockIdx.x*256 + threadIdx.x;
    if(i >= 64*192) return;
    int v = i / 192, g = i % 192;
    float acc = bih[g] + ((g < 128) ? bhh[g] : 0.0f);
    const float* wr = wih + g*64;
    const float* er = emb + v*64;
    for(int f = 0; f < 64; f++) acc += wr[f] * er[f];
    giT[i] = acc;
}

// ---------------- conv2 GEMM: src = bf16((h1 @ W2) * dinv) ----------------
__global__ __launch_bounds__(256, 4)
void k_conv2(const u16* __restrict__ h, const u16* __restrict__ w2p,
             const float* __restrict__ dinv, u16* __restrict__ src){
    int wv = threadIdx.x >> 6, lane = threadIdx.x & 63;
    int g = blockIdx.x*4 + wv;
    if(g >= N_NODES/16) return;
    int q = lane >> 4, m = lane & 15, col = m;
    bshort8 a0 = *(const bshort8*)(h + (g*16 + m)*64 + q*8);
    bshort8 a1 = *(const bshort8*)(h + (g*16 + m)*64 + 32 + q*8);
    f32x4 acc[4];
    #pragma unroll
    for(int nt = 0; nt < 4; nt++){
        f32x4 c = {0.f,0.f,0.f,0.f};
        c = __builtin_amdgcn_mfma_f32_16x16x32_bf16(a0, *(const bshort8*)(w2p + ((nt*2+0)*64 + lane)*8), c, 0,0,0);
        c = __builtin_amdgcn_mfma_f32_16x16x32_bf16(a1, *(const bshort8*)(w2p + ((nt*2+1)*64 + lane)*8), c, 0,0,0);
        acc[nt] = c;
    }
    #pragma unroll
    for(int nt = 0; nt < 4; nt++)
        #pragma unroll
        for(int r = 0; r < 4; r++){
            int node = g*16 + q*4 + r;
            src[node*64 + nt*16 + col] = f2bf(acc[nt][r] * dinv[node]);
        }
}

// ---------------- GRU: wave per 16 nodes; Whh in LDS; strided output into nodef ----------------
__global__ __launch_bounds__(256, 3)
void k_gru(const int* __restrict__ xt, const u16* __restrict__ whhp,
           const float* __restrict__ giT, const float* __restrict__ bhh,
           u16* __restrict__ txt){   // txt = nodef + 64, stride 128
    __shared__ __align__(16) u16 wsh[12288];
    __shared__ __align__(16) float hsh[4][16][68];
    int tid = threadIdx.x;
    {
        const uint4* s = (const uint4*)whhp;
        uint4* d = (uint4*)wsh;
        #pragma unroll
        for(int i = 0; i < 6; i++) d[tid + 256*i] = s[tid + 256*i];
    }
    __syncthreads();

    int wv = tid >> 6, lane = tid & 63;
    int q = lane >> 4, m = lane & 15, col = m;
    int g = blockIdx.x*4 + wv;
    bool active = g < (N_NODES/16);
    int nb = active ? g*16 : 0;

    float bhhn[4];
    #pragma unroll
    for(int t = 0; t < 4; t++) bhhn[t] = bhh[128 + t*16 + col];

    const bshort8* wl = (const bshort8*)wsh;
    float* hp = &hsh[wv][m][0];

    float hc[4][4];
    #pragma unroll
    for(int t = 0; t < 4; t++)
        #pragma unroll
        for(int r = 0; r < 4; r++) hc[t][r] = 0.f;

    for(int s = 0; s < 10; s++){
        #pragma unroll
        for(int t = 0; t < 4; t++)
            #pragma unroll
            for(int r = 0; r < 4; r++)
                hsh[wv][q*4 + r][t*16 + col] = hc[t][r];

        asm volatile("" ::: "memory");
        float4 x0 = *(float4*)(hp + q*8);
        float4 x1 = *(float4*)(hp + q*8 + 4);
        float4 x2 = *(float4*)(hp + 32 + q*8);
        float4 x3 = *(float4*)(hp + 32 + q*8 + 4);
        u32 aw[8];
        aw[0] = (u32)f2bf(x0.x) | ((u32)f2bf(x0.y) << 16);
        aw[1] = (u32)f2bf(x0.z) | ((u32)f2bf(x0.w) << 16);
        aw[2] = (u32)f2bf(x1.x) | ((u32)f2bf(x1.y) << 16);
        aw[3] = (u32)f2bf(x1.z) | ((u32)f2bf(x1.w) << 16);
        aw[4] = (u32)f2bf(x2.x) | ((u32)f2bf(x2.y) << 16);
        aw[5] = (u32)f2bf(x2.z) | ((u32)f2bf(x2.w) << 16);
        aw[6] = (u32)f2bf(x3.x) | ((u32)f2bf(x3.y) << 16);
        aw[7] = (u32)f2bf(x3.z) | ((u32)f2bf(x3.w) << 16);
        bshort8 a0 = *(bshort8*)&aw[0];
        bshort8 a1 = *(bshort8*)&aw[4];

        int tok[4];
        #pragma unroll
        for(int r = 0; r < 4; r++) tok[r] = xt[(nb + q*4 + r)*10 + s] & 63;

        f32x4 acc[12];
        #pragma unroll
        for(int nt = 0; nt < 12; nt++){
            f32x4 c = {0.f,0.f,0.f,0.f};
            c = __builtin_amdgcn_mfma_f32_16x16x32_bf16(a0, wl[(nt*2+0)*64 + lane], c, 0,0,0);
            c = __builtin_amdgcn_mfma_f32_16x16x32_bf16(a1, wl[(nt*2+1)*64 + lane], c, 0,0,0);
            acc[nt] = c;
        }

        #pragma unroll
        for(int r = 0; r < 4; r++){
            const float* gp = giT + tok[r]*192 + col;
            #pragma unroll
            for(int t = 0; t < 4; t++){
                float gir = gp[t*16], giz = gp[64 + t*16], gin = gp[128 + t*16];
                float rr = frcp(1.0f + fexp2(-LOG2E*(gir + acc[t][r])));
                float zz = frcp(1.0f + fexp2(-LOG2E*(giz + acc[4+t][r])));
                float narg = gin + rr*(acc[8+t][r] + bhhn[t]);
                float e2 = fexp2(2.0f*LOG2E*narg);
                float nn = 1.0f - 2.0f*frcp(e2 + 1.0f);
                hc[t][r] = nn + zz*(hc[t][r] - nn);
            }
        }
        asm volatile("" ::: "memory");
    }
    if(active){
        #pragma unroll
        for(int t = 0; t < 4; t++)
            #pragma unroll
            for(int r = 0; r < 4; r++)
                txt[(size_t)(nb + q*4 + r)*128 + t*16 + col] = f2bf(hc[t][r]);
    }
}

// ---------------- pair precompute: u1,v1 (bias-folded) in-place into nodef; u2,v2 -> udst ----
// u1 = W1a·h2 + b1, u2 = W1b·h2, v1 = Wta·txt + bt, v2 = Wtb·txt.
// In-place safe: every store's data depends (via MFMA) on all of this wave's loads.
__global__ __launch_bounds__(256, 3)
void k_pairpre(u16* nodef, u32* __restrict__ udst,
               const u16* __restrict__ w1a, const u16* __restrict__ w1b,
               const u16* __restrict__ wta, const u16* __restrict__ wtb,
               const float* __restrict__ b1, const float* __restrict__ bt){
    int wv = threadIdx.x >> 6, lane = threadIdx.x & 63;
    int g = blockIdx.x*4 + wv;
    if(g >= N_NODES/16) return;
    int q = lane >> 4, m = lane & 15, col = m;
    const u16* row = nodef + (size_t)(g*16 + m)*128;
    bshort8 ah0 = *(const bshort8*)(row);
    bshort8 ah1 = *(const bshort8*)(row + 32 - q*8 + q*8 + 32);   // placeholder removed below
    ah0 = *(const bshort8*)(row + q*8);
    ah1 = *(const bshort8*)(row + 32 + q*8);
    bshort8 at0 = *(const bshort8*)(row + 64 + q*8);
    bshort8 at1 = *(const bshort8*)(row + 96 + q*8);
    f32x4 u1[4], u2[4], v1[4], v2[4];
    #pragma unroll
    for(int nt = 0; nt < 4; nt++){
        f32x4 c;
        c = (f32x4){0.f,0.f,0.f,0.f};
        c = __builtin_amdgcn_mfma_f32_16x16x32_bf16(ah0, *(const bshort8*)(w1a + ((nt*2+0)*64 + lane)*8), c, 0,0,0);
        c = __builtin_amdgcn_mfma_f32_16x16x32_bf16(ah1, *(const bshort8*)(w1a + ((nt*2+1)*64 + lane)*8), c, 0,0,0);
        u1[nt] = c;
        c = (f32x4){0.f,0.f,0.f,0.f};
        c = __builtin_amdgcn_mfma_f32_16x16x32_bf16(ah0, *(const bshort8*)(w1b + ((nt*2+0)*64 + lane)*8), c, 0,0,0);
        c = __builtin_amdgcn_mfma_f32_16x16x32_bf16(ah1, *(const bshort8*)(w1b + ((nt*2+1)*64 + lane)*8), c, 0,0,0);
        u2[nt] = c;
        c = (f32x4){0.f,0.f,0.f,0.f};
        c = __builtin_amdgcn_mfma_f32_16x16x32_bf16(at0, *(const bshort8*)(wta + ((nt*2+0)*64 + lane)*8), c, 0,0,0);
        c = __builtin_amdgcn_mfma_f32_16x16x32_bf16(at1, *(const bshort8*)(wta + ((nt*2+1)*64 + lane)*8), c, 0,0,0);
        v1[nt] = c;
        c = (f32x4){0.f,0.f,0.f,0.f};
        c = __builtin_amdgcn_mfma_f32_16x16x32_bf16(at0, *(const bshort8*)(wtb + ((nt*2+0)*64 + lane)*8), c, 0,0,0);
        c = __builtin_amdgcn_mfma_f32_16x16x32_bf16(at1, *(const bshort8*)(wtb + ((nt*2+1)*64 + lane)*8), c, 0,0,0);
        v2[nt] = c;
    }
    u32* usrc = (u32*)nodef;
    #pragma unroll
    for(int nt = 0; nt < 4; nt++){
        int f = nt*16 + col;
        float b1f = b1[f], btf = bt[f];
        #pragma unroll
        for(int r = 0; r < 4; r++){
            int node = g*16 + q*4 + r;
            u32 pa = (u32)f2bf(u1[nt][r] + b1f) | ((u32)f2bf(v1[nt][r] + btf) << 16);
            u32 pb = (u32)f2bf(u2[nt][r]) | ((u32)f2bf(v2[nt][r]) << 16);
            usrc[(size_t)node*64 + f] = pa;
            udst[(size_t)node*64 + f] = pb;
        }
    }
}

// ---------------- edge kernel: 4 edges/wave, 16 lanes/edge, 4 feats/lane ----------------
// logit_c = sum_f relu(u1[s][f]+u2[d][f])*wf[c][f] + relu(v1[s][f]+v2[d][f])*wf[c][64+f] + bf[c]
__global__ __launch_bounds__(256, 6)
void k_edge2(const int* __restrict__ el, const int* __restrict__ dl, const int* __restrict__ eid,
             const u32* __restrict__ usrc, const u32* __restrict__ udst,
             const float* __restrict__ wfin, const float* __restrict__ bfin,
             const int* __restrict__ flagp, void* __restrict__ out){
    int tid = threadIdx.x;
    int lane = tid & 63;
    int q = lane >> 4, f0 = lane & 15;
    int wid = (blockIdx.x*256 + tid) >> 6;
    int nwv = (gridDim.x*256) >> 6;
    int fl = *flagp;

    float wp0[4], wp1[4], wt0[4], wt1[4];
    #pragma unroll
    for(int t = 0; t < 4; t++){
        int f = f0 + 16*t;
        wp0[t] = wfin[f];        wt0[t] = wfin[64 + f];
        wp1[t] = wfin[128 + f];  wt1[t] = wfin[192 + f];
    }
    float bf0 = bfin[0], bf1 = bfin[1];

    for(int grp = wid; grp < N_EDGES/4; grp += nwv){
        int e = grp*4 + q;
        int s = el[e], d = dl[e];
        const u32* up = usrc + (size_t)s*64 + f0;
        const u32* vp = udst + (size_t)d*64 + f0;
        u32 us[4], ud[4];
        #pragma unroll
        for(int t = 0; t < 4; t++){ us[t] = up[16*t]; ud[t] = vp[16*t]; }
        float s0 = 0.f, s1 = 0.f;
        #pragma unroll
        for(int t = 0; t < 4; t++){
            float u1 = __uint_as_float(us[t] << 16);
            float v1 = __uint_as_float(us[t] & 0xffff0000u);
            float u2 = __uint_as_float(ud[t] << 16);
            float v2 = __uint_as_float(ud[t] & 0xffff0000u);
            float xp = fmaxf(u1 + u2, 0.f);
            float xq = fmaxf(v1 + v2, 0.f);
            s0 += xp*wp0[t] + xq*wt0[t];
            s1 += xp*wp1[t] + xq*wt1[t];
        }
        #pragma unroll
        for(int msk = 1; msk < 16; msk <<= 1){
            s0 += __shfl_xor(s0, msk, 64);
            s1 += __shfl_xor(s1, msk, 64);
        }
        if(f0 == 0){
            float a = s0 + bf0, b = s1 + bf1;
            float mx = fmaxf(a, b);
            float lse = mx + __logf(__expf(a - mx) + __expf(b - mx));
            int oi = eid[e];
            if(fl){
                float2 v; v.x = a - lse; v.y = b - lse;
                ((float2*)out)[oi] = v;
            }else{
                u32 pack = (u32)f2bf(a - lse) | ((u32)f2bf(b - lse) << 16);
                ((u32*)out)[oi] = pack;
            }
        }
    }
}

// ---------------- workspace layout (~68.3 MB; R3-proven scale) ----------------
static const size_t O_FLAG   = 0;
static const size_t O_CANON  = 4096;       // 3,402,248
static const size_t O_GIT    = 3407872;    // 49,152
static const size_t O_W2P    = 3457024;    // 8,192
static const size_t O_WHHP   = 3465216;    // 24,576
static const size_t O_L1PA   = 3489792;    // 8,192
static const size_t O_L1PB   = 3497984;    // 8,192
static const size_t O_LTPA   = 3506176;    // 8,192
static const size_t O_LTPB   = 3514368;    // 8,192
static const size_t O_DINV   = 3522560;    // 400,000
static const size_t O_DEG    = 3922560;    // 400,000
static const size_t O_ROWPTR = 4322560;    // 400,128
static const size_t O_CURSOR = 4722688;    // 400,000
static const size_t O_BSUM   = 5122688;    // 2,048
static const size_t O_EL     = 5124736;    // 4,000,000
static const size_t O_DL     = 9125888;    // 4,000,000
static const size_t O_EID    = 13125888;   // 4,000,000
static const size_t O_SRC    = 17125888;   // N*64 bf16 = 12,800,000 (dead after gather_ep2)
static const size_t O_H1     = 29925888;   // N*64 bf16 = 12,800,000 (dead after conv2)
static const size_t O_UDST   = 17125888;   // N*128 bf16 = 25,600,000 (overlays SRC+H1, written in pairpre)
static const size_t O_NODEF  = 42725888;   // N*128 bf16 = 25,600,000 (h2 + txt; pairpre rewrites in-place as usrc)
// end = 68,325,888

extern "C" void kernel_launch(void* const* d_in, const int* in_sizes, int n_in,
                              void* d_out, int out_size, void* d_ws, size_t ws_size,
                              hipStream_t stream){
    const void* x    = d_in[0];
    const int*  ei   = (const int*)d_in[1];
    const int*  xt   = (const int*)d_in[2];

    char* ws = (char*)d_ws;
    int*   flagp  = (int*)(ws + O_FLAG);
    float* canon  = (float*)(ws + O_CANON);
    float* giT    = (float*)(ws + O_GIT);
    u16*   w2p    = (u16*)(ws + O_W2P);
    u16*   whhp   = (u16*)(ws + O_WHHP);
    u16*   l1pa   = (u16*)(ws + O_L1PA);
    u16*   l1pb   = (u16*)(ws + O_L1PB);
    u16*   ltpa   = (u16*)(ws + O_LTPA);
    u16*   ltpb   = (u16*)(ws + O_LTPB);
    float* dinv   = (float*)(ws + O_DINV);
    int*   deg    = (int*)(ws + O_DEG);
    int*   rowptr = (int*)(ws + O_ROWPTR);
    int*   cursor = (int*)(ws + O_CURSOR);
    int*   bsum   = (int*)(ws + O_BSUM);
    int*   el     = (int*)(ws + O_EL);
    int*   dl     = (int*)(ws + O_DL);
    int*   eid    = (int*)(ws + O_EID);
    u16*   src    = (u16*)(ws + O_SRC);
    u16*   hbuf1  = (u16*)(ws + O_H1);
    u32*   udst   = (u32*)(ws + O_UDST);
    u16*   nodef  = (u16*)(ws + O_NODEF);

    // dtype detect + canonicalize
    k_detect<<<1, 256, 0, stream>>>((const u16*)x, flagp);
    k_convert<<<(CTOT+255)/256, 256, 0, stream>>>(flagp,
        x, d_in[3], d_in[4], d_in[5], d_in[6], d_in[7], d_in[8], d_in[9],
        d_in[10], d_in[11], d_in[12], d_in[13], d_in[14], d_in[15], d_in[16], d_in[17],
        canon);

    const float* cx   = canon + CX;
    const float* cw1  = canon + CW1;
    const float* cb1  = canon + CB1;
    const float* cw2  = canon + CW2;
    const float* cb2  = canon + CB2;
    const float* cemb = canon + CEMB;
    const float* cwih = canon + CWIH;
    const float* cwhh = canon + CWHH;
    const float* cbih = canon + CBIH;
    const float* cbhh = canon + CBHH;
    const float* cl1w = canon + CL1W;
    const float* cl1b = canon + CL1B;
    const float* cltw = canon + CLTW;
    const float* cltb = canon + CLTB;
    const float* clfw = canon + CLFW;
    const float* clfb = canon + CLFB;

    // CSR build (once; reused by both GCN layers and the edge kernel)
    hipMemsetAsync(deg, 0, (size_t)N_NODES*4, stream);
    k_hist <<<(N_EDGES+255)/256, 256, 0, stream>>>(ei, deg);
    k_scan1<<<NBLK, 256, 0, stream>>>(deg, rowptr, bsum);
    k_scan2<<<1, 512, 0, stream>>>(bsum);
    k_scan3<<<NBLK, 256, 0, stream>>>(deg, bsum, rowptr, cursor, dinv);
    k_fill <<<(N_EDGES+255)/256, 256, 0, stream>>>(ei, cursor, el, dl, eid);

    // weight packing + gi table (tiny)
    k_packb<<<(64*64+255)/256, 256, 0, stream>>>(cw2, w2p, 64, 64, 64, 1);
    k_packb<<<(64*192+255)/256, 256, 0, stream>>>(cwhh, whhp, 64, 192, 1, 64);
    // lin1: W1a = cl1w[:, :64] -> B[k][n] = cl1w[n*128 + k]; W1b = cl1w[:, 64:]
    k_packb<<<(64*64+255)/256, 256, 0, stream>>>(cl1w,      l1pa, 64, 64, 1, 128);
    k_packb<<<(64*64+255)/256, 256, 0, stream>>>(cl1w + 64, l1pb, 64, 64, 1, 128);
    k_packb<<<(64*64+255)/256, 256, 0, stream>>>(cltw,      ltpa, 64, 64, 1, 128);
    k_packb<<<(64*64+255)/256, 256, 0, stream>>>(cltw + 64, ltpb, 64, 64, 1, 128);
    k_gitab<<<(64*192+255)/256, 256, 0, stream>>>(cemb, cwih, cbih, cbhh, giT);

    // GCN layer 1 (src -> h1, stride 64)
    k_t1s<<<N_NODES*64/256, 256, 0, stream>>>(cx, cw1, dinv, src);
    k_gather_ep<<<N_NODES*64/256, 256, 0, stream>>>(rowptr, el, src, dinv, cb1, hbuf1, 64);

    // GCN layer 2 (h1 -> src -> nodef[+0], stride 128)
    k_conv2<<<(N_NODES/16 + 3)/4, 256, 0, stream>>>(hbuf1, w2p, dinv, src);
    k_gather_ep<<<N_NODES*64/256, 256, 0, stream>>>(rowptr, el, src, dinv, cb2, nodef, 128);

    // GRU over text -> nodef[+64], stride 128
    k_gru<<<(N_NODES/16 + 3)/4, 256, 0, stream>>>(xt, whhp, giT, cbhh, nodef + 64);

    // per-node pair precompute (nodef -> usrc in-place, udst)
    k_pairpre<<<(N_NODES/16 + 3)/4, 256, 0, stream>>>(nodef, udst, l1pa, l1pb, ltpa, ltpb,
                                                      cl1b, cltb);

    // edge logits + log_softmax (CSR order, scatter by eid)
    k_edge2<<<4096, 256, 0, stream>>>(el, dl, eid, (const u32*)nodef, udst,
                                      clfw, clfb, flagp, d_out);
}

// Round 11
// 495.199 us; speedup vs baseline: 1.5150x; 1.0045x over previous
//
#include <hip/hip_runtime.h>
#include <stdint.h>

#define N_NODES 100000
#define N_EDGES 1000000
#define NBLK 391   // ceil(N_NODES/256)

typedef unsigned short u16;
typedef unsigned int u32;
typedef __attribute__((ext_vector_type(8))) short bshort8;
typedef __attribute__((ext_vector_type(4))) float f32x4;

__device__ __forceinline__ float bf2f(u16 u){ union{float f; u32 i;} x; x.i=((u32)u)<<16; return x.f; }
__device__ __forceinline__ u16 f2bf(float f){ union{float f; u32 i;} x; x.f=f; u32 r = x.i + 0x7FFFu + ((x.i>>16)&1u); return (u16)(r>>16); }

__device__ __forceinline__ float fexp2(float x){
#if __has_builtin(__builtin_amdgcn_exp2f)
    return __builtin_amdgcn_exp2f(x);
#else
    return exp2f(x);
#endif
}
__device__ __forceinline__ float frcp(float x){
#if __has_builtin(__builtin_amdgcn_rcpf)
    return __builtin_amdgcn_rcpf(x);
#else
    return 1.0f/x;
#endif
}
#define LOG2E 1.442695041f

// ---------------- dtype detector (f32 vs bf16 device buffers) ----------------
__global__ void k_detect(const u16* __restrict__ x, int* flagp){
    __shared__ int cnt;
    if(threadIdx.x == 0) cnt = 0;
    __syncthreads();
    int c = 0;
    for(int i = threadIdx.x; i < 2048; i += 256){
        int e = (x[i] >> 7) & 0xFF;
        if(e >= 0x90) c++;
    }
    atomicAdd(&cnt, c);
    __syncthreads();
    if(threadIdx.x == 0) flagp[0] = (cnt > 64) ? 1 : 0;   // 1 = f32, 0 = bf16
}

// canonical f32 table offsets
#define CX    0
#define CW1   800000
#define CB1   800512
#define CW2   800576
#define CB2   804672
#define CEMB  804736
#define CWIH  808832
#define CWHH  821120
#define CBIH  833408
#define CBHH  833600
#define CL1W  833792
#define CL1B  841984
#define CLTW  842048
#define CLTB  850240
#define CLFW  850304
#define CLFB  850560
#define CTOT  850562

__device__ __forceinline__ float ldany(const void* p, int i, int fl){
    return fl ? ((const float*)p)[i] : bf2f(((const u16*)p)[i]);
}

__global__ void k_convert(const int* __restrict__ flagp,
                          const void* x, const void* w1, const void* b1, const void* w2,
                          const void* b2, const void* emb, const void* wih, const void* whh,
                          const void* bih, const void* bhh, const void* l1w, const void* l1b,
                          const void* ltw, const void* ltb, const void* lfw, const void* lfb,
                          float* __restrict__ canon){
    int i = blockIdx.x*256 + threadIdx.x;
    if(i >= CTOT) return;
    int fl = *flagp;
    const void* p; int off;
    if     (i < CW1 ){ p = x;   off = i;        }
    else if(i < CB1 ){ p = w1;  off = i - CW1;  }
    else if(i < CW2 ){ p = b1;  off = i - CB1;  }
    else if(i < CB2 ){ p = w2;  off = i - CW2;  }
    else if(i < CEMB){ p = b2;  off = i - CB2;  }
    else if(i < CWIH){ p = emb; off = i - CEMB; }
    else if(i < CWHH){ p = wih; off = i - CWIH; }
    else if(i < CBIH){ p = whh; off = i - CWHH; }
    else if(i < CBHH){ p = bih; off = i - CBIH; }
    else if(i < CL1W){ p = bhh; off = i - CBHH; }
    else if(i < CL1B){ p = l1w; off = i - CL1W; }
    else if(i < CLTW){ p = l1b; off = i - CL1B; }
    else if(i < CLTB){ p = ltw; off = i - CLTW; }
    else if(i < CLFW){ p = ltb; off = i - CLTB; }
    else if(i < CLFB){ p = lfw; off = i - CLFW; }
    else             { p = lfb; off = i - CLFB; }
    float v = ldany(p, off, fl);
    canon[i] = (v == v && fabsf(v) < 1e30f) ? v : 0.f;
}

// ---------------- CSR build: histogram -> scan -> fill (el, dl, eid) ----------------
__global__ void k_hist(const int* __restrict__ ei, int* __restrict__ deg){
    int e = blockIdx.x*256 + threadIdx.x;
    if(e < N_EDGES) atomicAdd(&deg[ei[N_EDGES + e]], 1);
}
__global__ void k_scan1(const int* __restrict__ deg, int* __restrict__ rowptr,
                        int* __restrict__ bsum){
    __shared__ int sh[256];
    int tid = threadIdx.x;
    int i = blockIdx.x*256 + tid;
    int v = (i < N_NODES) ? deg[i] : 0;
    sh[tid] = v;
    __syncthreads();
    for(int off = 1; off < 256; off <<= 1){
        int t = (tid >= off) ? sh[tid - off] : 0;
        __syncthreads();
        sh[tid] += t;
        __syncthreads();
    }
    if(i < N_NODES) rowptr[i] = sh[tid] - v;
    if(tid == 255) bsum[blockIdx.x] = sh[255];
}
__global__ void k_scan2(int* __restrict__ bsum){
    __shared__ int sh[512];
    int tid = threadIdx.x;
    int v = (tid < NBLK) ? bsum[tid] : 0;
    sh[tid] = v;
    __syncthreads();
    for(int off = 1; off < 512; off <<= 1){
        int t = (tid >= off) ? sh[tid - off] : 0;
        __syncthreads();
        sh[tid] += t;
        __syncthreads();
    }
    if(tid < NBLK) bsum[tid] = sh[tid] - v;
}
__global__ void k_scan3(const int* __restrict__ deg, const int* __restrict__ bsum,
                        int* __restrict__ rowptr, int* __restrict__ cursor,
                        float* __restrict__ dinv){
    int i = blockIdx.x*256 + threadIdx.x;
    if(i < N_NODES){
        int r = rowptr[i] + bsum[i >> 8];
        rowptr[i] = r;
        cursor[i] = r;
        dinv[i] = rsqrtf((float)deg[i] + 1.0f);   // +1 self loop
    }
    if(i == 0) rowptr[N_NODES] = N_EDGES;
}
__global__ void k_fill(const int* __restrict__ ei, int* __restrict__ cursor,
                       int* __restrict__ el, int* __restrict__ dl, int* __restrict__ eid){
    int e = blockIdx.x*256 + threadIdx.x;
    if(e < N_EDGES){
        int s = ei[e], d = ei[N_EDGES + e];
        int pos = atomicAdd(&cursor[d], 1);
        el[pos] = s;
        dl[pos] = d;
        eid[pos] = e;
    }
}

// ---------------- conv1: src = bf16((x @ W1) * dinv) ----------------
__global__ void k_t1s(const float* __restrict__ cx, const float* __restrict__ cw1,
                      const float* __restrict__ dinv, u16* __restrict__ src){
    __shared__ float w[512];
    int t = threadIdx.x;
    w[t]       = cw1[t];
    w[t + 256] = cw1[t + 256];
    __syncthreads();
    int i = blockIdx.x*256 + t;      // grid exactly N*64/256
    int n = i >> 6, f = i & 63;
    const float* xr = cx + n*8;
    float acc = 0.f;
    #pragma unroll
    for(int k = 0; k < 8; k++) acc += xr[k] * w[k*64 + f];
    src[i] = f2bf(acc * dinv[n]);
}

// ---------------- fused gather + epilogue (bf16 src rows, strided bf16 out) ----------------
__global__ __launch_bounds__(256)
void k_gather_ep(const int* __restrict__ rowptr, const int* __restrict__ el,
                 const u16* __restrict__ src, const float* __restrict__ dinv,
                 const float* __restrict__ b, u16* __restrict__ h, int ostride){
    int gid = blockIdx.x*256 + threadIdx.x;   // grid exactly N*64/256
    int node = gid >> 6, lane = gid & 63;
    int beg = rowptr[node], end = rowptr[node + 1];
    float acc = bf2f(src[node*64 + lane]);    // self loop (pre-scaled by dinv[src])
    int i = beg;
    for(; i + 4 <= end; i += 4){
        int s0 = el[i], s1 = el[i+1], s2 = el[i+2], s3 = el[i+3];
        float a0 = bf2f(src[s0*64 + lane]);
        float a1 = bf2f(src[s1*64 + lane]);
        float a2 = bf2f(src[s2*64 + lane]);
        float a3 = bf2f(src[s3*64 + lane]);
        acc += a0; acc += a1; acc += a2; acc += a3;
    }
    for(; i < end; i++) acc += bf2f(src[el[i]*64 + lane]);
    h[node*ostride + lane] = f2bf(fmaxf(dinv[node]*acc + b[lane], 0.f));
}

// ---------------- pack B matrix (f32 canon -> bf16 MFMA fragment order) ----------------
__global__ void k_packb(const float* __restrict__ src, u16* __restrict__ dst,
                        int K, int N, int ldk, int ldn){
    int i = blockIdx.x*256 + threadIdx.x;
    if(i >= K*N) return;
    int k = i / N, n = i % N;
    int kt = k >> 5, kk = k & 31, q = kk >> 3, j = kk & 7;
    int nt = n >> 4, nn = n & 15;
    int KT = K >> 5;
    dst[(((nt*KT + kt)*64) + (q*16 + nn))*8 + j] = f2bf(src[k*ldk + n*ldn]);
}

// ---------------- gi table, transposed for float4 loads: giT[v][g3][col][t] ----------------
// g = g3*64 + t*16 + col;  b_hh folded for r,z groups (g3<2)
__global__ void k_gitab(const float* __restrict__ emb, const float* __restrict__ wih,
                        const float* __restrict__ bih, const float* __restrict__ bhh,
                        float* __restrict__ giT){
    int i = blockIdx.x*256 + threadIdx.x;
    if(i >= 64*192) return;
    int v = i / 192, g = i % 192;
    float acc = bih[g] + ((g < 128) ? bhh[g] : 0.0f);
    const float* wr = wih + g*64;
    const float* er = emb + v*64;
    for(int f = 0; f < 64; f++) acc += wr[f] * er[f];
    int g3 = g >> 6, rem = g & 63, t = rem >> 4, col = rem & 15;
    giT[(((size_t)v*3 + g3)*16 + col)*4 + t] = acc;
}

// ---------------- conv2 GEMM: src = bf16((h1 @ W2) * dinv) ----------------
__global__ __launch_bounds__(256, 4)
void k_conv2(const u16* __restrict__ h, const u16* __restrict__ w2p,
             const float* __restrict__ dinv, u16* __restrict__ src){
    int wv = threadIdx.x >> 6, lane = threadIdx.x & 63;
    int g = blockIdx.x*4 + wv;
    if(g >= N_NODES/16) return;
    int q = lane >> 4, m = lane & 15, col = m;
    bshort8 a0 = *(const bshort8*)(h + (g*16 + m)*64 + q*8);
    bshort8 a1 = *(const bshort8*)(h + (g*16 + m)*64 + 32 + q*8);
    f32x4 acc[4];
    #pragma unroll
    for(int nt = 0; nt < 4; nt++){
        f32x4 c = {0.f,0.f,0.f,0.f};
        c = __builtin_amdgcn_mfma_f32_16x16x32_bf16(a0, *(const bshort8*)(w2p + ((nt*2+0)*64 + lane)*8), c, 0,0,0);
        c = __builtin_amdgcn_mfma_f32_16x16x32_bf16(a1, *(const bshort8*)(w2p + ((nt*2+1)*64 + lane)*8), c, 0,0,0);
        acc[nt] = c;
    }
    #pragma unroll
    for(int nt = 0; nt < 4; nt++)
        #pragma unroll
        for(int r = 0; r < 4; r++){
            int node = g*16 + q*4 + r;
            src[node*64 + nt*16 + col] = f2bf(acc[nt][r] * dinv[node]);
        }
}

// ---------------- GRU: bf16 LDS h-tile (33.8 KB total), float4 gi loads, 4 blocks/CU ----------------
__global__ __launch_bounds__(256, 4)
void k_gru(const int* __restrict__ xt, const u16* __restrict__ whhp,
           const float* __restrict__ giT, const float* __restrict__ bhh,
           u16* __restrict__ txt){   // txt = nodef + 64, stride 128
    __shared__ __align__(16) u16 wsh[12288];        // 24 KB Whh frags
    __shared__ __align__(16) u16 hsh[4][16][72];    // bf16 h tile, row 144 B (16-B aligned)
    int tid = threadIdx.x;
    {
        const uint4* s = (const uint4*)whhp;
        uint4* d = (uint4*)wsh;
        #pragma unroll
        for(int i = 0; i < 6; i++) d[tid + 256*i] = s[tid + 256*i];
    }
    __syncthreads();

    int wv = tid >> 6, lane = tid & 63;
    int q = lane >> 4, m = lane & 15, col = m;
    int g = blockIdx.x*4 + wv;
    bool active = g < (N_NODES/16);
    int nb = active ? g*16 : 0;

    float bhhn[4];
    #pragma unroll
    for(int t = 0; t < 4; t++) bhhn[t] = bhh[128 + t*16 + col];

    const bshort8* wl = (const bshort8*)wsh;
    const u16* hp = &hsh[wv][m][0];

    float hc[4][4];
    #pragma unroll
    for(int t = 0; t < 4; t++)
        #pragma unroll
        for(int r = 0; r < 4; r++) hc[t][r] = 0.f;

    for(int s = 0; s < 10; s++){
        #pragma unroll
        for(int t = 0; t < 4; t++)
            #pragma unroll
            for(int r = 0; r < 4; r++)
                hsh[wv][q*4 + r][t*16 + col] = f2bf(hc[t][r]);

        asm volatile("" ::: "memory");
        bshort8 a0 = *(const bshort8*)(hp + q*8);
        bshort8 a1 = *(const bshort8*)(hp + 32 + q*8);

        int tok[4];
        #pragma unroll
        for(int r = 0; r < 4; r++) tok[r] = xt[(nb + q*4 + r)*10 + s] & 63;

        f32x4 acc[12];
        #pragma unroll
        for(int nt = 0; nt < 12; nt++){
            f32x4 c = {0.f,0.f,0.f,0.f};
            c = __builtin_amdgcn_mfma_f32_16x16x32_bf16(a0, wl[(nt*2+0)*64 + lane], c, 0,0,0);
            c = __builtin_amdgcn_mfma_f32_16x16x32_bf16(a1, wl[(nt*2+1)*64 + lane], c, 0,0,0);
            acc[nt] = c;
        }

        #pragma unroll
        for(int r = 0; r < 4; r++){
            const float4* gp = (const float4*)(giT + (size_t)tok[r]*192);
            float4 gr = gp[col];            // r-gates, t=0..3
            float4 gz = gp[16 + col];       // z-gates
            float4 gn = gp[32 + col];       // n-gates
            #pragma unroll
            for(int t = 0; t < 4; t++){
                float gir = ((const float*)&gr)[t];
                float giz = ((const float*)&gz)[t];
                float gin = ((const float*)&gn)[t];
                float rr = frcp(1.0f + fexp2(-LOG2E*(gir + acc[t][r])));
                float zz = frcp(1.0f + fexp2(-LOG2E*(giz + acc[4+t][r])));
                float narg = gin + rr*(acc[8+t][r] + bhhn[t]);
                float e2 = fexp2(2.0f*LOG2E*narg);
                float nn = 1.0f - 2.0f*frcp(e2 + 1.0f);
                hc[t][r] = nn + zz*(hc[t][r] - nn);
            }
        }
        asm volatile("" ::: "memory");
    }
    if(active){
        #pragma unroll
        for(int t = 0; t < 4; t++)
            #pragma unroll
            for(int r = 0; r < 4; r++)
                txt[(size_t)(nb + q*4 + r)*128 + t*16 + col] = f2bf(hc[t][r]);
    }
}

// ---------------- pair precompute: u1,v1 (bias-folded) in-place into nodef; u2,v2 -> udst ----
__global__ __launch_bounds__(256, 3)
void k_pairpre(u16* nodef, u32* __restrict__ udst,
               const u16* __restrict__ w1a, const u16* __restrict__ w1b,
               const u16* __restrict__ wta, const u16* __restrict__ wtb,
               const float* __restrict__ b1, const float* __restrict__ bt){
    int wv = threadIdx.x >> 6, lane = threadIdx.x & 63;
    int g = blockIdx.x*4 + wv;
    if(g >= N_NODES/16) return;
    int q = lane >> 4, m = lane & 15, col = m;
    const u16* row = nodef + (size_t)(g*16 + m)*128;
    bshort8 ah0 = *(const bshort8*)(row + q*8);
    bshort8 ah1 = *(const bshort8*)(row + 32 + q*8);
    bshort8 at0 = *(const bshort8*)(row + 64 + q*8);
    bshort8 at1 = *(const bshort8*)(row + 96 + q*8);
    f32x4 u1[4], u2[4], v1[4], v2[4];
    #pragma unroll
    for(int nt = 0; nt < 4; nt++){
        f32x4 c;
        c = (f32x4){0.f,0.f,0.f,0.f};
        c = __builtin_amdgcn_mfma_f32_16x16x32_bf16(ah0, *(const bshort8*)(w1a + ((nt*2+0)*64 + lane)*8), c, 0,0,0);
        c = __builtin_amdgcn_mfma_f32_16x16x32_bf16(ah1, *(const bshort8*)(w1a + ((nt*2+1)*64 + lane)*8), c, 0,0,0);
        u1[nt] = c;
        c = (f32x4){0.f,0.f,0.f,0.f};
        c = __builtin_amdgcn_mfma_f32_16x16x32_bf16(ah0, *(const bshort8*)(w1b + ((nt*2+0)*64 + lane)*8), c, 0,0,0);
        c = __builtin_amdgcn_mfma_f32_16x16x32_bf16(ah1, *(const bshort8*)(w1b + ((nt*2+1)*64 + lane)*8), c, 0,0,0);
        u2[nt] = c;
        c = (f32x4){0.f,0.f,0.f,0.f};
        c = __builtin_amdgcn_mfma_f32_16x16x32_bf16(at0, *(const bshort8*)(wta + ((nt*2+0)*64 + lane)*8), c, 0,0,0);
        c = __builtin_amdgcn_mfma_f32_16x16x32_bf16(at1, *(const bshort8*)(wta + ((nt*2+1)*64 + lane)*8), c, 0,0,0);
        v1[nt] = c;
        c = (f32x4){0.f,0.f,0.f,0.f};
        c = __builtin_amdgcn_mfma_f32_16x16x32_bf16(at0, *(const bshort8*)(wtb + ((nt*2+0)*64 + lane)*8), c, 0,0,0);
        c = __builtin_amdgcn_mfma_f32_16x16x32_bf16(at1, *(const bshort8*)(wtb + ((nt*2+1)*64 + lane)*8), c, 0,0,0);
        v2[nt] = c;
    }
    u32* usrc = (u32*)nodef;
    #pragma unroll
    for(int nt = 0; nt < 4; nt++){
        int f = nt*16 + col;
        float b1f = b1[f], btf = bt[f];
        #pragma unroll
        for(int r = 0; r < 4; r++){
            int node = g*16 + q*4 + r;
            u32 pa = (u32)f2bf(u1[nt][r] + b1f) | ((u32)f2bf(v1[nt][r] + btf) << 16);
            u32 pb = (u32)f2bf(u2[nt][r]) | ((u32)f2bf(v2[nt][r]) << 16);
            usrc[(size_t)node*64 + f] = pa;
            udst[(size_t)node*64 + f] = pb;
        }
    }
}

// ---------------- edge kernel: 4 edges/wave, 16 lanes/edge, 4 feats/lane ----------------
__global__ __launch_bounds__(256, 6)
void k_edge2(const int* __restrict__ el, const int* __restrict__ dl, const int* __restrict__ eid,
             const u32* __restrict__ usrc, const u32* __restrict__ udst,
             const float* __restrict__ wfin, const float* __restrict__ bfin,
             const int* __restrict__ flagp, void* __restrict__ out){
    int tid = threadIdx.x;
    int lane = tid & 63;
    int q = lane >> 4, f0 = lane & 15;
    int wid = (blockIdx.x*256 + tid) >> 6;
    int nwv = (gridDim.x*256) >> 6;
    int fl = *flagp;

    float wp0[4], wp1[4], wt0[4], wt1[4];
    #pragma unroll
    for(int t = 0; t < 4; t++){
        int f = f0 + 16*t;
        wp0[t] = wfin[f];        wt0[t] = wfin[64 + f];
        wp1[t] = wfin[128 + f];  wt1[t] = wfin[192 + f];
    }
    float bf0 = bfin[0], bf1 = bfin[1];

    for(int grp = wid; grp < N_EDGES/4; grp += nwv){
        int e = grp*4 + q;
        int s = el[e], d = dl[e];
        const u32* up = usrc + (size_t)s*64 + f0;
        const u32* vp = udst + (size_t)d*64 + f0;
        u32 us[4], ud[4];
        #pragma unroll
        for(int t = 0; t < 4; t++){ us[t] = up[16*t]; ud[t] = vp[16*t]; }
        float s0 = 0.f, s1 = 0.f;
        #pragma unroll
        for(int t = 0; t < 4; t++){
            float u1 = __uint_as_float(us[t] << 16);
            float v1 = __uint_as_float(us[t] & 0xffff0000u);
            float u2 = __uint_as_float(ud[t] << 16);
            float v2 = __uint_as_float(ud[t] & 0xffff0000u);
            float xp = fmaxf(u1 + u2, 0.f);
            float xq = fmaxf(v1 + v2, 0.f);
            s0 += xp*wp0[t] + xq*wt0[t];
            s1 += xp*wp1[t] + xq*wt1[t];
        }
        #pragma unroll
        for(int msk = 1; msk < 16; msk <<= 1){
            s0 += __shfl_xor(s0, msk, 64);
            s1 += __shfl_xor(s1, msk, 64);
        }
        if(f0 == 0){
            float a = s0 + bf0, b = s1 + bf1;
            float mx = fmaxf(a, b);
            float lse = mx + __logf(__expf(a - mx) + __expf(b - mx));
            int oi = eid[e];
            if(fl){
                float2 v; v.x = a - lse; v.y = b - lse;
                ((float2*)out)[oi] = v;
            }else{
                u32 pack = (u32)f2bf(a - lse) | ((u32)f2bf(b - lse) << 16);
                ((u32*)out)[oi] = pack;
            }
        }
    }
}

// ---------------- workspace layout (~68.3 MB) ----------------
static const size_t O_FLAG   = 0;
static const size_t O_CANON  = 4096;       // 3,402,248
static const size_t O_GIT    = 3407872;    // 49,152
static const size_t O_W2P    = 3457024;    // 8,192
static const size_t O_WHHP   = 3465216;    // 24,576
static const size_t O_L1PA   = 3489792;    // 8,192
static const size_t O_L1PB   = 3497984;    // 8,192
static const size_t O_LTPA   = 3506176;    // 8,192
static const size_t O_LTPB   = 3514368;    // 8,192
static const size_t O_DINV   = 3522560;    // 400,000
static const size_t O_DEG    = 3922560;    // 400,000
static const size_t O_ROWPTR = 4322560;    // 400,128
static const size_t O_CURSOR = 4722688;    // 400,000
static const size_t O_BSUM   = 5122688;    // 2,048
static const size_t O_EL     = 5124736;    // 4,000,000
static const size_t O_DL     = 9125888;    // 4,000,000
static const size_t O_EID    = 13125888;   // 4,000,000
static const size_t O_SRC    = 17125888;   // N*64 bf16 (dead after gather_ep2)
static const size_t O_H1     = 29925888;   // N*64 bf16 (dead after conv2)
static const size_t O_UDST   = 17125888;   // N*128 bf16 (overlays SRC+H1)
static const size_t O_NODEF  = 42725888;   // N*128 bf16 (h2 + txt; pairpre rewrites in-place)
// end = 68,325,888

extern "C" void kernel_launch(void* const* d_in, const int* in_sizes, int n_in,
                              void* d_out, int out_size, void* d_ws, size_t ws_size,
                              hipStream_t stream){
    const void* x    = d_in[0];
    const int*  ei   = (const int*)d_in[1];
    const int*  xt   = (const int*)d_in[2];

    char* ws = (char*)d_ws;
    int*   flagp  = (int*)(ws + O_FLAG);
    float* canon  = (float*)(ws + O_CANON);
    float* giT    = (float*)(ws + O_GIT);
    u16*   w2p    = (u16*)(ws + O_W2P);
    u16*   whhp   = (u16*)(ws + O_WHHP);
    u16*   l1pa   = (u16*)(ws + O_L1PA);
    u16*   l1pb   = (u16*)(ws + O_L1PB);
    u16*   ltpa   = (u16*)(ws + O_LTPA);
    u16*   ltpb   = (u16*)(ws + O_LTPB);
    float* dinv   = (float*)(ws + O_DINV);
    int*   deg    = (int*)(ws + O_DEG);
    int*   rowptr = (int*)(ws + O_ROWPTR);
    int*   cursor = (int*)(ws + O_CURSOR);
    int*   bsum   = (int*)(ws + O_BSUM);
    int*   el     = (int*)(ws + O_EL);
    int*   dl     = (int*)(ws + O_DL);
    int*   eid    = (int*)(ws + O_EID);
    u16*   src    = (u16*)(ws + O_SRC);
    u16*   hbuf1  = (u16*)(ws + O_H1);
    u32*   udst   = (u32*)(ws + O_UDST);
    u16*   nodef  = (u16*)(ws + O_NODEF);

    // dtype detect + canonicalize
    k_detect<<<1, 256, 0, stream>>>((const u16*)x, flagp);
    k_convert<<<(CTOT+255)/256, 256, 0, stream>>>(flagp,
        x, d_in[3], d_in[4], d_in[5], d_in[6], d_in[7], d_in[8], d_in[9],
        d_in[10], d_in[11], d_in[12], d_in[13], d_in[14], d_in[15], d_in[16], d_in[17],
        canon);

    const float* cx   = canon + CX;
    const float* cw1  = canon + CW1;
    const float* cb1  = canon + CB1;
    const float* cw2  = canon + CW2;
    const float* cb2  = canon + CB2;
    const float* cemb = canon + CEMB;
    const float* cwih = canon + CWIH;
    const float* cwhh = canon + CWHH;
    const float* cbih = canon + CBIH;
    const float* cbhh = canon + CBHH;
    const float* cl1w = canon + CL1W;
    const float* cl1b = canon + CL1B;
    const float* cltw = canon + CLTW;
    const float* cltb = canon + CLTB;
    const float* clfw = canon + CLFW;
    const float* clfb = canon + CLFB;

    // CSR build (once; reused by both GCN layers and the edge kernel)
    hipMemsetAsync(deg, 0, (size_t)N_NODES*4, stream);
    k_hist <<<(N_EDGES+255)/256, 256, 0, stream>>>(ei, deg);
    k_scan1<<<NBLK, 256, 0, stream>>>(deg, rowptr, bsum);
    k_scan2<<<1, 512, 0, stream>>>(bsum);
    k_scan3<<<NBLK, 256, 0, stream>>>(deg, bsum, rowptr, cursor, dinv);
    k_fill <<<(N_EDGES+255)/256, 256, 0, stream>>>(ei, cursor, el, dl, eid);

    // weight packing + gi table (tiny)
    k_packb<<<(64*64+255)/256, 256, 0, stream>>>(cw2, w2p, 64, 64, 64, 1);
    k_packb<<<(64*192+255)/256, 256, 0, stream>>>(cwhh, whhp, 64, 192, 1, 64);
    k_packb<<<(64*64+255)/256, 256, 0, stream>>>(cl1w,      l1pa, 64, 64, 1, 128);
    k_packb<<<(64*64+255)/256, 256, 0, stream>>>(cl1w + 64, l1pb, 64, 64, 1, 128);
    k_packb<<<(64*64+255)/256, 256, 0, stream>>>(cltw,      ltpa, 64, 64, 1, 128);
    k_packb<<<(64*64+255)/256, 256, 0, stream>>>(cltw + 64, ltpb, 64, 64, 1, 128);
    k_gitab<<<(64*192+255)/256, 256, 0, stream>>>(cemb, cwih, cbih, cbhh, giT);

    // GCN layer 1 (src -> h1, stride 64)
    k_t1s<<<N_NODES*64/256, 256, 0, stream>>>(cx, cw1, dinv, src);
    k_gather_ep<<<N_NODES*64/256, 256, 0, stream>>>(rowptr, el, src, dinv, cb1, hbuf1, 64);

    // GCN layer 2 (h1 -> src -> nodef[+0], stride 128)
    k_conv2<<<(N_NODES/16 + 3)/4, 256, 0, stream>>>(hbuf1, w2p, dinv, src);
    k_gather_ep<<<N_NODES*64/256, 256, 0, stream>>>(rowptr, el, src, dinv, cb2, nodef, 128);

    // GRU over text -> nodef[+64], stride 128
    k_gru<<<(N_NODES/16 + 3)/4, 256, 0, stream>>>(xt, whhp, giT, cbhh, nodef + 64);

    // per-node pair precompute (nodef -> usrc in-place, udst)
    k_pairpre<<<(N_NODES/16 + 3)/4, 256, 0, stream>>>(nodef, udst, l1pa, l1pb, ltpa, ltpb,
                                                      cl1b, cltb);

    // edge logits + log_softmax (CSR order, scatter by eid)
    k_edge2<<<4096, 256, 0, stream>>>(el, dl, eid, (const u32*)nodef, udst,
                                      clfw, clfb, flagp, d_out);
}

// Round 12
// 473.525 us; speedup vs baseline: 1.5843x; 1.0458x over previous
//
#include <hip/hip_runtime.h>
#include <stdint.h>

#define N_NODES 100000
#define N_EDGES 1000000
#define NBLK 391   // ceil(N_NODES/256)

typedef unsigned short u16;
typedef unsigned int u32;
typedef __attribute__((ext_vector_type(8))) short bshort8;
typedef __attribute__((ext_vector_type(4))) float f32x4;

__device__ __forceinline__ float bf2f(u16 u){ union{float f; u32 i;} x; x.i=((u32)u)<<16; return x.f; }
__device__ __forceinline__ u16 f2bf(float f){ union{float f; u32 i;} x; x.f=f; u32 r = x.i + 0x7FFFu + ((x.i>>16)&1u); return (u16)(r>>16); }

__device__ __forceinline__ float fexp2(float x){
#if __has_builtin(__builtin_amdgcn_exp2f)
    return __builtin_amdgcn_exp2f(x);
#else
    return exp2f(x);
#endif
}
__device__ __forceinline__ float frcp(float x){
#if __has_builtin(__builtin_amdgcn_rcpf)
    return __builtin_amdgcn_rcpf(x);
#else
    return 1.0f/x;
#endif
}
#define LOG2E 1.442695041f

// ---------------- dtype detector (f32 vs bf16 device buffers) ----------------
__global__ void k_detect(const u16* __restrict__ x, int* flagp){
    __shared__ int cnt;
    if(threadIdx.x == 0) cnt = 0;
    __syncthreads();
    int c = 0;
    for(int i = threadIdx.x; i < 2048; i += 256){
        int e = (x[i] >> 7) & 0xFF;
        if(e >= 0x90) c++;
    }
    atomicAdd(&cnt, c);
    __syncthreads();
    if(threadIdx.x == 0) flagp[0] = (cnt > 64) ? 1 : 0;   // 1 = f32, 0 = bf16
}

// canonical f32 table offsets
#define CX    0
#define CW1   800000
#define CB1   800512
#define CW2   800576
#define CB2   804672
#define CEMB  804736
#define CWIH  808832
#define CWHH  821120
#define CBIH  833408
#define CBHH  833600
#define CL1W  833792
#define CL1B  841984
#define CLTW  842048
#define CLTB  850240
#define CLFW  850304
#define CLFB  850560
#define CTOT  850562

__device__ __forceinline__ float ldany(const void* p, int i, int fl){
    return fl ? ((const float*)p)[i] : bf2f(((const u16*)p)[i]);
}

// ---------------- merged tables kernel: convert + 6x packb + gitab ----------------
// Block ranges (each branch reads RAW inputs; no intra-kernel dependencies).
#define NCONV 3323                  // ceil(CTOT/256)
#define B_W2  (NCONV)               // 16 blocks  (64x64)
#define B_WHH (B_W2 + 16)           // 48 blocks  (64x192)
#define B_L1A (B_WHH + 48)          // 16
#define B_L1B (B_L1A + 16)          // 16
#define B_LTA (B_L1B + 16)          // 16
#define B_LTB (B_LTA + 16)          // 16
#define B_GIT (B_LTB + 16)          // 48 blocks  (64x192)
#define B_TOT (B_GIT + 48)

__device__ __forceinline__ void packb_dev(const void* src, u16* dst,
                                          int K, int N, int ldk, int ldn,
                                          int fl, int i){
    if(i >= K*N) return;
    int k = i / N, n = i % N;
    int kt = k >> 5, kk = k & 31, q = kk >> 3, j = kk & 7;
    int nt = n >> 4, nn = n & 15;
    int KT = K >> 5;
    dst[(((nt*KT + kt)*64) + (q*16 + nn))*8 + j] = f2bf(ldany(src, k*ldk + n*ldn, fl));
}

__global__ void k_tables(const int* __restrict__ flagp,
                         const void* x, const void* w1, const void* b1, const void* w2,
                         const void* b2, const void* emb, const void* wih, const void* whh,
                         const void* bih, const void* bhh, const void* l1w, const void* l1b,
                         const void* ltw, const void* ltb, const void* lfw, const void* lfb,
                         float* __restrict__ canon,
                         u16* __restrict__ w2p, u16* __restrict__ whhp,
                         u16* __restrict__ l1pa, u16* __restrict__ l1pb,
                         u16* __restrict__ ltpa, u16* __restrict__ ltpb,
                         float* __restrict__ giT){
    int b = blockIdx.x, tid = threadIdx.x;
    int fl = *flagp;
    if(b < NCONV){
        int i = b*256 + tid;
        if(i >= CTOT) return;
        const void* p; int off;
        if     (i < CW1 ){ p = x;   off = i;        }
        else if(i < CB1 ){ p = w1;  off = i - CW1;  }
        else if(i < CW2 ){ p = b1;  off = i - CB1;  }
        else if(i < CB2 ){ p = w2;  off = i - CW2;  }
        else if(i < CEMB){ p = b2;  off = i - CB2;  }
        else if(i < CWIH){ p = emb; off = i - CEMB; }
        else if(i < CWHH){ p = wih; off = i - CWIH; }
        else if(i < CBIH){ p = whh; off = i - CWHH; }
        else if(i < CBHH){ p = bih; off = i - CBIH; }
        else if(i < CL1W){ p = bhh; off = i - CBHH; }
        else if(i < CL1B){ p = l1w; off = i - CL1W; }
        else if(i < CLTW){ p = l1b; off = i - CL1B; }
        else if(i < CLTB){ p = ltw; off = i - CLTW; }
        else if(i < CLFW){ p = ltb; off = i - CLTB; }
        else if(i < CLFB){ p = lfw; off = i - CLFW; }
        else             { p = lfb; off = i - CLFB; }
        float v = ldany(p, off, fl);
        canon[i] = (v == v && fabsf(v) < 1e30f) ? v : 0.f;
    }else if(b < B_WHH){
        packb_dev(w2, w2p, 64, 64, 64, 1, fl, (b - B_W2)*256 + tid);
    }else if(b < B_L1A){
        packb_dev(whh, whhp, 64, 192, 1, 64, fl, (b - B_WHH)*256 + tid);
    }else if(b < B_L1B){
        packb_dev(l1w, l1pa, 64, 64, 1, 128, fl, (b - B_L1A)*256 + tid);
    }else if(b < B_LTA){
        packb_dev((const u16*)0 ? (const void*)0 : (const void*)((const char*)l1w + (fl ? 64*4 : 64*2)),
                  l1pb, 64, 64, 1, 128, fl, (b - B_L1B)*256 + tid);
    }else if(b < B_LTB){
        packb_dev(ltw, ltpa, 64, 64, 1, 128, fl, (b - B_LTA)*256 + tid);
    }else if(b < B_GIT){
        packb_dev((const void*)((const char*)ltw + (fl ? 64*4 : 64*2)),
                  ltpb, 64, 64, 1, 128, fl, (b - B_LTB)*256 + tid);
    }else{
        // gi table, transposed: giT[v][g3][col][t];  b_hh folded for r,z (g3<2)
        int i = (b - B_GIT)*256 + tid;
        if(i >= 64*192) return;
        int v = i / 192, g = i % 192;
        float acc = ldany(bih, g, fl) + ((g < 128) ? ldany(bhh, g, fl) : 0.0f);
        for(int f = 0; f < 64; f++) acc += ldany(wih, g*64 + f, fl) * ldany(emb, v*64 + f, fl);
        int g3 = g >> 6, rem = g & 63, t = rem >> 4, col = rem & 15;
        giT[(((size_t)v*3 + g3)*16 + col)*4 + t] = acc;
    }
}

// ---------------- CSR build: histogram -> scan -> fill (el, dl, eid) ----------------
__global__ void k_hist(const int* __restrict__ ei, int* __restrict__ deg){
    int e = blockIdx.x*256 + threadIdx.x;
    if(e < N_EDGES) atomicAdd(&deg[ei[N_EDGES + e]], 1);
}
__global__ void k_scan1(const int* __restrict__ deg, int* __restrict__ rowptr,
                        int* __restrict__ bsum){
    __shared__ int sh[256];
    int tid = threadIdx.x;
    int i = blockIdx.x*256 + tid;
    int v = (i < N_NODES) ? deg[i] : 0;
    sh[tid] = v;
    __syncthreads();
    for(int off = 1; off < 256; off <<= 1){
        int t = (tid >= off) ? sh[tid - off] : 0;
        __syncthreads();
        sh[tid] += t;
        __syncthreads();
    }
    if(i < N_NODES) rowptr[i] = sh[tid] - v;
    if(tid == 255) bsum[blockIdx.x] = sh[255];
}
__global__ void k_scan2(int* __restrict__ bsum){
    __shared__ int sh[512];
    int tid = threadIdx.x;
    int v = (tid < NBLK) ? bsum[tid] : 0;
    sh[tid] = v;
    __syncthreads();
    for(int off = 1; off < 512; off <<= 1){
        int t = (tid >= off) ? sh[tid - off] : 0;
        __syncthreads();
        sh[tid] += t;
        __syncthreads();
    }
    if(tid < NBLK) bsum[tid] = sh[tid] - v;
}
__global__ void k_scan3(const int* __restrict__ deg, const int* __restrict__ bsum,
                        int* __restrict__ rowptr, int* __restrict__ cursor,
                        float* __restrict__ dinv){
    int i = blockIdx.x*256 + threadIdx.x;
    if(i < N_NODES){
        int r = rowptr[i] + bsum[i >> 8];
        rowptr[i] = r;
        cursor[i] = r;
        dinv[i] = rsqrtf((float)deg[i] + 1.0f);   // +1 self loop
    }
    if(i == 0) rowptr[N_NODES] = N_EDGES;
}
__global__ void k_fill(const int* __restrict__ ei, int* __restrict__ cursor,
                       int* __restrict__ el, int* __restrict__ dl, int* __restrict__ eid){
    int e = blockIdx.x*256 + threadIdx.x;
    if(e < N_EDGES){
        int s = ei[e], d = ei[N_EDGES + e];
        int pos = atomicAdd(&cursor[d], 1);
        el[pos] = s;
        dl[pos] = d;
        eid[pos] = e;
    }
}

// ---------------- conv1: src = bf16((x @ W1) * dinv) ----------------
__global__ void k_t1s(const float* __restrict__ cx, const float* __restrict__ cw1,
                      const float* __restrict__ dinv, u16* __restrict__ src){
    __shared__ float w[512];
    int t = threadIdx.x;
    w[t]       = cw1[t];
    w[t + 256] = cw1[t + 256];
    __syncthreads();
    int i = blockIdx.x*256 + t;      // grid exactly N*64/256
    int n = i >> 6, f = i & 63;
    const float* xr = cx + n*8;
    float acc = 0.f;
    #pragma unroll
    for(int k = 0; k < 8; k++) acc += xr[k] * w[k*64 + f];
    src[i] = f2bf(acc * dinv[n]);
}

// ---------------- fused gather + epilogue (bf16 src rows, strided bf16 out) ----------------
__global__ __launch_bounds__(256)
void k_gather_ep(const int* __restrict__ rowptr, const int* __restrict__ el,
                 const u16* __restrict__ src, const float* __restrict__ dinv,
                 const float* __restrict__ b, u16* __restrict__ h, int ostride){
    int gid = blockIdx.x*256 + threadIdx.x;   // grid exactly N*64/256
    int node = gid >> 6, lane = gid & 63;
    int beg = rowptr[node], end = rowptr[node + 1];
    float acc = bf2f(src[node*64 + lane]);    // self loop (pre-scaled by dinv[src])
    int i = beg;
    for(; i + 4 <= end; i += 4){
        int s0 = el[i], s1 = el[i+1], s2 = el[i+2], s3 = el[i+3];
        float a0 = bf2f(src[s0*64 + lane]);
        float a1 = bf2f(src[s1*64 + lane]);
        float a2 = bf2f(src[s2*64 + lane]);
        float a3 = bf2f(src[s3*64 + lane]);
        acc += a0; acc += a1; acc += a2; acc += a3;
    }
    for(; i < end; i++) acc += bf2f(src[el[i]*64 + lane]);
    h[node*ostride + lane] = f2bf(fmaxf(dinv[node]*acc + b[lane], 0.f));
}

// ---------------- conv2 GEMM: src = bf16((h1 @ W2) * dinv) ----------------
__global__ __launch_bounds__(256, 4)
void k_conv2(const u16* __restrict__ h, const u16* __restrict__ w2p,
             const float* __restrict__ dinv, u16* __restrict__ src){
    int wv = threadIdx.x >> 6, lane = threadIdx.x & 63;
    int g = blockIdx.x*4 + wv;
    if(g >= N_NODES/16) return;
    int q = lane >> 4, m = lane & 15, col = m;
    bshort8 a0 = *(const bshort8*)(h + (g*16 + m)*64 + q*8);
    bshort8 a1 = *(const bshort8*)(h + (g*16 + m)*64 + 32 + q*8);
    f32x4 acc[4];
    #pragma unroll
    for(int nt = 0; nt < 4; nt++){
        f32x4 c = {0.f,0.f,0.f,0.f};
        c = __builtin_amdgcn_mfma_f32_16x16x32_bf16(a0, *(const bshort8*)(w2p + ((nt*2+0)*64 + lane)*8), c, 0,0,0);
        c = __builtin_amdgcn_mfma_f32_16x16x32_bf16(a1, *(const bshort8*)(w2p + ((nt*2+1)*64 + lane)*8), c, 0,0,0);
        acc[nt] = c;
    }
    #pragma unroll
    for(int nt = 0; nt < 4; nt++)
        #pragma unroll
        for(int r = 0; r < 4; r++){
            int node = g*16 + q*4 + r;
            src[node*64 + nt*16 + col] = f2bf(acc[nt][r] * dinv[node]);
        }
}

// ---------------- GRU + pair precompute, fused ----------------
// 10-step GRU (bf16 LDS h-tile, float4 gi loads), then in the epilogue:
//   u1 = W1a·h2 + b1, u2 = W1b·h2 (h2 from nodef rows),
//   v1 = Wta·txt + bt, v2 = Wtb·txt (txt from registers via LDS tile).
// usrc (u1|v1) written IN-PLACE over nodef (wave-local rows, frags in regs);
// udst (u2|v2) to separate buffer. txt never touches global memory.
__global__ __launch_bounds__(256, 4)
void k_gru(const int* __restrict__ xt, const u16* __restrict__ whhp,
           const float* __restrict__ giT, const float* __restrict__ bhh,
           u16* nodef, u32* __restrict__ udst,
           const u16* __restrict__ w1a, const u16* __restrict__ w1b,
           const u16* __restrict__ wta, const u16* __restrict__ wtb,
           const float* __restrict__ b1, const float* __restrict__ bt){
    __shared__ __align__(16) u16 wsh[12288];        // 24 KB Whh frags
    __shared__ __align__(16) u16 hsh[4][16][72];    // bf16 h tile
    int tid = threadIdx.x;
    {
        const uint4* s = (const uint4*)whhp;
        uint4* d = (uint4*)wsh;
        #pragma unroll
        for(int i = 0; i < 6; i++) d[tid + 256*i] = s[tid + 256*i];
    }
    __syncthreads();

    int wv = tid >> 6, lane = tid & 63;
    int q = lane >> 4, m = lane & 15, col = m;
    int g = blockIdx.x*4 + wv;
    bool active = g < (N_NODES/16);
    int nb = active ? g*16 : 0;

    float bhhn[4];
    #pragma unroll
    for(int t = 0; t < 4; t++) bhhn[t] = bhh[128 + t*16 + col];

    const bshort8* wl = (const bshort8*)wsh;
    const u16* hp = &hsh[wv][m][0];

    float hc[4][4];
    #pragma unroll
    for(int t = 0; t < 4; t++)
        #pragma unroll
        for(int r = 0; r < 4; r++) hc[t][r] = 0.f;

    for(int s = 0; s < 10; s++){
        #pragma unroll
        for(int t = 0; t < 4; t++)
            #pragma unroll
            for(int r = 0; r < 4; r++)
                hsh[wv][q*4 + r][t*16 + col] = f2bf(hc[t][r]);

        asm volatile("" ::: "memory");
        bshort8 a0 = *(const bshort8*)(hp + q*8);
        bshort8 a1 = *(const bshort8*)(hp + 32 + q*8);

        int tok[4];
        #pragma unroll
        for(int r = 0; r < 4; r++) tok[r] = xt[(nb + q*4 + r)*10 + s] & 63;

        f32x4 acc[12];
        #pragma unroll
        for(int nt = 0; nt < 12; nt++){
            f32x4 c = {0.f,0.f,0.f,0.f};
            c = __builtin_amdgcn_mfma_f32_16x16x32_bf16(a0, wl[(nt*2+0)*64 + lane], c, 0,0,0);
            c = __builtin_amdgcn_mfma_f32_16x16x32_bf16(a1, wl[(nt*2+1)*64 + lane], c, 0,0,0);
            acc[nt] = c;
        }

        #pragma unroll
        for(int r = 0; r < 4; r++){
            const float4* gp = (const float4*)(giT + (size_t)tok[r]*192);
            float4 gr = gp[col];
            float4 gz = gp[16 + col];
            float4 gn = gp[32 + col];
            #pragma unroll
            for(int t = 0; t < 4; t++){
                float gir = ((const float*)&gr)[t];
                float giz = ((const float*)&gz)[t];
                float gin = ((const float*)&gn)[t];
                float rr = frcp(1.0f + fexp2(-LOG2E*(gir + acc[t][r])));
                float zz = frcp(1.0f + fexp2(-LOG2E*(giz + acc[4+t][r])));
                float narg = gin + rr*(acc[8+t][r] + bhhn[t]);
                float e2 = fexp2(2.0f*LOG2E*narg);
                float nn = 1.0f - 2.0f*frcp(e2 + 1.0f);
                hc[t][r] = nn + zz*(hc[t][r] - nn);
            }
        }
        asm volatile("" ::: "memory");
    }

    // ---- fused pair precompute ----
    #pragma unroll
    for(int t = 0; t < 4; t++)
        #pragma unroll
        for(int r = 0; r < 4; r++)
            hsh[wv][q*4 + r][t*16 + col] = f2bf(hc[t][r]);   // txt tile
    asm volatile("" ::: "memory");
    bshort8 at0 = *(const bshort8*)(hp + q*8);
    bshort8 at1 = *(const bshort8*)(hp + 32 + q*8);
    const u16* row = nodef + (size_t)(nb + m)*128;           // h2 rows
    bshort8 ah0 = *(const bshort8*)(row + q*8);
    bshort8 ah1 = *(const bshort8*)(row + 32 + q*8);

    u32* usrc = (u32*)nodef;
    #pragma unroll
    for(int nt = 0; nt < 4; nt++){
        f32x4 cu1 = {0.f,0.f,0.f,0.f}, cu2 = {0.f,0.f,0.f,0.f};
        f32x4 cv1 = {0.f,0.f,0.f,0.f}, cv2 = {0.f,0.f,0.f,0.f};
        cu1 = __builtin_amdgcn_mfma_f32_16x16x32_bf16(ah0, *(const bshort8*)(w1a + ((nt*2+0)*64 + lane)*8), cu1, 0,0,0);
        cu1 = __builtin_amdgcn_mfma_f32_16x16x32_bf16(ah1, *(const bshort8*)(w1a + ((nt*2+1)*64 + lane)*8), cu1, 0,0,0);
        cu2 = __builtin_amdgcn_mfma_f32_16x16x32_bf16(ah0, *(const bshort8*)(w1b + ((nt*2+0)*64 + lane)*8), cu2, 0,0,0);
        cu2 = __builtin_amdgcn_mfma_f32_16x16x32_bf16(ah1, *(const bshort8*)(w1b + ((nt*2+1)*64 + lane)*8), cu2, 0,0,0);
        cv1 = __builtin_amdgcn_mfma_f32_16x16x32_bf16(at0, *(const bshort8*)(wta + ((nt*2+0)*64 + lane)*8), cv1, 0,0,0);
        cv1 = __builtin_amdgcn_mfma_f32_16x16x32_bf16(at1, *(const bshort8*)(wta + ((nt*2+1)*64 + lane)*8), cv1, 0,0,0);
        cv2 = __builtin_amdgcn_mfma_f32_16x16x32_bf16(at0, *(const bshort8*)(wtb + ((nt*2+0)*64 + lane)*8), cv2, 0,0,0);
        cv2 = __builtin_amdgcn_mfma_f32_16x16x32_bf16(at1, *(const bshort8*)(wtb + ((nt*2+1)*64 + lane)*8), cv2, 0,0,0);
        if(active){
            int f = nt*16 + col;
            float b1f = b1[f], btf = bt[f];
            #pragma unroll
            for(int r = 0; r < 4; r++){
                int node = nb + q*4 + r;
                u32 pa = (u32)f2bf(cu1[r] + b1f) | ((u32)f2bf(cv1[r] + btf) << 16);
                u32 pb = (u32)f2bf(cu2[r]) | ((u32)f2bf(cv2[r]) << 16);
                usrc[(size_t)node*64 + f] = pa;
                udst[(size_t)node*64 + f] = pb;
            }
        }
    }
}

// ---------------- edge kernel: 4 edges/wave, 16 lanes/edge, 4 feats/lane ----------------
__global__ __launch_bounds__(256, 6)
void k_edge2(const int* __restrict__ el, const int* __restrict__ dl, const int* __restrict__ eid,
             const u32* __restrict__ usrc, const u32* __restrict__ udst,
             const float* __restrict__ wfin, const float* __restrict__ bfin,
             const int* __restrict__ flagp, void* __restrict__ out){
    int tid = threadIdx.x;
    int lane = tid & 63;
    int q = lane >> 4, f0 = lane & 15;
    int wid = (blockIdx.x*256 + tid) >> 6;
    int nwv = (gridDim.x*256) >> 6;
    int fl = *flagp;

    float wp0[4], wp1[4], wt0[4], wt1[4];
    #pragma unroll
    for(int t = 0; t < 4; t++){
        int f = f0 + 16*t;
        wp0[t] = wfin[f];        wt0[t] = wfin[64 + f];
        wp1[t] = wfin[128 + f];  wt1[t] = wfin[192 + f];
    }
    float bf0 = bfin[0], bf1 = bfin[1];

    for(int grp = wid; grp < N_EDGES/4; grp += nwv){
        int e = grp*4 + q;
        int s = el[e], d = dl[e];
        const u32* up = usrc + (size_t)s*64 + f0;
        const u32* vp = udst + (size_t)d*64 + f0;
        u32 us[4], ud[4];
        #pragma unroll
        for(int t = 0; t < 4; t++){ us[t] = up[16*t]; ud[t] = vp[16*t]; }
        float s0 = 0.f, s1 = 0.f;
        #pragma unroll
        for(int t = 0; t < 4; t++){
            float u1 = __uint_as_float(us[t] << 16);
            float v1 = __uint_as_float(us[t] & 0xffff0000u);
            float u2 = __uint_as_float(ud[t] << 16);
            float v2 = __uint_as_float(ud[t] & 0xffff0000u);
            float xp = fmaxf(u1 + u2, 0.f);
            float xq = fmaxf(v1 + v2, 0.f);
            s0 += xp*wp0[t] + xq*wt0[t];
            s1 += xp*wp1[t] + xq*wt1[t];
        }
        #pragma unroll
        for(int msk = 1; msk < 16; msk <<= 1){
            s0 += __shfl_xor(s0, msk, 64);
            s1 += __shfl_xor(s1, msk, 64);
        }
        if(f0 == 0){
            float a = s0 + bf0, b = s1 + bf1;
            float mx = fmaxf(a, b);
            float lse = mx + __logf(__expf(a - mx) + __expf(b - mx));
            int oi = eid[e];
            if(fl){
                float2 v; v.x = a - lse; v.y = b - lse;
                ((float2*)out)[oi] = v;
            }else{
                u32 pack = (u32)f2bf(a - lse) | ((u32)f2bf(b - lse) << 16);
                ((u32*)out)[oi] = pack;
            }
        }
    }
}

// ---------------- workspace layout (~68.3 MB) ----------------
static const size_t O_FLAG   = 0;
static const size_t O_CANON  = 4096;       // 3,402,248
static const size_t O_GIT    = 3407872;    // 49,152
static const size_t O_W2P    = 3457024;    // 8,192
static const size_t O_WHHP   = 3465216;    // 24,576
static const size_t O_L1PA   = 3489792;    // 8,192
static const size_t O_L1PB   = 3497984;    // 8,192
static const size_t O_LTPA   = 3506176;    // 8,192
static const size_t O_LTPB   = 3514368;    // 8,192
static const size_t O_DINV   = 3522560;    // 400,000
static const size_t O_DEG    = 3922560;    // 400,000
static const size_t O_ROWPTR = 4322560;    // 400,128
static const size_t O_CURSOR = 4722688;    // 400,000
static const size_t O_BSUM   = 5122688;    // 2,048
static const size_t O_EL     = 5124736;    // 4,000,000
static const size_t O_DL     = 9125888;    // 4,000,000
static const size_t O_EID    = 13125888;   // 4,000,000
static const size_t O_SRC    = 17125888;   // N*64 bf16 (dead after gather_ep2)
static const size_t O_H1     = 29925888;   // N*64 bf16 (dead after conv2)
static const size_t O_UDST   = 17125888;   // N*64 u32 (overlays SRC+H1, written in fused gru)
static const size_t O_NODEF  = 42725888;   // N*128 bf16 (h2; fused gru rewrites in-place as usrc)
// end = 68,325,888

extern "C" void kernel_launch(void* const* d_in, const int* in_sizes, int n_in,
                              void* d_out, int out_size, void* d_ws, size_t ws_size,
                              hipStream_t stream){
    const void* x    = d_in[0];
    const int*  ei   = (const int*)d_in[1];
    const int*  xt   = (const int*)d_in[2];

    char* ws = (char*)d_ws;
    int*   flagp  = (int*)(ws + O_FLAG);
    float* canon  = (float*)(ws + O_CANON);
    float* giT    = (float*)(ws + O_GIT);
    u16*   w2p    = (u16*)(ws + O_W2P);
    u16*   whhp   = (u16*)(ws + O_WHHP);
    u16*   l1pa   = (u16*)(ws + O_L1PA);
    u16*   l1pb   = (u16*)(ws + O_L1PB);
    u16*   ltpa   = (u16*)(ws + O_LTPA);
    u16*   ltpb   = (u16*)(ws + O_LTPB);
    float* dinv   = (float*)(ws + O_DINV);
    int*   deg    = (int*)(ws + O_DEG);
    int*   rowptr = (int*)(ws + O_ROWPTR);
    int*   cursor = (int*)(ws + O_CURSOR);
    int*   bsum   = (int*)(ws + O_BSUM);
    int*   el     = (int*)(ws + O_EL);
    int*   dl     = (int*)(ws + O_DL);
    int*   eid    = (int*)(ws + O_EID);
    u16*   src    = (u16*)(ws + O_SRC);
    u16*   hbuf1  = (u16*)(ws + O_H1);
    u32*   udst   = (u32*)(ws + O_UDST);
    u16*   nodef  = (u16*)(ws + O_NODEF);

    // dtype detect, then ALL table prep in one kernel
    k_detect<<<1, 256, 0, stream>>>((const u16*)x, flagp);
    k_tables<<<B_TOT, 256, 0, stream>>>(flagp,
        x, d_in[3], d_in[4], d_in[5], d_in[6], d_in[7], d_in[8], d_in[9],
        d_in[10], d_in[11], d_in[12], d_in[13], d_in[14], d_in[15], d_in[16], d_in[17],
        canon, w2p, whhp, l1pa, l1pb, ltpa, ltpb, giT);

    const float* cx   = canon + CX;
    const float* cw1  = canon + CW1;
    const float* cb1  = canon + CB1;
    const float* cb2  = canon + CB2;
    const float* cbhh = canon + CBHH;
    const float* cl1b = canon + CL1B;
    const float* cltb = canon + CLTB;
    const float* clfw = canon + CLFW;
    const float* clfb = canon + CLFB;

    // CSR build (once; reused by both GCN layers and the edge kernel)
    hipMemsetAsync(deg, 0, (size_t)N_NODES*4, stream);
    k_hist <<<(N_EDGES+255)/256, 256, 0, stream>>>(ei, deg);
    k_scan1<<<NBLK, 256, 0, stream>>>(deg, rowptr, bsum);
    k_scan2<<<1, 512, 0, stream>>>(bsum);
    k_scan3<<<NBLK, 256, 0, stream>>>(deg, bsum, rowptr, cursor, dinv);
    k_fill <<<(N_EDGES+255)/256, 256, 0, stream>>>(ei, cursor, el, dl, eid);

    // GCN layer 1 (src -> h1, stride 64)
    k_t1s<<<N_NODES*64/256, 256, 0, stream>>>(cx, cw1, dinv, src);
    k_gather_ep<<<N_NODES*64/256, 256, 0, stream>>>(rowptr, el, src, dinv, cb1, hbuf1, 64);

    // GCN layer 2 (h1 -> src -> nodef[+0], stride 128)
    k_conv2<<<(N_NODES/16 + 3)/4, 256, 0, stream>>>(hbuf1, w2p, dinv, src);
    k_gather_ep<<<N_NODES*64/256, 256, 0, stream>>>(rowptr, el, src, dinv, cb2, nodef, 128);

    // GRU + pair precompute fused (nodef -> usrc in-place, udst)
    k_gru<<<(N_NODES/16 + 3)/4, 256, 0, stream>>>(xt, whhp, giT, cbhh,
                                                  nodef, udst, l1pa, l1pb, ltpa, ltpb,
                                                  cl1b, cltb);

    // edge logits + log_softmax (CSR order, scatter by eid)
    k_edge2<<<4096, 256, 0, stream>>>(el, dl, eid, (const u32*)nodef, udst,
                                      clfw, clfb, flagp, d_out);
}

// Round 13
// 450.378 us; speedup vs baseline: 1.6658x; 1.0514x over previous
//
#include <hip/hip_runtime.h>
#include <stdint.h>

#define N_NODES 100000
#define N_EDGES 1000000
#define NBLK 391   // ceil(N_NODES/256)

typedef unsigned short u16;
typedef unsigned int u32;
typedef __attribute__((ext_vector_type(8))) short bshort8;
typedef __attribute__((ext_vector_type(4))) float f32x4;

__device__ __forceinline__ float bf2f(u16 u){ union{float f; u32 i;} x; x.i=((u32)u)<<16; return x.f; }
__device__ __forceinline__ u16 f2bf(float f){ union{float f; u32 i;} x; x.f=f; u32 r = x.i + 0x7FFFu + ((x.i>>16)&1u); return (u16)(r>>16); }

__device__ __forceinline__ float fexp2(float x){
#if __has_builtin(__builtin_amdgcn_exp2f)
    return __builtin_amdgcn_exp2f(x);
#else
    return exp2f(x);
#endif
}
__device__ __forceinline__ float frcp(float x){
#if __has_builtin(__builtin_amdgcn_rcpf)
    return __builtin_amdgcn_rcpf(x);
#else
    return 1.0f/x;
#endif
}
#define LOG2E 1.442695041f

// ---------------- dtype detector (f32 vs bf16 device buffers) ----------------
__global__ void k_detect(const u16* __restrict__ x, int* flagp){
    __shared__ int cnt;
    if(threadIdx.x == 0) cnt = 0;
    __syncthreads();
    int c = 0;
    for(int i = threadIdx.x; i < 2048; i += 256){
        int e = (x[i] >> 7) & 0xFF;
        if(e >= 0x90) c++;
    }
    atomicAdd(&cnt, c);
    __syncthreads();
    if(threadIdx.x == 0) flagp[0] = (cnt > 64) ? 1 : 0;   // 1 = f32, 0 = bf16
}

// canonical f32 table offsets
#define CX    0
#define CW1   800000
#define CB1   800512
#define CW2   800576
#define CB2   804672
#define CEMB  804736
#define CWIH  808832
#define CWHH  821120
#define CBIH  833408
#define CBHH  833600
#define CL1W  833792
#define CL1B  841984
#define CLTW  842048
#define CLTB  850240
#define CLFW  850304
#define CLFB  850560
#define CTOT  850562

__device__ __forceinline__ float ldany(const void* p, int i, int fl){
    return fl ? ((const float*)p)[i] : bf2f(((const u16*)p)[i]);
}

// ---------------- merged tables kernel: convert + 6x packb + gitab ----------------
#define NCONV 3323                  // ceil(CTOT/256)
#define B_W2  (NCONV)               // 16 blocks  (64x64)
#define B_WHH (B_W2 + 16)           // 48 blocks  (64x192)
#define B_L1A (B_WHH + 48)          // 16
#define B_L1B (B_L1A + 16)          // 16
#define B_LTA (B_L1B + 16)          // 16
#define B_LTB (B_LTA + 16)          // 16
#define B_GIT (B_LTB + 16)          // 48 blocks  (64x192)
#define B_TOT (B_GIT + 48)

__device__ __forceinline__ void packb_dev(const void* src, u16* dst,
                                          int K, int N, int ldk, int ldn,
                                          int fl, int i){
    if(i >= K*N) return;
    int k = i / N, n = i % N;
    int kt = k >> 5, kk = k & 31, q = kk >> 3, j = kk & 7;
    int nt = n >> 4, nn = n & 15;
    int KT = K >> 5;
    dst[(((nt*KT + kt)*64) + (q*16 + nn))*8 + j] = f2bf(ldany(src, k*ldk + n*ldn, fl));
}

__global__ void k_tables(const int* __restrict__ flagp,
                         const void* x, const void* w1, const void* b1, const void* w2,
                         const void* b2, const void* emb, const void* wih, const void* whh,
                         const void* bih, const void* bhh, const void* l1w, const void* l1b,
                         const void* ltw, const void* ltb, const void* lfw, const void* lfb,
                         float* __restrict__ canon,
                         u16* __restrict__ w2p, u16* __restrict__ whhp,
                         u16* __restrict__ l1pa, u16* __restrict__ l1pb,
                         u16* __restrict__ ltpa, u16* __restrict__ ltpb,
                         float* __restrict__ giT){
    int b = blockIdx.x, tid = threadIdx.x;
    int fl = *flagp;
    if(b < NCONV){
        int i = b*256 + tid;
        if(i >= CTOT) return;
        const void* p; int off;
        if     (i < CW1 ){ p = x;   off = i;        }
        else if(i < CB1 ){ p = w1;  off = i - CW1;  }
        else if(i < CW2 ){ p = b1;  off = i - CB1;  }
        else if(i < CB2 ){ p = w2;  off = i - CW2;  }
        else if(i < CEMB){ p = b2;  off = i - CB2;  }
        else if(i < CWIH){ p = emb; off = i - CEMB; }
        else if(i < CWHH){ p = wih; off = i - CWIH; }
        else if(i < CBIH){ p = whh; off = i - CWHH; }
        else if(i < CBHH){ p = bih; off = i - CBIH; }
        else if(i < CL1W){ p = bhh; off = i - CBHH; }
        else if(i < CL1B){ p = l1w; off = i - CL1W; }
        else if(i < CLTW){ p = l1b; off = i - CL1B; }
        else if(i < CLTB){ p = ltw; off = i - CLTW; }
        else if(i < CLFW){ p = ltb; off = i - CLTB; }
        else if(i < CLFB){ p = lfw; off = i - CLFW; }
        else             { p = lfb; off = i - CLFB; }
        float v = ldany(p, off, fl);
        canon[i] = (v == v && fabsf(v) < 1e30f) ? v : 0.f;
    }else if(b < B_WHH){
        packb_dev(w2, w2p, 64, 64, 64, 1, fl, (b - B_W2)*256 + tid);
    }else if(b < B_L1A){
        packb_dev(whh, whhp, 64, 192, 1, 64, fl, (b - B_WHH)*256 + tid);
    }else if(b < B_L1B){
        packb_dev(l1w, l1pa, 64, 64, 1, 128, fl, (b - B_L1A)*256 + tid);
    }else if(b < B_LTA){
        packb_dev((const void*)((const char*)l1w + (fl ? 64*4 : 64*2)),
                  l1pb, 64, 64, 1, 128, fl, (b - B_L1B)*256 + tid);
    }else if(b < B_LTB){
        packb_dev(ltw, ltpa, 64, 64, 1, 128, fl, (b - B_LTA)*256 + tid);
    }else if(b < B_GIT){
        packb_dev((const void*)((const char*)ltw + (fl ? 64*4 : 64*2)),
                  ltpb, 64, 64, 1, 128, fl, (b - B_LTB)*256 + tid);
    }else{
        // gi table, transposed: giT[v][g3][col][t];  b_hh folded for r,z (g3<2)
        int i = (b - B_GIT)*256 + tid;
        if(i >= 64*192) return;
        int v = i / 192, g = i % 192;
        float acc = ldany(bih, g, fl) + ((g < 128) ? ldany(bhh, g, fl) : 0.0f);
        for(int f = 0; f < 64; f++) acc += ldany(wih, g*64 + f, fl) * ldany(emb, v*64 + f, fl);
        int g3 = g >> 6, rem = g & 63, t = rem >> 4, col = rem & 15;
        giT[(((size_t)v*3 + g3)*16 + col)*4 + t] = acc;
    }
}

// ---------------- CSR build: histogram -> scan -> fill (el, dl, eid) ----------------
__global__ void k_hist(const int* __restrict__ ei, int* __restrict__ deg){
    int e = blockIdx.x*256 + threadIdx.x;
    if(e < N_EDGES) atomicAdd(&deg[ei[N_EDGES + e]], 1);
}
__global__ void k_scan1(const int* __restrict__ deg, int* __restrict__ rowptr,
                        int* __restrict__ bsum){
    __shared__ int sh[256];
    int tid = threadIdx.x;
    int i = blockIdx.x*256 + tid;
    int v = (i < N_NODES) ? deg[i] : 0;
    sh[tid] = v;
    __syncthreads();
    for(int off = 1; off < 256; off <<= 1){
        int t = (tid >= off) ? sh[tid - off] : 0;
        __syncthreads();
        sh[tid] += t;
        __syncthreads();
    }
    if(i < N_NODES) rowptr[i] = sh[tid] - v;
    if(tid == 255) bsum[blockIdx.x] = sh[255];
}
__global__ void k_scan2(int* __restrict__ bsum){
    __shared__ int sh[512];
    int tid = threadIdx.x;
    int v = (tid < NBLK) ? bsum[tid] : 0;
    sh[tid] = v;
    __syncthreads();
    for(int off = 1; off < 512; off <<= 1){
        int t = (tid >= off) ? sh[tid - off] : 0;
        __syncthreads();
        sh[tid] += t;
        __syncthreads();
    }
    if(tid < NBLK) bsum[tid] = sh[tid] - v;
}
__global__ void k_scan3(const int* __restrict__ deg, const int* __restrict__ bsum,
                        int* __restrict__ rowptr, int* __restrict__ cursor,
                        float* __restrict__ dinv){
    int i = blockIdx.x*256 + threadIdx.x;
    if(i < N_NODES){
        int r = rowptr[i] + bsum[i >> 8];
        rowptr[i] = r;
        cursor[i] = r;
        dinv[i] = rsqrtf((float)deg[i] + 1.0f);   // +1 self loop
    }
    if(i == 0) rowptr[N_NODES] = N_EDGES;
}
__global__ void k_fill(const int* __restrict__ ei, int* __restrict__ cursor,
                       int* __restrict__ el, int* __restrict__ dl, int* __restrict__ eid){
    int e = blockIdx.x*256 + threadIdx.x;
    if(e < N_EDGES){
        int s = ei[e], d = ei[N_EDGES + e];
        int pos = atomicAdd(&cursor[d], 1);
        el[pos] = s;
        dl[pos] = d;
        eid[pos] = e;
    }
}

// ---------------- conv1: src = bf16((x @ W1) * dinv) ----------------
__global__ void k_t1s(const float* __restrict__ cx, const float* __restrict__ cw1,
                      const float* __restrict__ dinv, u16* __restrict__ src){
    __shared__ float w[512];
    int t = threadIdx.x;
    w[t]       = cw1[t];
    w[t + 256] = cw1[t + 256];
    __syncthreads();
    int i = blockIdx.x*256 + t;      // grid exactly N*64/256
    int n = i >> 6, f = i & 63;
    const float* xr = cx + n*8;
    float acc = 0.f;
    #pragma unroll
    for(int k = 0; k < 8; k++) acc += xr[k] * w[k*64 + f];
    src[i] = f2bf(acc * dinv[n]);
}

// ---------------- fused gather + epilogue: u32 loads, 2 feats/thread, 32 lanes/node ----------------
__global__ __launch_bounds__(256)
void k_gather_ep(const int* __restrict__ rowptr, const int* __restrict__ el,
                 const u16* __restrict__ src, const float* __restrict__ dinv,
                 const float* __restrict__ b, u16* __restrict__ h, int ostride){
    int gid = blockIdx.x*256 + threadIdx.x;   // grid exactly N*32/256
    int node = gid >> 5, fp = (gid & 31)*2;
    int beg = rowptr[node], end = rowptr[node + 1];
    u32 self = *(const u32*)(src + (size_t)node*64 + fp);
    float acc0 = bf2f((u16)self), acc1 = bf2f((u16)(self >> 16));
    int i = beg;
    for(; i + 4 <= end; i += 4){
        int s0 = el[i], s1 = el[i+1], s2 = el[i+2], s3 = el[i+3];
        u32 a0 = *(const u32*)(src + (size_t)s0*64 + fp);
        u32 a1 = *(const u32*)(src + (size_t)s1*64 + fp);
        u32 a2 = *(const u32*)(src + (size_t)s2*64 + fp);
        u32 a3 = *(const u32*)(src + (size_t)s3*64 + fp);
        acc0 += bf2f((u16)a0); acc1 += bf2f((u16)(a0 >> 16));
        acc0 += bf2f((u16)a1); acc1 += bf2f((u16)(a1 >> 16));
        acc0 += bf2f((u16)a2); acc1 += bf2f((u16)(a2 >> 16));
        acc0 += bf2f((u16)a3); acc1 += bf2f((u16)(a3 >> 16));
    }
    for(; i < end; i++){
        u32 a = *(const u32*)(src + (size_t)el[i]*64 + fp);
        acc0 += bf2f((u16)a); acc1 += bf2f((u16)(a >> 16));
    }
    float dv = dinv[node];
    float r0 = fmaxf(dv*acc0 + b[fp],     0.f);
    float r1 = fmaxf(dv*acc1 + b[fp + 1], 0.f);
    *(u32*)(h + (size_t)node*ostride + fp) = (u32)f2bf(r0) | ((u32)f2bf(r1) << 16);
}

// ---------------- conv2 GEMM: src = bf16((h1 @ W2) * dinv) ----------------
__global__ __launch_bounds__(256, 4)
void k_conv2(const u16* __restrict__ h, const u16* __restrict__ w2p,
             const float* __restrict__ dinv, u16* __restrict__ src){
    int wv = threadIdx.x >> 6, lane = threadIdx.x & 63;
    int g = blockIdx.x*4 + wv;
    if(g >= N_NODES/16) return;
    int q = lane >> 4, m = lane & 15, col = m;
    bshort8 a0 = *(const bshort8*)(h + (g*16 + m)*64 + q*8);
    bshort8 a1 = *(const bshort8*)(h + (g*16 + m)*64 + 32 + q*8);
    f32x4 acc[4];
    #pragma unroll
    for(int nt = 0; nt < 4; nt++){
        f32x4 c = {0.f,0.f,0.f,0.f};
        c = __builtin_amdgcn_mfma_f32_16x16x32_bf16(a0, *(const bshort8*)(w2p + ((nt*2+0)*64 + lane)*8), c, 0,0,0);
        c = __builtin_amdgcn_mfma_f32_16x16x32_bf16(a1, *(const bshort8*)(w2p + ((nt*2+1)*64 + lane)*8), c, 0,0,0);
        acc[nt] = c;
    }
    #pragma unroll
    for(int nt = 0; nt < 4; nt++)
        #pragma unroll
        for(int r = 0; r < 4; r++){
            int node = g*16 + q*4 + r;
            src[node*64 + nt*16 + col] = f2bf(acc[nt][r] * dinv[node]);
        }
}

// ---------------- GRU + pair precompute, fused ----------------
__global__ __launch_bounds__(256, 4)
void k_gru(const int* __restrict__ xt, const u16* __restrict__ whhp,
           const float* __restrict__ giT, const float* __restrict__ bhh,
           u16* nodef, u32* __restrict__ udst,
           const u16* __restrict__ w1a, const u16* __restrict__ w1b,
           const u16* __restrict__ wta, const u16* __restrict__ wtb,
           const float* __restrict__ b1, const float* __restrict__ bt){
    __shared__ __align__(16) u16 wsh[12288];        // 24 KB Whh frags
    __shared__ __align__(16) u16 hsh[4][16][72];    // bf16 h tile
    int tid = threadIdx.x;
    {
        const uint4* s = (const uint4*)whhp;
        uint4* d = (uint4*)wsh;
        #pragma unroll
        for(int i = 0; i < 6; i++) d[tid + 256*i] = s[tid + 256*i];
    }
    __syncthreads();

    int wv = tid >> 6, lane = tid & 63;
    int q = lane >> 4, m = lane & 15, col = m;
    int g = blockIdx.x*4 + wv;
    bool active = g < (N_NODES/16);
    int nb = active ? g*16 : 0;

    float bhhn[4];
    #pragma unroll
    for(int t = 0; t < 4; t++) bhhn[t] = bhh[128 + t*16 + col];

    const bshort8* wl = (const bshort8*)wsh;
    const u16* hp = &hsh[wv][m][0];

    float hc[4][4];
    #pragma unroll
    for(int t = 0; t < 4; t++)
        #pragma unroll
        for(int r = 0; r < 4; r++) hc[t][r] = 0.f;

    for(int s = 0; s < 10; s++){
        #pragma unroll
        for(int t = 0; t < 4; t++)
            #pragma unroll
            for(int r = 0; r < 4; r++)
                hsh[wv][q*4 + r][t*16 + col] = f2bf(hc[t][r]);

        asm volatile("" ::: "memory");
        bshort8 a0 = *(const bshort8*)(hp + q*8);
        bshort8 a1 = *(const bshort8*)(hp + 32 + q*8);

        int tok[4];
        #pragma unroll
        for(int r = 0; r < 4; r++) tok[r] = xt[(nb + q*4 + r)*10 + s] & 63;

        f32x4 acc[12];
        #pragma unroll
        for(int nt = 0; nt < 12; nt++){
            f32x4 c = {0.f,0.f,0.f,0.f};
            c = __builtin_amdgcn_mfma_f32_16x16x32_bf16(a0, wl[(nt*2+0)*64 + lane], c, 0,0,0);
            c = __builtin_amdgcn_mfma_f32_16x16x32_bf16(a1, wl[(nt*2+1)*64 + lane], c, 0,0,0);
            acc[nt] = c;
        }

        #pragma unroll
        for(int r = 0; r < 4; r++){
            const float4* gp = (const float4*)(giT + (size_t)tok[r]*192);
            float4 gr = gp[col];
            float4 gz = gp[16 + col];
            float4 gn = gp[32 + col];
            #pragma unroll
            for(int t = 0; t < 4; t++){
                float gir = ((const float*)&gr)[t];
                float giz = ((const float*)&gz)[t];
                float gin = ((const float*)&gn)[t];
                float rr = frcp(1.0f + fexp2(-LOG2E*(gir + acc[t][r])));
                float zz = frcp(1.0f + fexp2(-LOG2E*(giz + acc[4+t][r])));
                float narg = gin + rr*(acc[8+t][r] + bhhn[t]);
                float e2 = fexp2(2.0f*LOG2E*narg);
                float nn = 1.0f - 2.0f*frcp(e2 + 1.0f);
                hc[t][r] = nn + zz*(hc[t][r] - nn);
            }
        }
        asm volatile("" ::: "memory");
    }

    // ---- fused pair precompute ----
    #pragma unroll
    for(int t = 0; t < 4; t++)
        #pragma unroll
        for(int r = 0; r < 4; r++)
            hsh[wv][q*4 + r][t*16 + col] = f2bf(hc[t][r]);   // txt tile
    asm volatile("" ::: "memory");
    bshort8 at0 = *(const bshort8*)(hp + q*8);
    bshort8 at1 = *(const bshort8*)(hp + 32 + q*8);
    const u16* row = nodef + (size_t)(nb + m)*128;           // h2 rows
    bshort8 ah0 = *(const bshort8*)(row + q*8);
    bshort8 ah1 = *(const bshort8*)(row + 32 + q*8);

    u32* usrc = (u32*)nodef;
    #pragma unroll
    for(int nt = 0; nt < 4; nt++){
        f32x4 cu1 = {0.f,0.f,0.f,0.f}, cu2 = {0.f,0.f,0.f,0.f};
        f32x4 cv1 = {0.f,0.f,0.f,0.f}, cv2 = {0.f,0.f,0.f,0.f};
        cu1 = __builtin_amdgcn_mfma_f32_16x16x32_bf16(ah0, *(const bshort8*)(w1a + ((nt*2+0)*64 + lane)*8), cu1, 0,0,0);
        cu1 = __builtin_amdgcn_mfma_f32_16x16x32_bf16(ah1, *(const bshort8*)(w1a + ((nt*2+1)*64 + lane)*8), cu1, 0,0,0);
        cu2 = __builtin_amdgcn_mfma_f32_16x16x32_bf16(ah0, *(const bshort8*)(w1b + ((nt*2+0)*64 + lane)*8), cu2, 0,0,0);
        cu2 = __builtin_amdgcn_mfma_f32_16x16x32_bf16(ah1, *(const bshort8*)(w1b + ((nt*2+1)*64 + lane)*8), cu2, 0,0,0);
        cv1 = __builtin_amdgcn_mfma_f32_16x16x32_bf16(at0, *(const bshort8*)(wta + ((nt*2+0)*64 + lane)*8), cv1, 0,0,0);
        cv1 = __builtin_amdgcn_mfma_f32_16x16x32_bf16(at1, *(const bshort8*)(wta + ((nt*2+1)*64 + lane)*8), cv1, 0,0,0);
        cv2 = __builtin_amdgcn_mfma_f32_16x16x32_bf16(at0, *(const bshort8*)(wtb + ((nt*2+0)*64 + lane)*8), cv2, 0,0,0);
        cv2 = __builtin_amdgcn_mfma_f32_16x16x32_bf16(at1, *(const bshort8*)(wtb + ((nt*2+1)*64 + lane)*8), cv2, 0,0,0);
        if(active){
            int f = nt*16 + col;
            float b1f = b1[f], btf = bt[f];
            #pragma unroll
            for(int r = 0; r < 4; r++){
                int node = nb + q*4 + r;
                u32 pa = (u32)f2bf(cu1[r] + b1f) | ((u32)f2bf(cv1[r] + btf) << 16);
                u32 pb = (u32)f2bf(cu2[r]) | ((u32)f2bf(cv2[r]) << 16);
                usrc[(size_t)node*64 + f] = pa;
                udst[(size_t)node*64 + f] = pb;
            }
        }
    }
}

// ---------------- edge kernel: uint4 row loads; 4 edges/wave, 16 lanes/edge ----------------
// lane f0 covers feats 4f0..4f0+3 (one 16-B chunk of the 256-B u-row).
__global__ __launch_bounds__(256, 6)
void k_edge2(const int* __restrict__ el, const int* __restrict__ dl, const int* __restrict__ eid,
             const u32* __restrict__ usrc, const u32* __restrict__ udst,
             const float* __restrict__ wfin, const float* __restrict__ bfin,
             const int* __restrict__ flagp, void* __restrict__ out){
    int tid = threadIdx.x;
    int lane = tid & 63;
    int q = lane >> 4, f0 = lane & 15;
    int wid = (blockIdx.x*256 + tid) >> 6;
    int nwv = (gridDim.x*256) >> 6;
    int fl = *flagp;

    float wp0[4], wp1[4], wt0[4], wt1[4];
    #pragma unroll
    for(int t = 0; t < 4; t++){
        int f = 4*f0 + t;
        wp0[t] = wfin[f];        wt0[t] = wfin[64 + f];
        wp1[t] = wfin[128 + f];  wt1[t] = wfin[192 + f];
    }
    float bf0 = bfin[0], bf1 = bfin[1];

    for(int grp = wid; grp < N_EDGES/4; grp += nwv){
        int e = grp*4 + q;
        int s = el[e], d = dl[e];
        uint4 us4 = *((const uint4*)(usrc + (size_t)s*64) + f0);
        uint4 ud4 = *((const uint4*)(udst + (size_t)d*64) + f0);
        u32 us[4] = {us4.x, us4.y, us4.z, us4.w};
        u32 ud[4] = {ud4.x, ud4.y, ud4.z, ud4.w};
        float s0 = 0.f, s1 = 0.f;
        #pragma unroll
        for(int t = 0; t < 4; t++){
            float u1 = __uint_as_float(us[t] << 16);
            float v1 = __uint_as_float(us[t] & 0xffff0000u);
            float u2 = __uint_as_float(ud[t] << 16);
            float v2 = __uint_as_float(ud[t] & 0xffff0000u);
            float xp = fmaxf(u1 + u2, 0.f);
            float xq = fmaxf(v1 + v2, 0.f);
            s0 += xp*wp0[t] + xq*wt0[t];
            s1 += xp*wp1[t] + xq*wt1[t];
        }
        #pragma unroll
        for(int msk = 1; msk < 16; msk <<= 1){
            s0 += __shfl_xor(s0, msk, 64);
            s1 += __shfl_xor(s1, msk, 64);
        }
        if(f0 == 0){
            float a = s0 + bf0, b = s1 + bf1;
            float mx = fmaxf(a, b);
            float lse = mx + __logf(__expf(a - mx) + __expf(b - mx));
            int oi = eid[e];
            if(fl){
                float2 v; v.x = a - lse; v.y = b - lse;
                ((float2*)out)[oi] = v;
            }else{
                u32 pack = (u32)f2bf(a - lse) | ((u32)f2bf(b - lse) << 16);
                ((u32*)out)[oi] = pack;
            }
        }
    }
}

// ---------------- workspace layout (~68.3 MB) ----------------
static const size_t O_FLAG   = 0;
static const size_t O_CANON  = 4096;       // 3,402,248
static const size_t O_GIT    = 3407872;    // 49,152
static const size_t O_W2P    = 3457024;    // 8,192
static const size_t O_WHHP   = 3465216;    // 24,576
static const size_t O_L1PA   = 3489792;    // 8,192
static const size_t O_L1PB   = 3497984;    // 8,192
static const size_t O_LTPA   = 3506176;    // 8,192
static const size_t O_LTPB   = 3514368;    // 8,192
static const size_t O_DINV   = 3522560;    // 400,000
static const size_t O_DEG    = 3922560;    // 400,000
static const size_t O_ROWPTR = 4322560;    // 400,128
static const size_t O_CURSOR = 4722688;    // 400,000
static const size_t O_BSUM   = 5122688;    // 2,048
static const size_t O_EL     = 5124736;    // 4,000,000
static const size_t O_DL     = 9125888;    // 4,000,000
static const size_t O_EID    = 13125888;   // 4,000,000
static const size_t O_SRC    = 17125888;   // N*64 bf16 (dead after gather_ep2)
static const size_t O_H1     = 29925888;   // N*64 bf16 (dead after conv2)
static const size_t O_UDST   = 17125888;   // N*64 u32 (overlays SRC+H1, written in fused gru)
static const size_t O_NODEF  = 42725888;   // N*128 bf16 (h2; fused gru rewrites in-place as usrc)
// end = 68,325,888

extern "C" void kernel_launch(void* const* d_in, const int* in_sizes, int n_in,
                              void* d_out, int out_size, void* d_ws, size_t ws_size,
                              hipStream_t stream){
    const void* x    = d_in[0];
    const int*  ei   = (const int*)d_in[1];
    const int*  xt   = (const int*)d_in[2];

    char* ws = (char*)d_ws;
    int*   flagp  = (int*)(ws + O_FLAG);
    float* canon  = (float*)(ws + O_CANON);
    float* giT    = (float*)(ws + O_GIT);
    u16*   w2p    = (u16*)(ws + O_W2P);
    u16*   whhp   = (u16*)(ws + O_WHHP);
    u16*   l1pa   = (u16*)(ws + O_L1PA);
    u16*   l1pb   = (u16*)(ws + O_L1PB);
    u16*   ltpa   = (u16*)(ws + O_LTPA);
    u16*   ltpb   = (u16*)(ws + O_LTPB);
    float* dinv   = (float*)(ws + O_DINV);
    int*   deg    = (int*)(ws + O_DEG);
    int*   rowptr = (int*)(ws + O_ROWPTR);
    int*   cursor = (int*)(ws + O_CURSOR);
    int*   bsum   = (int*)(ws + O_BSUM);
    int*   el     = (int*)(ws + O_EL);
    int*   dl     = (int*)(ws + O_DL);
    int*   eid    = (int*)(ws + O_EID);
    u16*   src    = (u16*)(ws + O_SRC);
    u16*   hbuf1  = (u16*)(ws + O_H1);
    u32*   udst   = (u32*)(ws + O_UDST);
    u16*   nodef  = (u16*)(ws + O_NODEF);

    // dtype detect, then ALL table prep in one kernel
    k_detect<<<1, 256, 0, stream>>>((const u16*)x, flagp);
    k_tables<<<B_TOT, 256, 0, stream>>>(flagp,
        x, d_in[3], d_in[4], d_in[5], d_in[6], d_in[7], d_in[8], d_in[9],
        d_in[10], d_in[11], d_in[12], d_in[13], d_in[14], d_in[15], d_in[16], d_in[17],
        canon, w2p, whhp, l1pa, l1pb, ltpa, ltpb, giT);

    const float* cx   = canon + CX;
    const float* cw1  = canon + CW1;
    const float* cb1  = canon + CB1;
    const float* cb2  = canon + CB2;
    const float* cbhh = canon + CBHH;
    const float* cl1b = canon + CL1B;
    const float* cltb = canon + CLTB;
    const float* clfw = canon + CLFW;
    const float* clfb = canon + CLFB;

    // CSR build (once; reused by both GCN layers and the edge kernel)
    hipMemsetAsync(deg, 0, (size_t)N_NODES*4, stream);
    k_hist <<<(N_EDGES+255)/256, 256, 0, stream>>>(ei, deg);
    k_scan1<<<NBLK, 256, 0, stream>>>(deg, rowptr, bsum);
    k_scan2<<<1, 512, 0, stream>>>(bsum);
    k_scan3<<<NBLK, 256, 0, stream>>>(deg, bsum, rowptr, cursor, dinv);
    k_fill <<<(N_EDGES+255)/256, 256, 0, stream>>>(ei, cursor, el, dl, eid);

    // GCN layer 1 (src -> h1, stride 64)
    k_t1s<<<N_NODES*64/256, 256, 0, stream>>>(cx, cw1, dinv, src);
    k_gather_ep<<<N_NODES*32/256, 256, 0, stream>>>(rowptr, el, src, dinv, cb1, hbuf1, 64);

    // GCN layer 2 (h1 -> src -> nodef[+0], stride 128)
    k_conv2<<<(N_NODES/16 + 3)/4, 256, 0, stream>>>(hbuf1, w2p, dinv, src);
    k_gather_ep<<<N_NODES*32/256, 256, 0, stream>>>(rowptr, el, src, dinv, cb2, nodef, 128);

    // GRU + pair precompute fused (nodef -> usrc in-place, udst)
    k_gru<<<(N_NODES/16 + 3)/4, 256, 0, stream>>>(xt, whhp, giT, cbhh,
                                                  nodef, udst, l1pa, l1pb, ltpa, ltpb,
                                                  cl1b, cltb);

    // edge logits + log_softmax (CSR order, scatter by eid)
    k_edge2<<<4096, 256, 0, stream>>>(el, dl, eid, (const u32*)nodef, udst,
                                      clfw, clfb, flagp, d_out);
}

// Round 16
// 428.726 us; speedup vs baseline: 1.7499x; 1.0505x over previous
//
#include <hip/hip_runtime.h>
#include <stdint.h>

#define N_NODES 100000
#define N_EDGES 1000000
#define NBLK 391   // ceil(N_NODES/256)

typedef unsigned short u16;
typedef unsigned int u32;
typedef __attribute__((ext_vector_type(8))) short bshort8;
typedef __attribute__((ext_vector_type(4))) float f32x4;

__device__ __forceinline__ float bf2f(u16 u){ union{float f; u32 i;} x; x.i=((u32)u)<<16; return x.f; }
__device__ __forceinline__ u16 f2bf(float f){ union{float f; u32 i;} x; x.f=f; u32 r = x.i + 0x7FFFu + ((x.i>>16)&1u); return (u16)(r>>16); }

__device__ __forceinline__ float fexp2(float x){
#if __has_builtin(__builtin_amdgcn_exp2f)
    return __builtin_amdgcn_exp2f(x);
#else
    return exp2f(x);
#endif
}
__device__ __forceinline__ float frcp(float x){
#if __has_builtin(__builtin_amdgcn_rcpf)
    return __builtin_amdgcn_rcpf(x);
#else
    return 1.0f/x;
#endif
}
#define LOG2E 1.442695041f

// ---------------- dtype detector (f32 vs bf16 device buffers) ----------------
__global__ void k_detect(const u16* __restrict__ x, int* flagp){
    __shared__ int cnt;
    if(threadIdx.x == 0) cnt = 0;
    __syncthreads();
    int c = 0;
    for(int i = threadIdx.x; i < 2048; i += 256){
        int e = (x[i] >> 7) & 0xFF;
        if(e >= 0x90) c++;
    }
    atomicAdd(&cnt, c);
    __syncthreads();
    if(threadIdx.x == 0) flagp[0] = (cnt > 64) ? 1 : 0;   // 1 = f32, 0 = bf16
}

// canonical f32 table offsets
#define CX    0
#define CW1   800000
#define CB1   800512
#define CW2   800576
#define CB2   804672
#define CEMB  804736
#define CWIH  808832
#define CWHH  821120
#define CBIH  833408
#define CBHH  833600
#define CL1W  833792
#define CL1B  841984
#define CLTW  842048
#define CLTB  850240
#define CLFW  850304
#define CLFB  850560
#define CTOT  850562

__device__ __forceinline__ float ldany(const void* p, int i, int fl){
    return fl ? ((const float*)p)[i] : bf2f(((const u16*)p)[i]);
}

// ---------------- merged tables kernel: convert + 6x packb + gitab ----------------
#define NCONV 3323                  // ceil(CTOT/256)
#define B_W2  (NCONV)               // 16 blocks  (64x64)
#define B_WHH (B_W2 + 16)           // 48 blocks  (64x192)
#define B_L1A (B_WHH + 48)          // 16
#define B_L1B (B_L1A + 16)          // 16
#define B_LTA (B_L1B + 16)          // 16
#define B_LTB (B_LTA + 16)          // 16
#define B_GIT (B_LTB + 16)          // 48 blocks  (64x192)
#define B_TOT (B_GIT + 48)

__device__ __forceinline__ void packb_dev(const void* src, u16* dst,
                                          int K, int N, int ldk, int ldn,
                                          int fl, int i){
    if(i >= K*N) return;
    int k = i / N, n = i % N;
    int kt = k >> 5, kk = k & 31, q = kk >> 3, j = kk & 7;
    int nt = n >> 4, nn = n & 15;
    int KT = K >> 5;
    dst[(((nt*KT + kt)*64) + (q*16 + nn))*8 + j] = f2bf(ldany(src, k*ldk + n*ldn, fl));
}

__global__ void k_tables(const int* __restrict__ flagp,
                         const void* x, const void* w1, const void* b1, const void* w2,
                         const void* b2, const void* emb, const void* wih, const void* whh,
                         const void* bih, const void* bhh, const void* l1w, const void* l1b,
                         const void* ltw, const void* ltb, const void* lfw, const void* lfb,
                         float* __restrict__ canon,
                         u16* __restrict__ w2p, u16* __restrict__ whhp,
                         u16* __restrict__ l1pa, u16* __restrict__ l1pb,
                         u16* __restrict__ ltpa, u16* __restrict__ ltpb,
                         float* __restrict__ giT){
    int b = blockIdx.x, tid = threadIdx.x;
    int fl = *flagp;
    if(b < NCONV){
        int i = b*256 + tid;
        if(i >= CTOT) return;
        const void* p; int off;
        if     (i < CW1 ){ p = x;   off = i;        }
        else if(i < CB1 ){ p = w1;  off = i - CW1;  }
        else if(i < CW2 ){ p = b1;  off = i - CB1;  }
        else if(i < CB2 ){ p = w2;  off = i - CW2;  }
        else if(i < CEMB){ p = b2;  off = i - CB2;  }
        else if(i < CWIH){ p = emb; off = i - CEMB; }
        else if(i < CWHH){ p = wih; off = i - CWIH; }
        else if(i < CBIH){ p = whh; off = i - CWHH; }
        else if(i < CBHH){ p = bih; off = i - CBIH; }
        else if(i < CL1W){ p = bhh; off = i - CBHH; }
        else if(i < CL1B){ p = l1w; off = i - CL1W; }
        else if(i < CLTW){ p = l1b; off = i - CL1B; }
        else if(i < CLTB){ p = ltw; off = i - CLTW; }
        else if(i < CLFW){ p = ltb; off = i - CLTB; }
        else if(i < CLFB){ p = lfw; off = i - CLFW; }
        else             { p = lfb; off = i - CLFB; }
        float v = ldany(p, off, fl);
        canon[i] = (v == v && fabsf(v) < 1e30f) ? v : 0.f;
    }else if(b < B_WHH){
        packb_dev(w2, w2p, 64, 64, 64, 1, fl, (b - B_W2)*256 + tid);
    }else if(b < B_L1A){
        packb_dev(whh, whhp, 64, 192, 1, 64, fl, (b - B_WHH)*256 + tid);
    }else if(b < B_L1B){
        packb_dev(l1w, l1pa, 64, 64, 1, 128, fl, (b - B_L1A)*256 + tid);
    }else if(b < B_LTA){
        packb_dev((const void*)((const char*)l1w + (fl ? 64*4 : 64*2)),
                  l1pb, 64, 64, 1, 128, fl, (b - B_L1B)*256 + tid);
    }else if(b < B_LTB){
        packb_dev(ltw, ltpa, 64, 64, 1, 128, fl, (b - B_LTA)*256 + tid);
    }else if(b < B_GIT){
        packb_dev((const void*)((const char*)ltw + (fl ? 64*4 : 64*2)),
                  ltpb, 64, 64, 1, 128, fl, (b - B_LTB)*256 + tid);
    }else{
        // gi table, transposed: giT[v][g3][col][t];  b_hh folded for r,z (g3<2)
        int i = (b - B_GIT)*256 + tid;
        if(i >= 64*192) return;
        int v = i / 192, g = i % 192;
        float acc = ldany(bih, g, fl) + ((g < 128) ? ldany(bhh, g, fl) : 0.0f);
        for(int f = 0; f < 64; f++) acc += ldany(wih, g*64 + f, fl) * ldany(emb, v*64 + f, fl);
        int g3 = g >> 6, rem = g & 63, t = rem >> 4, col = rem & 15;
        giT[(((size_t)v*3 + g3)*16 + col)*4 + t] = acc;
    }
}

// ---------------- CSR build: histogram -> scan -> fill (el, dl, eid) ----------------
__global__ void k_hist(const int* __restrict__ ei, int* __restrict__ deg){
    int e = blockIdx.x*256 + threadIdx.x;
    if(e < N_EDGES) atomicAdd(&deg[ei[N_EDGES + e]], 1);
}
__global__ void k_scan1(const int* __restrict__ deg, int* __restrict__ rowptr,
                        int* __restrict__ bsum){
    __shared__ int sh[256];
    int tid = threadIdx.x;
    int i = blockIdx.x*256 + tid;
    int v = (i < N_NODES) ? deg[i] : 0;
    sh[tid] = v;
    __syncthreads();
    for(int off = 1; off < 256; off <<= 1){
        int t = (tid >= off) ? sh[tid - off] : 0;
        __syncthreads();
        sh[tid] += t;
        __syncthreads();
    }
    if(i < N_NODES) rowptr[i] = sh[tid] - v;
    if(tid == 255) bsum[blockIdx.x] = sh[255];
}
__global__ void k_scan2(int* __restrict__ bsum){
    __shared__ int sh[512];
    int tid = threadIdx.x;
    int v = (tid < NBLK) ? bsum[tid] : 0;
    sh[tid] = v;
    __syncthreads();
    for(int off = 1; off < 512; off <<= 1){
        int t = (tid >= off) ? sh[tid - off] : 0;
        __syncthreads();
        sh[tid] += t;
        __syncthreads();
    }
    if(tid < NBLK) bsum[tid] = sh[tid] - v;
}
// scan3 + xs = f32 x*dinv (8 feats/node; rank-8 trick, FULL f32 for replay-stable numerics)
__global__ void k_scan3(const int* __restrict__ deg, const int* __restrict__ bsum,
                        int* __restrict__ rowptr, int* __restrict__ cursor,
                        float* __restrict__ dinv, const float* __restrict__ cx,
                        float* __restrict__ xs){
    int i = blockIdx.x*256 + threadIdx.x;
    if(i < N_NODES){
        int r = rowptr[i] + bsum[i >> 8];
        rowptr[i] = r;
        cursor[i] = r;
        float dv = rsqrtf((float)deg[i] + 1.0f);   // +1 self loop
        dinv[i] = dv;
        const float* xr = cx + (size_t)i*8;
        float* xo = xs + (size_t)i*8;
        #pragma unroll
        for(int k = 0; k < 8; k++) xo[k] = xr[k]*dv;
    }
    if(i == 0) rowptr[N_NODES] = N_EDGES;
}
__global__ void k_fill(const int* __restrict__ ei, int* __restrict__ cursor,
                       int* __restrict__ el, int* __restrict__ dl, int* __restrict__ eid){
    int e = blockIdx.x*256 + threadIdx.x;
    if(e < N_EDGES){
        int s = ei[e], d = ei[N_EDGES + e];
        int pos = atomicAdd(&cursor[d], 1);
        el[pos] = s;
        dl[pos] = d;
        eid[pos] = e;
    }
}

// ---------------- layer-1 gather on 8 feats (f32): agg8[n] = xs[n] + sum xs[neighbors] ----------------
__global__ __launch_bounds__(256)
void k_gather8(const int* __restrict__ rowptr, const int* __restrict__ el,
               const float* __restrict__ xs, float* __restrict__ agg8){
    int gid = blockIdx.x*256 + threadIdx.x;
    int node = gid >> 2, fp = (gid & 3)*2;
    if(node >= N_NODES) return;               // tail guard (R14 crash fix)
    int beg = rowptr[node], end = rowptr[node + 1];
    float2 self = *(const float2*)(xs + (size_t)node*8 + fp);
    float a0 = self.x, a1 = self.y;
    int i = beg;
    for(; i + 4 <= end; i += 4){
        int s0 = el[i], s1 = el[i+1], s2 = el[i+2], s3 = el[i+3];
        float2 v0 = *(const float2*)(xs + (size_t)s0*8 + fp);
        float2 v1 = *(const float2*)(xs + (size_t)s1*8 + fp);
        float2 v2 = *(const float2*)(xs + (size_t)s2*8 + fp);
        float2 v3 = *(const float2*)(xs + (size_t)s3*8 + fp);
        a0 += v0.x; a1 += v0.y;
        a0 += v1.x; a1 += v1.y;
        a0 += v2.x; a1 += v2.y;
        a0 += v3.x; a1 += v3.y;
    }
    for(; i < end; i++){
        float2 v = *(const float2*)(xs + (size_t)el[i]*8 + fp);
        a0 += v.x; a1 += v.y;
    }
    float2 o; o.x = a0; o.y = a1;
    *(float2*)(agg8 + (size_t)node*8 + fp) = o;
}

// ---------------- conv1 epilogue: h1 = bf16(relu(dinv*(agg8 @ W1) + b1)) ----------------
__global__ void k_conv1(const float* __restrict__ agg8, const float* __restrict__ cw1,
                        const float* __restrict__ dinv, const float* __restrict__ b1,
                        u16* __restrict__ h1){
    __shared__ float w[512];
    int t = threadIdx.x;
    w[t]       = cw1[t];
    w[t + 256] = cw1[t + 256];
    __syncthreads();
    int i = blockIdx.x*256 + t;      // grid exactly N*64/256
    int n = i >> 6, f = i & 63;
    const float* ar = agg8 + (size_t)n*8;
    float acc = 0.f;
    #pragma unroll
    for(int k = 0; k < 8; k++) acc += ar[k] * w[k*64 + f];
    h1[(size_t)n*64 + f] = f2bf(fmaxf(dinv[n]*acc + b1[f], 0.f));
}

// ---------------- layer-2 fused gather + epilogue: u32 loads, 2 feats/thread ----------------
__global__ __launch_bounds__(256)
void k_gather_ep(const int* __restrict__ rowptr, const int* __restrict__ el,
                 const u16* __restrict__ src, const float* __restrict__ dinv,
                 const float* __restrict__ b, u16* __restrict__ h, int ostride){
    int gid = blockIdx.x*256 + threadIdx.x;   // grid exactly N*32/256
    int node = gid >> 5, fp = (gid & 31)*2;
    int beg = rowptr[node], end = rowptr[node + 1];
    u32 self = *(const u32*)(src + (size_t)node*64 + fp);
    float acc0 = bf2f((u16)self), acc1 = bf2f((u16)(self >> 16));
    int i = beg;
    for(; i + 4 <= end; i += 4){
        int s0 = el[i], s1 = el[i+1], s2 = el[i+2], s3 = el[i+3];
        u32 a0 = *(const u32*)(src + (size_t)s0*64 + fp);
        u32 a1 = *(const u32*)(src + (size_t)s1*64 + fp);
        u32 a2 = *(const u32*)(src + (size_t)s2*64 + fp);
        u32 a3 = *(const u32*)(src + (size_t)s3*64 + fp);
        acc0 += bf2f((u16)a0); acc1 += bf2f((u16)(a0 >> 16));
        acc0 += bf2f((u16)a1); acc1 += bf2f((u16)(a1 >> 16));
        acc0 += bf2f((u16)a2); acc1 += bf2f((u16)(a2 >> 16));
        acc0 += bf2f((u16)a3); acc1 += bf2f((u16)(a3 >> 16));
    }
    for(; i < end; i++){
        u32 a = *(const u32*)(src + (size_t)el[i]*64 + fp);
        acc0 += bf2f((u16)a); acc1 += bf2f((u16)(a >> 16));
    }
    float dv = dinv[node];
    float r0 = fmaxf(dv*acc0 + b[fp],     0.f);
    float r1 = fmaxf(dv*acc1 + b[fp + 1], 0.f);
    *(u32*)(h + (size_t)node*ostride + fp) = (u32)f2bf(r0) | ((u32)f2bf(r1) << 16);
}

// ---------------- conv2 GEMM: src = bf16((h1 @ W2) * dinv) ----------------
__global__ __launch_bounds__(256, 4)
void k_conv2(const u16* __restrict__ h, const u16* __restrict__ w2p,
             const float* __restrict__ dinv, u16* __restrict__ src){
    int wv = threadIdx.x >> 6, lane = threadIdx.x & 63;
    int g = blockIdx.x*4 + wv;
    if(g >= N_NODES/16) return;
    int q = lane >> 4, m = lane & 15, col = m;
    bshort8 a0 = *(const bshort8*)(h + (g*16 + m)*64 + q*8);
    bshort8 a1 = *(const bshort8*)(h + (g*16 + m)*64 + 32 + q*8);
    f32x4 acc[4];
    #pragma unroll
    for(int nt = 0; nt < 4; nt++){
        f32x4 c = {0.f,0.f,0.f,0.f};
        c = __builtin_amdgcn_mfma_f32_16x16x32_bf16(a0, *(const bshort8*)(w2p + ((nt*2+0)*64 + lane)*8), c, 0,0,0);
        c = __builtin_amdgcn_mfma_f32_16x16x32_bf16(a1, *(const bshort8*)(w2p + ((nt*2+1)*64 + lane)*8), c, 0,0,0);
        acc[nt] = c;
    }
    #pragma unroll
    for(int nt = 0; nt < 4; nt++)
        #pragma unroll
        for(int r = 0; r < 4; r++){
            int node = g*16 + q*4 + r;
            src[node*64 + nt*16 + col] = f2bf(acc[nt][r] * dinv[node]);
        }
}

// ---------------- GRU + pair precompute, fused ----------------
__global__ __launch_bounds__(256, 4)
void k_gru(const int* __restrict__ xt, const u16* __restrict__ whhp,
           const float* __restrict__ giT, const float* __restrict__ bhh,
           u16* nodef, u32* __restrict__ udst,
           const u16* __restrict__ w1a, const u16* __restrict__ w1b,
           const u16* __restrict__ wta, const u16* __restrict__ wtb,
           const float* __restrict__ b1, const float* __restrict__ bt){
    __shared__ __align__(16) u16 wsh[12288];        // 24 KB Whh frags
    __shared__ __align__(16) u16 hsh[4][16][72];    // bf16 h tile
    int tid = threadIdx.x;
    {
        const uint4* s = (const uint4*)whhp;
        uint4* d = (uint4*)wsh;
        #pragma unroll
        for(int i = 0; i < 6; i++) d[tid + 256*i] = s[tid + 256*i];
    }
    __syncthreads();

    int wv = tid >> 6, lane = tid & 63;
    int q = lane >> 4, m = lane & 15, col = m;
    int g = blockIdx.x*4 + wv;
    bool active = g < (N_NODES/16);
    int nb = active ? g*16 : 0;

    float bhhn[4];
    #pragma unroll
    for(int t = 0; t < 4; t++) bhhn[t] = bhh[128 + t*16 + col];

    const bshort8* wl = (const bshort8*)wsh;
    const u16* hp = &hsh[wv][m][0];

    float hc[4][4];
    #pragma unroll
    for(int t = 0; t < 4; t++)
        #pragma unroll
        for(int r = 0; r < 4; r++) hc[t][r] = 0.f;

    for(int s = 0; s < 10; s++){
        #pragma unroll
        for(int t = 0; t < 4; t++)
            #pragma unroll
            for(int r = 0; r < 4; r++)
                hsh[wv][q*4 + r][t*16 + col] = f2bf(hc[t][r]);

        asm volatile("" ::: "memory");
        bshort8 a0 = *(const bshort8*)(hp + q*8);
        bshort8 a1 = *(const bshort8*)(hp + 32 + q*8);

        int tok[4];
        #pragma unroll
        for(int r = 0; r < 4; r++) tok[r] = xt[(nb + q*4 + r)*10 + s] & 63;

        f32x4 acc[12];
        #pragma unroll
        for(int nt = 0; nt < 12; nt++){
            f32x4 c = {0.f,0.f,0.f,0.f};
            c = __builtin_amdgcn_mfma_f32_16x16x32_bf16(a0, wl[(nt*2+0)*64 + lane], c, 0,0,0);
            c = __builtin_amdgcn_mfma_f32_16x16x32_bf16(a1, wl[(nt*2+1)*64 + lane], c, 0,0,0);
            acc[nt] = c;
        }

        #pragma unroll
        for(int r = 0; r < 4; r++){
            const float4* gp = (const float4*)(giT + (size_t)tok[r]*192);
            float4 gr = gp[col];
            float4 gz = gp[16 + col];
            float4 gn = gp[32 + col];
            #pragma unroll
            for(int t = 0; t < 4; t++){
                float gir = ((const float*)&gr)[t];
                float giz = ((const float*)&gz)[t];
                float gin = ((const float*)&gn)[t];
                float rr = frcp(1.0f + fexp2(-LOG2E*(gir + acc[t][r])));
                float zz = frcp(1.0f + fexp2(-LOG2E*(giz + acc[4+t][r])));
                float narg = gin + rr*(acc[8+t][r] + bhhn[t]);
                float e2 = fexp2(2.0f*LOG2E*narg);
                float nn = 1.0f - 2.0f*frcp(e2 + 1.0f);
                hc[t][r] = nn + zz*(hc[t][r] - nn);
            }
        }
        asm volatile("" ::: "memory");
    }

    // ---- fused pair precompute ----
    #pragma unroll
    for(int t = 0; t < 4; t++)
        #pragma unroll
        for(int r = 0; r < 4; r++)
            hsh[wv][q*4 + r][t*16 + col] = f2bf(hc[t][r]);   // txt tile
    asm volatile("" ::: "memory");
    bshort8 at0 = *(const bshort8*)(hp + q*8);
    bshort8 at1 = *(const bshort8*)(hp + 32 + q*8);
    const u16* row = nodef + (size_t)(nb + m)*128;           // h2 rows
    bshort8 ah0 = *(const bshort8*)(row + q*8);
    bshort8 ah1 = *(const bshort8*)(row + 32 + q*8);

    u32* usrc = (u32*)nodef;
    #pragma unroll
    for(int nt = 0; nt < 4; nt++){
        f32x4 cu1 = {0.f,0.f,0.f,0.f}, cu2 = {0.f,0.f,0.f,0.f};
        f32x4 cv1 = {0.f,0.f,0.f,0.f}, cv2 = {0.f,0.f,0.f,0.f};
        cu1 = __builtin_amdgcn_mfma_f32_16x16x32_bf16(ah0, *(const bshort8*)(w1a + ((nt*2+0)*64 + lane)*8), cu1, 0,0,0);
        cu1 = __builtin_amdgcn_mfma_f32_16x16x32_bf16(ah1, *(const bshort8*)(w1a + ((nt*2+1)*64 + lane)*8), cu1, 0,0,0);
        cu2 = __builtin_amdgcn_mfma_f32_16x16x32_bf16(ah0, *(const bshort8*)(w1b + ((nt*2+0)*64 + lane)*8), cu2, 0,0,0);
        cu2 = __builtin_amdgcn_mfma_f32_16x16x32_bf16(ah1, *(const bshort8*)(w1b + ((nt*2+1)*64 + lane)*8), cu2, 0,0,0);
        cv1 = __builtin_amdgcn_mfma_f32_16x16x32_bf16(at0, *(const bshort8*)(wta + ((nt*2+0)*64 + lane)*8), cv1, 0,0,0);
        cv1 = __builtin_amdgcn_mfma_f32_16x16x32_bf16(at1, *(const bshort8*)(wta + ((nt*2+1)*64 + lane)*8), cv1, 0,0,0);
        cv2 = __builtin_amdgcn_mfma_f32_16x16x32_bf16(at0, *(const bshort8*)(wtb + ((nt*2+0)*64 + lane)*8), cv2, 0,0,0);
        cv2 = __builtin_amdgcn_mfma_f32_16x16x32_bf16(at1, *(const bshort8*)(wtb + ((nt*2+1)*64 + lane)*8), cv2, 0,0,0);
        if(active){
            int f = nt*16 + col;
            float b1f = b1[f], btf = bt[f];
            #pragma unroll
            for(int r = 0; r < 4; r++){
                int node = nb + q*4 + r;
                u32 pa = (u32)f2bf(cu1[r] + b1f) | ((u32)f2bf(cv1[r] + btf) << 16);
                u32 pb = (u32)f2bf(cu2[r]) | ((u32)f2bf(cv2[r]) << 16);
                usrc[(size_t)node*64 + f] = pa;
                udst[(size_t)node*64 + f] = pb;
            }
        }
    }
}

// ---------------- edge kernel: uint4 row loads; 4 edges/wave, 16 lanes/edge ----------------
__global__ __launch_bounds__(256, 6)
void k_edge2(const int* __restrict__ el, const int* __restrict__ dl, const int* __restrict__ eid,
             const u32* __restrict__ usrc, const u32* __restrict__ udst,
             const float* __restrict__ wfin, const float* __restrict__ bfin,
             const int* __restrict__ flagp, void* __restrict__ out){
    int tid = threadIdx.x;
    int lane = tid & 63;
    int q = lane >> 4, f0 = lane & 15;
    int wid = (blockIdx.x*256 + tid) >> 6;
    int nwv = (gridDim.x*256) >> 6;
    int fl = *flagp;

    float wp0[4], wp1[4], wt0[4], wt1[4];
    #pragma unroll
    for(int t = 0; t < 4; t++){
        int f = 4*f0 + t;
        wp0[t] = wfin[f];        wt0[t] = wfin[64 + f];
        wp1[t] = wfin[128 + f];  wt1[t] = wfin[192 + f];
    }
    float bf0 = bfin[0], bf1 = bfin[1];

    for(int grp = wid; grp < N_EDGES/4; grp += nwv){
        int e = grp*4 + q;
        int s = el[e], d = dl[e];
        uint4 us4 = *((const uint4*)(usrc + (size_t)s*64) + f0);
        uint4 ud4 = *((const uint4*)(udst + (size_t)d*64) + f0);
        u32 us[4] = {us4.x, us4.y, us4.z, us4.w};
        u32 ud[4] = {ud4.x, ud4.y, ud4.z, ud4.w};
        float s0 = 0.f, s1 = 0.f;
        #pragma unroll
        for(int t = 0; t < 4; t++){
            float u1 = __uint_as_float(us[t] << 16);
            float v1 = __uint_as_float(us[t] & 0xffff0000u);
            float u2 = __uint_as_float(ud[t] << 16);
            float v2 = __uint_as_float(ud[t] & 0xffff0000u);
            float xp = fmaxf(u1 + u2, 0.f);
            float xq = fmaxf(v1 + v2, 0.f);
            s0 += xp*wp0[t] + xq*wt0[t];
            s1 += xp*wp1[t] + xq*wt1[t];
        }
        #pragma unroll
        for(int msk = 1; msk < 16; msk <<= 1){
            s0 += __shfl_xor(s0, msk, 64);
            s1 += __shfl_xor(s1, msk, 64);
        }
        if(f0 == 0){
            float a = s0 + bf0, b = s1 + bf1;
            float mx = fmaxf(a, b);
            float lse = mx + __logf(__expf(a - mx) + __expf(b - mx));
            int oi = eid[e];
            if(fl){
                float2 v; v.x = a - lse; v.y = b - lse;
                ((float2*)out)[oi] = v;
            }else{
                u32 pack = (u32)f2bf(a - lse) | ((u32)f2bf(b - lse) << 16);
                ((u32*)out)[oi] = pack;
            }
        }
    }
}

// ---------------- workspace layout (68.3 MB) ----------------
static const size_t O_FLAG   = 0;
static const size_t O_CANON  = 4096;       // 3,402,248
static const size_t O_GIT    = 3407872;    // 49,152
static const size_t O_W2P    = 3457024;    // 8,192
static const size_t O_WHHP   = 3465216;    // 24,576
static const size_t O_L1PA   = 3489792;    // 8,192
static const size_t O_L1PB   = 3497984;    // 8,192
static const size_t O_LTPA   = 3506176;    // 8,192
static const size_t O_LTPB   = 3514368;    // 8,192
static const size_t O_DINV   = 3522560;    // 400,000
static const size_t O_DEG    = 3922560;    // 400,000
static const size_t O_ROWPTR = 4322560;    // 400,128
static const size_t O_CURSOR = 4722688;    // 400,000
static const size_t O_BSUM   = 5122688;    // 2,048
static const size_t O_EL     = 5124736;    // 4,000,000
static const size_t O_DL     = 9125888;    // 4,000,000
static const size_t O_EID    = 13125888;   // 4,000,000
static const size_t O_SRC    = 17125888;   // N*64 bf16 (written by conv2; dead after gather_ep)
static const size_t O_XS     = 17125888;   // N*8 f32 = 3,200,000 (overlays SRC; dead before conv2 writes)
static const size_t O_AGG8   = 20325888;   // N*8 f32 = 3,200,000 (overlays SRC; dead before conv2 writes)
static const size_t O_H1     = 29925888;   // N*64 bf16 (dead after conv2)
static const size_t O_UDST   = 17125888;   // N*64 u32 (overlays SRC+H1, written in fused gru)
static const size_t O_NODEF  = 42725888;   // N*128 bf16 (h2; fused gru rewrites in-place as usrc)
// end = 68,325,888

extern "C" void kernel_launch(void* const* d_in, const int* in_sizes, int n_in,
                              void* d_out, int out_size, void* d_ws, size_t ws_size,
                              hipStream_t stream){
    const void* x    = d_in[0];
    const int*  ei   = (const int*)d_in[1];
    const int*  xt   = (const int*)d_in[2];

    char* ws = (char*)d_ws;
    int*   flagp  = (int*)(ws + O_FLAG);
    float* canon  = (float*)(ws + O_CANON);
    float* giT    = (float*)(ws + O_GIT);
    u16*   w2p    = (u16*)(ws + O_W2P);
    u16*   whhp   = (u16*)(ws + O_WHHP);
    u16*   l1pa   = (u16*)(ws + O_L1PA);
    u16*   l1pb   = (u16*)(ws + O_L1PB);
    u16*   ltpa   = (u16*)(ws + O_LTPA);
    u16*   ltpb   = (u16*)(ws + O_LTPB);
    float* dinv   = (float*)(ws + O_DINV);
    int*   deg    = (int*)(ws + O_DEG);
    int*   rowptr = (int*)(ws + O_ROWPTR);
    int*   cursor = (int*)(ws + O_CURSOR);
    int*   bsum   = (int*)(ws + O_BSUM);
    int*   el     = (int*)(ws + O_EL);
    int*   dl     = (int*)(ws + O_DL);
    int*   eid    = (int*)(ws + O_EID);
    u16*   src    = (u16*)(ws + O_SRC);
    float* xs     = (float*)(ws + O_XS);
    float* agg8   = (float*)(ws + O_AGG8);
    u16*   hbuf1  = (u16*)(ws + O_H1);
    u32*   udst   = (u32*)(ws + O_UDST);
    u16*   nodef  = (u16*)(ws + O_NODEF);

    // dtype detect, then ALL table prep in one kernel
    k_detect<<<1, 256, 0, stream>>>((const u16*)x, flagp);
    k_tables<<<B_TOT, 256, 0, stream>>>(flagp,
        x, d_in[3], d_in[4], d_in[5], d_in[6], d_in[7], d_in[8], d_in[9],
        d_in[10], d_in[11], d_in[12], d_in[13], d_in[14], d_in[15], d_in[16], d_in[17],
        canon, w2p, whhp, l1pa, l1pb, ltpa, ltpb, giT);

    const float* cx   = canon + CX;
    const float* cw1  = canon + CW1;
    const float* cb1  = canon + CB1;
    const float* cb2  = canon + CB2;
    const float* cbhh = canon + CBHH;
    const float* cl1b = canon + CL1B;
    const float* cltb = canon + CLTB;
    const float* clfw = canon + CLFW;
    const float* clfb = canon + CLFB;

    // CSR build (scan3 also emits xs = x*dinv in f32)
    hipMemsetAsync(deg, 0, (size_t)N_NODES*4, stream);
    k_hist <<<(N_EDGES+255)/256, 256, 0, stream>>>(ei, deg);
    k_scan1<<<NBLK, 256, 0, stream>>>(deg, rowptr, bsum);
    k_scan2<<<1, 512, 0, stream>>>(bsum);
    k_scan3<<<NBLK, 256, 0, stream>>>(deg, bsum, rowptr, cursor, dinv, cx, xs);
    k_fill <<<(N_EDGES+255)/256, 256, 0, stream>>>(ei, cursor, el, dl, eid);

    // GCN layer 1 via rank-8 aggregation (f32): xs -> agg8 -> h1
    k_gather8<<<(N_NODES*4 + 255)/256, 256, 0, stream>>>(rowptr, el, xs, agg8);
    k_conv1<<<N_NODES*64/256, 256, 0, stream>>>(agg8, cw1, dinv, cb1, hbuf1);

    // GCN layer 2 (h1 -> src -> nodef[+0], stride 128)
    k_conv2<<<(N_NODES/16 + 3)/4, 256, 0, stream>>>(hbuf1, w2p, dinv, src);
    k_gather_ep<<<N_NODES*32/256, 256, 0, stream>>>(rowptr, el, src, dinv, cb2, nodef, 128);

    // GRU + pair precompute fused (nodef -> usrc in-place, udst)
    k_gru<<<(N_NODES/16 + 3)/4, 256, 0, stream>>>(xt, whhp, giT, cbhh,
                                                  nodef, udst, l1pa, l1pb, ltpa, ltpb,
                                                  cl1b, cltb);

    // edge logits + log_softmax (CSR order, scatter by eid)
    k_edge2<<<4096, 256, 0, stream>>>(el, dl, eid, (const u32*)nodef, udst,
                                      clfw, clfb, flagp, d_out);
}

// Round 17
// 424.092 us; speedup vs baseline: 1.7690x; 1.0109x over previous
//
#include <hip/hip_runtime.h>
#include <stdint.h>

#define N_NODES 100000
#define N_EDGES 1000000
#define NBLK 391   // ceil(N_NODES/256)

typedef unsigned short u16;
typedef unsigned int u32;
typedef __attribute__((ext_vector_type(8))) short bshort8;
typedef __attribute__((ext_vector_type(4))) float f32x4;

__device__ __forceinline__ float bf2f(u16 u){ union{float f; u32 i;} x; x.i=((u32)u)<<16; return x.f; }
__device__ __forceinline__ u16 f2bf(float f){ union{float f; u32 i;} x; x.f=f; u32 r = x.i + 0x7FFFu + ((x.i>>16)&1u); return (u16)(r>>16); }

__device__ __forceinline__ float fexp2(float x){
#if __has_builtin(__builtin_amdgcn_exp2f)
    return __builtin_amdgcn_exp2f(x);
#else
    return exp2f(x);
#endif
}
__device__ __forceinline__ float frcp(float x){
#if __has_builtin(__builtin_amdgcn_rcpf)
    return __builtin_amdgcn_rcpf(x);
#else
    return 1.0f/x;
#endif
}
#define LOG2E 1.442695041f

// ---------------- dtype detector (f32 vs bf16 device buffers) ----------------
__global__ void k_detect(const u16* __restrict__ x, int* flagp){
    __shared__ int cnt;
    if(threadIdx.x == 0) cnt = 0;
    __syncthreads();
    int c = 0;
    for(int i = threadIdx.x; i < 2048; i += 256){
        int e = (x[i] >> 7) & 0xFF;
        if(e >= 0x90) c++;
    }
    atomicAdd(&cnt, c);
    __syncthreads();
    if(threadIdx.x == 0) flagp[0] = (cnt > 64) ? 1 : 0;   // 1 = f32, 0 = bf16
}

// canonical f32 table offsets
#define CX    0
#define CW1   800000
#define CB1   800512
#define CW2   800576
#define CB2   804672
#define CEMB  804736
#define CWIH  808832
#define CWHH  821120
#define CBIH  833408
#define CBHH  833600
#define CL1W  833792
#define CL1B  841984
#define CLTW  842048
#define CLTB  850240
#define CLFW  850304
#define CLFB  850560
#define CTOT  850562

__device__ __forceinline__ float ldany(const void* p, int i, int fl){
    return fl ? ((const float*)p)[i] : bf2f(((const u16*)p)[i]);
}

// ---------------- merged tables kernel: convert + 6x packb + gitab + hist ----------------
#define NCONV 3323                  // ceil(CTOT/256)
#define B_W2  (NCONV)               // 16 blocks  (64x64)
#define B_WHH (B_W2 + 16)           // 48 blocks  (64x192)
#define B_L1A (B_WHH + 48)          // 16
#define B_L1B (B_L1A + 16)          // 16
#define B_LTA (B_L1B + 16)          // 16
#define B_LTB (B_LTA + 16)          // 16
#define B_GIT (B_LTB + 16)          // 48 blocks  (64x192)
#define B_HIST (B_GIT + 48)         // 3907 blocks (1M edges)
#define B_TOT (B_HIST + 3907)

__device__ __forceinline__ void packb_dev(const void* src, u16* dst,
                                          int K, int N, int ldk, int ldn,
                                          int fl, int i){
    if(i >= K*N) return;
    int k = i / N, n = i % N;
    int kt = k >> 5, kk = k & 31, q = kk >> 3, j = kk & 7;
    int nt = n >> 4, nn = n & 15;
    int KT = K >> 5;
    dst[(((nt*KT + kt)*64) + (q*16 + nn))*8 + j] = f2bf(ldany(src, k*ldk + n*ldn, fl));
}

__global__ void k_tables(const int* __restrict__ flagp,
                         const void* x, const void* w1, const void* b1, const void* w2,
                         const void* b2, const void* emb, const void* wih, const void* whh,
                         const void* bih, const void* bhh, const void* l1w, const void* l1b,
                         const void* ltw, const void* ltb, const void* lfw, const void* lfb,
                         const int* __restrict__ ei, int* __restrict__ deg,
                         float* __restrict__ canon,
                         u16* __restrict__ w2p, u16* __restrict__ whhp,
                         u16* __restrict__ l1pa, u16* __restrict__ l1pb,
                         u16* __restrict__ ltpa, u16* __restrict__ ltpb,
                         float* __restrict__ giT){
    int b = blockIdx.x, tid = threadIdx.x;
    int fl = *flagp;
    if(b < NCONV){
        int i = b*256 + tid;
        if(i >= CTOT) return;
        const void* p; int off;
        if     (i < CW1 ){ p = x;   off = i;        }
        else if(i < CB1 ){ p = w1;  off = i - CW1;  }
        else if(i < CW2 ){ p = b1;  off = i - CB1;  }
        else if(i < CB2 ){ p = w2;  off = i - CW2;  }
        else if(i < CEMB){ p = b2;  off = i - CB2;  }
        else if(i < CWIH){ p = emb; off = i - CEMB; }
        else if(i < CWHH){ p = wih; off = i - CWIH; }
        else if(i < CBIH){ p = whh; off = i - CWHH; }
        else if(i < CBHH){ p = bih; off = i - CBIH; }
        else if(i < CL1W){ p = bhh; off = i - CBHH; }
        else if(i < CL1B){ p = l1w; off = i - CL1W; }
        else if(i < CLTW){ p = l1b; off = i - CL1B; }
        else if(i < CLTB){ p = ltw; off = i - CLTW; }
        else if(i < CLFW){ p = ltb; off = i - CLTB; }
        else if(i < CLFB){ p = lfw; off = i - CLFW; }
        else             { p = lfb; off = i - CLFB; }
        float v = ldany(p, off, fl);
        canon[i] = (v == v && fabsf(v) < 1e30f) ? v : 0.f;
    }else if(b < B_WHH){
        packb_dev(w2, w2p, 64, 64, 64, 1, fl, (b - B_W2)*256 + tid);
    }else if(b < B_L1A){
        packb_dev(whh, whhp, 64, 192, 1, 64, fl, (b - B_WHH)*256 + tid);
    }else if(b < B_L1B){
        packb_dev(l1w, l1pa, 64, 64, 1, 128, fl, (b - B_L1A)*256 + tid);
    }else if(b < B_LTA){
        packb_dev((const void*)((const char*)l1w + (fl ? 64*4 : 64*2)),
                  l1pb, 64, 64, 1, 128, fl, (b - B_L1B)*256 + tid);
    }else if(b < B_LTB){
        packb_dev(ltw, ltpa, 64, 64, 1, 128, fl, (b - B_LTA)*256 + tid);
    }else if(b < B_GIT){
        packb_dev((const void*)((const char*)ltw + (fl ? 64*4 : 64*2)),
                  ltpb, 64, 64, 1, 128, fl, (b - B_LTB)*256 + tid);
    }else if(b < B_HIST){
        // gi table, transposed: giT[v][g3][col][t];  b_hh folded for r,z (g3<2)
        int i = (b - B_GIT)*256 + tid;
        if(i >= 64*192) return;
        int v = i / 192, g = i % 192;
        float acc = ldany(bih, g, fl) + ((g < 128) ? ldany(bhh, g, fl) : 0.0f);
        for(int f = 0; f < 64; f++) acc += ldany(wih, g*64 + f, fl) * ldany(emb, v*64 + f, fl);
        int g3 = g >> 6, rem = g & 63, t = rem >> 4, col = rem & 15;
        giT[(((size_t)v*3 + g3)*16 + col)*4 + t] = acc;
    }else{
        // degree histogram (deg pre-zeroed by memset before this kernel)
        int e = (b - B_HIST)*256 + tid;
        if(e < N_EDGES) atomicAdd(&deg[ei[N_EDGES + e]], 1);
    }
}

// ---------------- CSR build: scan -> fill (el, dl, eid) ----------------
__global__ void k_scan1(const int* __restrict__ deg, int* __restrict__ rowptr,
                        int* __restrict__ bsum){
    __shared__ int sh[256];
    int tid = threadIdx.x;
    int i = blockIdx.x*256 + tid;
    int v = (i < N_NODES) ? deg[i] : 0;
    sh[tid] = v;
    __syncthreads();
    for(int off = 1; off < 256; off <<= 1){
        int t = (tid >= off) ? sh[tid - off] : 0;
        __syncthreads();
        sh[tid] += t;
        __syncthreads();
    }
    if(i < N_NODES) rowptr[i] = sh[tid] - v;
    if(tid == 255) bsum[blockIdx.x] = sh[255];
}
__global__ void k_scan2(int* __restrict__ bsum){
    __shared__ int sh[512];
    int tid = threadIdx.x;
    int v = (tid < NBLK) ? bsum[tid] : 0;
    sh[tid] = v;
    __syncthreads();
    for(int off = 1; off < 512; off <<= 1){
        int t = (tid >= off) ? sh[tid - off] : 0;
        __syncthreads();
        sh[tid] += t;
        __syncthreads();
    }
    if(tid < NBLK) bsum[tid] = sh[tid] - v;
}
// scan3 + xs = f32 x*dinv (8 feats/node; rank-8 trick, f32 for replay-stable numerics)
__global__ void k_scan3(const int* __restrict__ deg, const int* __restrict__ bsum,
                        int* __restrict__ rowptr, int* __restrict__ cursor,
                        float* __restrict__ dinv, const float* __restrict__ cx,
                        float* __restrict__ xs){
    int i = blockIdx.x*256 + threadIdx.x;
    if(i < N_NODES){
        int r = rowptr[i] + bsum[i >> 8];
        rowptr[i] = r;
        cursor[i] = r;
        float dv = rsqrtf((float)deg[i] + 1.0f);   // +1 self loop
        dinv[i] = dv;
        const float* xr = cx + (size_t)i*8;
        float* xo = xs + (size_t)i*8;
        #pragma unroll
        for(int k = 0; k < 8; k++) xo[k] = xr[k]*dv;
    }
    if(i == 0) rowptr[N_NODES] = N_EDGES;
}
__global__ void k_fill(const int* __restrict__ ei, int* __restrict__ cursor,
                       int* __restrict__ el, int* __restrict__ dl, int* __restrict__ eid){
    int e = blockIdx.x*256 + threadIdx.x;
    if(e < N_EDGES){
        int s = ei[e], d = ei[N_EDGES + e];
        int pos = atomicAdd(&cursor[d], 1);
        el[pos] = s;
        dl[pos] = d;
        eid[pos] = e;
    }
}

// ---------------- layer-1 gather on 8 feats (f32): agg8[n] = xs[n] + sum xs[neighbors] ----------------
__global__ __launch_bounds__(256)
void k_gather8(const int* __restrict__ rowptr, const int* __restrict__ el,
               const float* __restrict__ xs, float* __restrict__ agg8){
    int gid = blockIdx.x*256 + threadIdx.x;
    int node = gid >> 2, fp = (gid & 3)*2;
    if(node >= N_NODES) return;               // tail guard
    int beg = rowptr[node], end = rowptr[node + 1];
    float2 self = *(const float2*)(xs + (size_t)node*8 + fp);
    float a0 = self.x, a1 = self.y;
    int i = beg;
    for(; i + 4 <= end; i += 4){
        int s0 = el[i], s1 = el[i+1], s2 = el[i+2], s3 = el[i+3];
        float2 v0 = *(const float2*)(xs + (size_t)s0*8 + fp);
        float2 v1 = *(const float2*)(xs + (size_t)s1*8 + fp);
        float2 v2 = *(const float2*)(xs + (size_t)s2*8 + fp);
        float2 v3 = *(const float2*)(xs + (size_t)s3*8 + fp);
        a0 += v0.x; a1 += v0.y;
        a0 += v1.x; a1 += v1.y;
        a0 += v2.x; a1 += v2.y;
        a0 += v3.x; a1 += v3.y;
    }
    for(; i < end; i++){
        float2 v = *(const float2*)(xs + (size_t)el[i]*8 + fp);
        a0 += v.x; a1 += v.y;
    }
    float2 o; o.x = a0; o.y = a1;
    *(float2*)(agg8 + (size_t)node*8 + fp) = o;
}

// ---------------- conv1 epilogue: h1 = bf16(relu(dinv*(agg8 @ W1) + b1)) ----------------
__global__ void k_conv1(const float* __restrict__ agg8, const float* __restrict__ cw1,
                        const float* __restrict__ dinv, const float* __restrict__ b1,
                        u16* __restrict__ h1){
    __shared__ float w[512];
    int t = threadIdx.x;
    w[t]       = cw1[t];
    w[t + 256] = cw1[t + 256];
    __syncthreads();
    int i = blockIdx.x*256 + t;      // grid exactly N*64/256
    int n = i >> 6, f = i & 63;
    const float* ar = agg8 + (size_t)n*8;
    float acc = 0.f;
    #pragma unroll
    for(int k = 0; k < 8; k++) acc += ar[k] * w[k*64 + f];
    h1[(size_t)n*64 + f] = f2bf(fmaxf(dinv[n]*acc + b1[f], 0.f));
}

// ---------------- layer-2 fused gather + epilogue: u32 loads, 2 feats/thread ----------------
__global__ __launch_bounds__(256)
void k_gather_ep(const int* __restrict__ rowptr, const int* __restrict__ el,
                 const u16* __restrict__ src, const float* __restrict__ dinv,
                 const float* __restrict__ b, u16* __restrict__ h, int ostride){
    int gid = blockIdx.x*256 + threadIdx.x;   // grid exactly N*32/256
    int node = gid >> 5, fp = (gid & 31)*2;
    int beg = rowptr[node], end = rowptr[node + 1];
    u32 self = *(const u32*)(src + (size_t)node*64 + fp);
    float acc0 = bf2f((u16)self), acc1 = bf2f((u16)(self >> 16));
    int i = beg;
    for(; i + 4 <= end; i += 4){
        int s0 = el[i], s1 = el[i+1], s2 = el[i+2], s3 = el[i+3];
        u32 a0 = *(const u32*)(src + (size_t)s0*64 + fp);
        u32 a1 = *(const u32*)(src + (size_t)s1*64 + fp);
        u32 a2 = *(const u32*)(src + (size_t)s2*64 + fp);
        u32 a3 = *(const u32*)(src + (size_t)s3*64 + fp);
        acc0 += bf2f((u16)a0); acc1 += bf2f((u16)(a0 >> 16));
        acc0 += bf2f((u16)a1); acc1 += bf2f((u16)(a1 >> 16));
        acc0 += bf2f((u16)a2); acc1 += bf2f((u16)(a2 >> 16));
        acc0 += bf2f((u16)a3); acc1 += bf2f((u16)(a3 >> 16));
    }
    for(; i < end; i++){
        u32 a = *(const u32*)(src + (size_t)el[i]*64 + fp);
        acc0 += bf2f((u16)a); acc1 += bf2f((u16)(a >> 16));
    }
    float dv = dinv[node];
    float r0 = fmaxf(dv*acc0 + b[fp],     0.f);
    float r1 = fmaxf(dv*acc1 + b[fp + 1], 0.f);
    *(u32*)(h + (size_t)node*ostride + fp) = (u32)f2bf(r0) | ((u32)f2bf(r1) << 16);
}

// ---------------- conv2 GEMM: src = bf16((h1 @ W2) * dinv) ----------------
__global__ __launch_bounds__(256, 4)
void k_conv2(const u16* __restrict__ h, const u16* __restrict__ w2p,
             const float* __restrict__ dinv, u16* __restrict__ src){
    int wv = threadIdx.x >> 6, lane = threadIdx.x & 63;
    int g = blockIdx.x*4 + wv;
    if(g >= N_NODES/16) return;
    int q = lane >> 4, m = lane & 15, col = m;
    bshort8 a0 = *(const bshort8*)(h + (g*16 + m)*64 + q*8);
    bshort8 a1 = *(const bshort8*)(h + (g*16 + m)*64 + 32 + q*8);
    f32x4 acc[4];
    #pragma unroll
    for(int nt = 0; nt < 4; nt++){
        f32x4 c = {0.f,0.f,0.f,0.f};
        c = __builtin_amdgcn_mfma_f32_16x16x32_bf16(a0, *(const bshort8*)(w2p + ((nt*2+0)*64 + lane)*8), c, 0,0,0);
        c = __builtin_amdgcn_mfma_f32_16x16x32_bf16(a1, *(const bshort8*)(w2p + ((nt*2+1)*64 + lane)*8), c, 0,0,0);
        acc[nt] = c;
    }
    #pragma unroll
    for(int nt = 0; nt < 4; nt++)
        #pragma unroll
        for(int r = 0; r < 4; r++){
            int node = g*16 + q*4 + r;
            src[node*64 + nt*16 + col] = f2bf(acc[nt][r] * dinv[node]);
        }
}

// ---------------- GRU + pair precompute, fused; gi loads hoisted above MFMA ----------------
__global__ __launch_bounds__(256, 4)
void k_gru(const int* __restrict__ xt, const u16* __restrict__ whhp,
           const float* __restrict__ giT, const float* __restrict__ bhh,
           u16* nodef, u32* __restrict__ udst,
           const u16* __restrict__ w1a, const u16* __restrict__ w1b,
           const u16* __restrict__ wta, const u16* __restrict__ wtb,
           const float* __restrict__ b1, const float* __restrict__ bt){
    __shared__ __align__(16) u16 wsh[12288];        // 24 KB Whh frags
    __shared__ __align__(16) u16 hsh[4][16][72];    // bf16 h tile
    int tid = threadIdx.x;
    {
        const uint4* s = (const uint4*)whhp;
        uint4* d = (uint4*)wsh;
        #pragma unroll
        for(int i = 0; i < 6; i++) d[tid + 256*i] = s[tid + 256*i];
    }
    __syncthreads();

    int wv = tid >> 6, lane = tid & 63;
    int q = lane >> 4, m = lane & 15, col = m;
    int g = blockIdx.x*4 + wv;
    bool active = g < (N_NODES/16);
    int nb = active ? g*16 : 0;

    float bhhn[4];
    #pragma unroll
    for(int t = 0; t < 4; t++) bhhn[t] = bhh[128 + t*16 + col];

    const bshort8* wl = (const bshort8*)wsh;
    const u16* hp = &hsh[wv][m][0];

    float hc[4][4];
    #pragma unroll
    for(int t = 0; t < 4; t++)
        #pragma unroll
        for(int r = 0; r < 4; r++) hc[t][r] = 0.f;

    for(int s = 0; s < 10; s++){
        #pragma unroll
        for(int t = 0; t < 4; t++)
            #pragma unroll
            for(int r = 0; r < 4; r++)
                hsh[wv][q*4 + r][t*16 + col] = f2bf(hc[t][r]);

        asm volatile("" ::: "memory");
        bshort8 a0 = *(const bshort8*)(hp + q*8);
        bshort8 a1 = *(const bshort8*)(hp + 32 + q*8);

        int tok[4];
        #pragma unroll
        for(int r = 0; r < 4; r++) tok[r] = xt[(nb + q*4 + r)*10 + s] & 63;

        // gi loads hoisted: issue BEFORE the MFMA block so MFMA issue covers L2 latency
        float4 gr4[4], gz4[4], gn4[4];
        #pragma unroll
        for(int r = 0; r < 4; r++){
            const float4* gp = (const float4*)(giT + (size_t)tok[r]*192);
            gr4[r] = gp[col];
            gz4[r] = gp[16 + col];
            gn4[r] = gp[32 + col];
        }

        f32x4 acc[12];
        #pragma unroll
        for(int nt = 0; nt < 12; nt++){
            f32x4 c = {0.f,0.f,0.f,0.f};
            c = __builtin_amdgcn_mfma_f32_16x16x32_bf16(a0, wl[(nt*2+0)*64 + lane], c, 0,0,0);
            c = __builtin_amdgcn_mfma_f32_16x16x32_bf16(a1, wl[(nt*2+1)*64 + lane], c, 0,0,0);
            acc[nt] = c;
        }

        #pragma unroll
        for(int r = 0; r < 4; r++){
            #pragma unroll
            for(int t = 0; t < 4; t++){
                float gir = ((const float*)&gr4[r])[t];
                float giz = ((const float*)&gz4[r])[t];
                float gin = ((const float*)&gn4[r])[t];
                float rr = frcp(1.0f + fexp2(-LOG2E*(gir + acc[t][r])));
                float zz = frcp(1.0f + fexp2(-LOG2E*(giz + acc[4+t][r])));
                float narg = gin + rr*(acc[8+t][r] + bhhn[t]);
                float e2 = fexp2(2.0f*LOG2E*narg);
                float nn = 1.0f - 2.0f*frcp(e2 + 1.0f);
                hc[t][r] = nn + zz*(hc[t][r] - nn);
            }
        }
        asm volatile("" ::: "memory");
    }

    // ---- fused pair precompute ----
    #pragma unroll
    for(int t = 0; t < 4; t++)
        #pragma unroll
        for(int r = 0; r < 4; r++)
            hsh[wv][q*4 + r][t*16 + col] = f2bf(hc[t][r]);   // txt tile
    asm volatile("" ::: "memory");
    bshort8 at0 = *(const bshort8*)(hp + q*8);
    bshort8 at1 = *(const bshort8*)(hp + 32 + q*8);
    const u16* row = nodef + (size_t)(nb + m)*128;           // h2 rows
    bshort8 ah0 = *(const bshort8*)(row + q*8);
    bshort8 ah1 = *(const bshort8*)(row + 32 + q*8);

    u32* usrc = (u32*)nodef;
    #pragma unroll
    for(int nt = 0; nt < 4; nt++){
        f32x4 cu1 = {0.f,0.f,0.f,0.f}, cu2 = {0.f,0.f,0.f,0.f};
        f32x4 cv1 = {0.f,0.f,0.f,0.f}, cv2 = {0.f,0.f,0.f,0.f};
        cu1 = __builtin_amdgcn_mfma_f32_16x16x32_bf16(ah0, *(const bshort8*)(w1a + ((nt*2+0)*64 + lane)*8), cu1, 0,0,0);
        cu1 = __builtin_amdgcn_mfma_f32_16x16x32_bf16(ah1, *(const bshort8*)(w1a + ((nt*2+1)*64 + lane)*8), cu1, 0,0,0);
        cu2 = __builtin_amdgcn_mfma_f32_16x16x32_bf16(ah0, *(const bshort8*)(w1b + ((nt*2+0)*64 + lane)*8), cu2, 0,0,0);
        cu2 = __builtin_amdgcn_mfma_f32_16x16x32_bf16(ah1, *(const bshort8*)(w1b + ((nt*2+1)*64 + lane)*8), cu2, 0,0,0);
        cv1 = __builtin_amdgcn_mfma_f32_16x16x32_bf16(at0, *(const bshort8*)(wta + ((nt*2+0)*64 + lane)*8), cv1, 0,0,0);
        cv1 = __builtin_amdgcn_mfma_f32_16x16x32_bf16(at1, *(const bshort8*)(wta + ((nt*2+1)*64 + lane)*8), cv1, 0,0,0);
        cv2 = __builtin_amdgcn_mfma_f32_16x16x32_bf16(at0, *(const bshort8*)(wtb + ((nt*2+0)*64 + lane)*8), cv2, 0,0,0);
        cv2 = __builtin_amdgcn_mfma_f32_16x16x32_bf16(at1, *(const bshort8*)(wtb + ((nt*2+1)*64 + lane)*8), cv2, 0,0,0);
        if(active){
            int f = nt*16 + col;
            float b1f = b1[f], btf = bt[f];
            #pragma unroll
            for(int r = 0; r < 4; r++){
                int node = nb + q*4 + r;
                u32 pa = (u32)f2bf(cu1[r] + b1f) | ((u32)f2bf(cv1[r] + btf) << 16);
                u32 pb = (u32)f2bf(cu2[r]) | ((u32)f2bf(cv2[r]) << 16);
                usrc[(size_t)node*64 + f] = pa;
                udst[(size_t)node*64 + f] = pb;
            }
        }
    }
}

// ---------------- edge kernel: uint4 row loads; 4 edges/wave, 16 lanes/edge ----------------
__global__ __launch_bounds__(256, 6)
void k_edge2(const int* __restrict__ el, const int* __restrict__ dl, const int* __restrict__ eid,
             const u32* __restrict__ usrc, const u32* __restrict__ udst,
             const float* __restrict__ wfin, const float* __restrict__ bfin,
             const int* __restrict__ flagp, void* __restrict__ out){
    int tid = threadIdx.x;
    int lane = tid & 63;
    int q = lane >> 4, f0 = lane & 15;
    int wid = (blockIdx.x*256 + tid) >> 6;
    int nwv = (gridDim.x*256) >> 6;
    int fl = *flagp;

    float wp0[4], wp1[4], wt0[4], wt1[4];
    #pragma unroll
    for(int t = 0; t < 4; t++){
        int f = 4*f0 + t;
        wp0[t] = wfin[f];        wt0[t] = wfin[64 + f];
        wp1[t] = wfin[128 + f];  wt1[t] = wfin[192 + f];
    }
    float bf0 = bfin[0], bf1 = bfin[1];

    for(int grp = wid; grp < N_EDGES/4; grp += nwv){
        int e = grp*4 + q;
        int s = el[e], d = dl[e];
        uint4 us4 = *((const uint4*)(usrc + (size_t)s*64) + f0);
        uint4 ud4 = *((const uint4*)(udst + (size_t)d*64) + f0);
        u32 us[4] = {us4.x, us4.y, us4.z, us4.w};
        u32 ud[4] = {ud4.x, ud4.y, ud4.z, ud4.w};
        float s0 = 0.f, s1 = 0.f;
        #pragma unroll
        for(int t = 0; t < 4; t++){
            float u1 = __uint_as_float(us[t] << 16);
            float v1 = __uint_as_float(us[t] & 0xffff0000u);
            float u2 = __uint_as_float(ud[t] << 16);
            float v2 = __uint_as_float(ud[t] & 0xffff0000u);
            float xp = fmaxf(u1 + u2, 0.f);
            float xq = fmaxf(v1 + v2, 0.f);
            s0 += xp*wp0[t] + xq*wt0[t];
            s1 += xp*wp1[t] + xq*wt1[t];
        }
        #pragma unroll
        for(int msk = 1; msk < 16; msk <<= 1){
            s0 += __shfl_xor(s0, msk, 64);
            s1 += __shfl_xor(s1, msk, 64);
        }
        if(f0 == 0){
            float a = s0 + bf0, b = s1 + bf1;
            float mx = fmaxf(a, b);
            float lse = mx + __logf(__expf(a - mx) + __expf(b - mx));
            int oi = eid[e];
            if(fl){
                float2 v; v.x = a - lse; v.y = b - lse;
                ((float2*)out)[oi] = v;
            }else{
                u32 pack = (u32)f2bf(a - lse) | ((u32)f2bf(b - lse) << 16);
                ((u32*)out)[oi] = pack;
            }
        }
    }
}

// ---------------- workspace layout (68.3 MB) ----------------
static const size_t O_FLAG   = 0;
static const size_t O_CANON  = 4096;       // 3,402,248
static const size_t O_GIT    = 3407872;    // 49,152
static const size_t O_W2P    = 3457024;    // 8,192
static const size_t O_WHHP   = 3465216;    // 24,576
static const size_t O_L1PA   = 3489792;    // 8,192
static const size_t O_L1PB   = 3497984;    // 8,192
static const size_t O_LTPA   = 3506176;    // 8,192
static const size_t O_LTPB   = 3514368;    // 8,192
static const size_t O_DINV   = 3522560;    // 400,000
static const size_t O_DEG    = 3922560;    // 400,000
static const size_t O_ROWPTR = 4322560;    // 400,128
static const size_t O_CURSOR = 4722688;    // 400,000
static const size_t O_BSUM   = 5122688;    // 2,048
static const size_t O_EL     = 5124736;    // 4,000,000
static const size_t O_DL     = 9125888;    // 4,000,000
static const size_t O_EID    = 13125888;   // 4,000,000
static const size_t O_SRC    = 17125888;   // N*64 bf16 (written by conv2; dead after gather_ep)
static const size_t O_XS     = 17125888;   // N*8 f32 (overlays SRC; dead before conv2 writes)
static const size_t O_AGG8   = 20325888;   // N*8 f32 (overlays SRC; dead before conv2 writes)
static const size_t O_H1     = 29925888;   // N*64 bf16 (dead after conv2)
static const size_t O_UDST   = 17125888;   // N*64 u32 (overlays SRC+H1, written in fused gru)
static const size_t O_NODEF  = 42725888;   // N*128 bf16 (h2; fused gru rewrites in-place as usrc)
// end = 68,325,888

extern "C" void kernel_launch(void* const* d_in, const int* in_sizes, int n_in,
                              void* d_out, int out_size, void* d_ws, size_t ws_size,
                              hipStream_t stream){
    const void* x    = d_in[0];
    const int*  ei   = (const int*)d_in[1];
    const int*  xt   = (const int*)d_in[2];

    char* ws = (char*)d_ws;
    int*   flagp  = (int*)(ws + O_FLAG);
    float* canon  = (float*)(ws + O_CANON);
    float* giT    = (float*)(ws + O_GIT);
    u16*   w2p    = (u16*)(ws + O_W2P);
    u16*   whhp   = (u16*)(ws + O_WHHP);
    u16*   l1pa   = (u16*)(ws + O_L1PA);
    u16*   l1pb   = (u16*)(ws + O_L1PB);
    u16*   ltpa   = (u16*)(ws + O_LTPA);
    u16*   ltpb   = (u16*)(ws + O_LTPB);
    float* dinv   = (float*)(ws + O_DINV);
    int*   deg    = (int*)(ws + O_DEG);
    int*   rowptr = (int*)(ws + O_ROWPTR);
    int*   cursor = (int*)(ws + O_CURSOR);
    int*   bsum   = (int*)(ws + O_BSUM);
    int*   el     = (int*)(ws + O_EL);
    int*   dl     = (int*)(ws + O_DL);
    int*   eid    = (int*)(ws + O_EID);
    u16*   src    = (u16*)(ws + O_SRC);
    float* xs     = (float*)(ws + O_XS);
    float* agg8   = (float*)(ws + O_AGG8);
    u16*   hbuf1  = (u16*)(ws + O_H1);
    u32*   udst   = (u32*)(ws + O_UDST);
    u16*   nodef  = (u16*)(ws + O_NODEF);

    // deg zero + dtype detect, then ALL table prep + histogram in one kernel
    hipMemsetAsync(deg, 0, (size_t)N_NODES*4, stream);
    k_detect<<<1, 256, 0, stream>>>((const u16*)x, flagp);
    k_tables<<<B_TOT, 256, 0, stream>>>(flagp,
        x, d_in[3], d_in[4], d_in[5], d_in[6], d_in[7], d_in[8], d_in[9],
        d_in[10], d_in[11], d_in[12], d_in[13], d_in[14], d_in[15], d_in[16], d_in[17],
        ei, deg,
        canon, w2p, whhp, l1pa, l1pb, ltpa, ltpb, giT);

    const float* cx   = canon + CX;
    const float* cw1  = canon + CW1;
    const float* cb1  = canon + CB1;
    const float* cb2  = canon + CB2;
    const float* cbhh = canon + CBHH;
    const float* cl1b = canon + CL1B;
    const float* cltb = canon + CLTB;
    const float* clfw = canon + CLFW;
    const float* clfb = canon + CLFB;

    // CSR build (scan3 also emits xs = x*dinv in f32)
    k_scan1<<<NBLK, 256, 0, stream>>>(deg, rowptr, bsum);
    k_scan2<<<1, 512, 0, stream>>>(bsum);
    k_scan3<<<NBLK, 256, 0, stream>>>(deg, bsum, rowptr, cursor, dinv, cx, xs);
    k_fill <<<(N_EDGES+255)/256, 256, 0, stream>>>(ei, cursor, el, dl, eid);

    // GCN layer 1 via rank-8 aggregation (f32): xs -> agg8 -> h1
    k_gather8<<<(N_NODES*4 + 255)/256, 256, 0, stream>>>(rowptr, el, xs, agg8);
    k_conv1<<<N_NODES*64/256, 256, 0, stream>>>(agg8, cw1, dinv, cb1, hbuf1);

    // GCN layer 2 (h1 -> src -> nodef[+0], stride 128)
    k_conv2<<<(N_NODES/16 + 3)/4, 256, 0, stream>>>(hbuf1, w2p, dinv, src);
    k_gather_ep<<<N_NODES*32/256, 256, 0, stream>>>(rowptr, el, src, dinv, cb2, nodef, 128);

    // GRU + pair precompute fused (nodef -> usrc in-place, udst)
    k_gru<<<(N_NODES/16 + 3)/4, 256, 0, stream>>>(xt, whhp, giT, cbhh,
                                                  nodef, udst, l1pa, l1pb, ltpa, ltpb,
                                                  cl1b, cltb);

    // edge logits + log_softmax (CSR order, scatter by eid)
    k_edge2<<<4096, 256, 0, stream>>>(el, dl, eid, (const u32*)nodef, udst,
                                      clfw, clfb, flagp, d_out);
}